// Round 1
// baseline (4726.590 us; speedup 1.0000x reference)
//
#include <hip/hip_runtime.h>
#include <cstdint>
#include <cstddef>

#define DEV_INLINE __device__ __forceinline__

// Problem constants
// B=8, L_IN=512 -> L=1024, M = 8*1024 = 8192 rows
// C=512, D_INNER=1024, D_STATE=16, DT_RANK=32, DEPTH=4
static constexpr float EPS = 1e-5f;

DEV_INLINE float sigmoidf_(float x) { return 1.0f / (1.0f + __expf(-x)); }
DEV_INLINE float siluf_(float x) { return x * sigmoidf_(x); }
DEV_INLINE float softplusf_(float x) {
    // numerically stable log(1+exp(x))
    return fmaxf(x, 0.0f) + log1pf(__expf(-fabsf(x)));
}

// ---------------------------------------------------------------------------
// Generic tiled fp32 GEMM:  C[M,N] (+)= A[M,K] * W[N,K]^T  (+ bias + embed)
// Requirements: M%64==0, N%64==0, K%16==0, lda/ldw multiples of 4.
// ACT: 0=none, 1=softplus.  ACC: accumulate into C.  EMBED: add embed[row>>10][col].
// ---------------------------------------------------------------------------
template <int ACT, bool ACC, bool EMBED>
__global__ __launch_bounds__(256) void gemm_tn(
    const float* __restrict__ A, int lda,
    const float* __restrict__ W, int ldw,
    float* __restrict__ Cm, int ldc,
    int N, int K,
    const float* __restrict__ bias,
    const float* __restrict__ embed)
{
    __shared__ float As[16][64];
    __shared__ float Ws[16][64];
    const int bm = blockIdx.y * 64;
    const int bn = blockIdx.x * 64;
    const int tid = (int)threadIdx.x;
    const int tx = tid & 15;        // 0..15  -> 4 cols each
    const int ty = tid >> 4;        // 0..15  -> 4 rows each
    const int lr = tid >> 2;        // 0..63  tile row for loading
    const int lk = (tid & 3) << 2;  // 0,4,8,12 k-offset for loading

    float acc[4][4] = {};

    const float* Aload = A + (size_t)(bm + lr) * lda + lk;
    const float* Wload = W + (size_t)(bn + lr) * ldw + lk;

    for (int k0 = 0; k0 < K; k0 += 16) {
        float4 av = *(const float4*)(Aload + k0);
        float4 wv = *(const float4*)(Wload + k0);
        As[lk + 0][lr] = av.x; As[lk + 1][lr] = av.y;
        As[lk + 2][lr] = av.z; As[lk + 3][lr] = av.w;
        Ws[lk + 0][lr] = wv.x; Ws[lk + 1][lr] = wv.y;
        Ws[lk + 2][lr] = wv.z; Ws[lk + 3][lr] = wv.w;
        __syncthreads();
#pragma unroll
        for (int kk = 0; kk < 16; ++kk) {
            float a[4], w[4];
#pragma unroll
            for (int i = 0; i < 4; ++i) a[i] = As[kk][ty * 4 + i];
#pragma unroll
            for (int j = 0; j < 4; ++j) w[j] = Ws[kk][tx * 4 + j];
#pragma unroll
            for (int i = 0; i < 4; ++i)
#pragma unroll
                for (int j = 0; j < 4; ++j)
                    acc[i][j] += a[i] * w[j];
        }
        __syncthreads();
    }

#pragma unroll
    for (int i = 0; i < 4; ++i) {
        const int row = bm + ty * 4 + i;
#pragma unroll
        for (int j = 0; j < 4; ++j) {
            const int col = bn + tx * 4 + j;
            float v = acc[i][j];
            if (bias) v += bias[col];
            if (EMBED) v += embed[(size_t)(row >> 10) * N + col];
            if (ACT == 1) v = softplusf_(v);
            float* cp = Cm + (size_t)row * ldc + col;
            if (ACC) *cp += v; else *cp = v;
        }
    }
}

// ---------------------------------------------------------------------------
// Transpose w_up (512,512,2) -> wt[k][o][c] two (512x512) K-contiguous mats
// ---------------------------------------------------------------------------
__global__ __launch_bounds__(256) void transpose_wup(
    const float* __restrict__ wup, float* __restrict__ wt)
{
    int t = blockIdx.x * 256 + (int)threadIdx.x;   // t = c*512 + o
    if (t >= 512 * 512) return;
    int c = t >> 9, o = t & 511;
    float2 v = *(const float2*)(wup + (size_t)t * 2);
    wt[(size_t)o * 512 + c] = v.x;
    wt[(size_t)(512 * 512) + (size_t)o * 512 + c] = v.y;
}

// ---------------------------------------------------------------------------
// Concat skip_feats into x0 cols [512,1024)
// ---------------------------------------------------------------------------
__global__ __launch_bounds__(256) void concat_skip(
    const float* __restrict__ skip, float* __restrict__ x0)
{
    int t = blockIdx.x * 256 + (int)threadIdx.x;   // float4 index, 8192*512/4
    int row = t >> 7;
    int col4 = (t & 127) << 2;
    float4 v = *(const float4*)(skip + (size_t)row * 512 + col4);
    *(float4*)(x0 + (size_t)row * 1024 + 512 + col4) = v;
}

// ---------------------------------------------------------------------------
// Row ops on 512-wide rows: one wave (64 lanes) per row, 4 rows per block.
// ---------------------------------------------------------------------------
__global__ __launch_bounds__(256) void layernorm_k(
    const float* __restrict__ x, float* __restrict__ out,
    const float* __restrict__ w, const float* __restrict__ b)
{
    const int row = blockIdx.x * 4 + ((int)threadIdx.x >> 6);
    const int lane = (int)threadIdx.x & 63;
    const float* xr = x + (size_t)row * 512;
    float4 v0 = *(const float4*)(xr + lane * 4);
    float4 v1 = *(const float4*)(xr + 256 + lane * 4);
    float s = v0.x + v0.y + v0.z + v0.w + v1.x + v1.y + v1.z + v1.w;
    float q = v0.x*v0.x + v0.y*v0.y + v0.z*v0.z + v0.w*v0.w
            + v1.x*v1.x + v1.y*v1.y + v1.z*v1.z + v1.w*v1.w;
#pragma unroll
    for (int o = 32; o; o >>= 1) {
        s += __shfl_xor(s, o, 64);
        q += __shfl_xor(q, o, 64);
    }
    const float mean = s * (1.0f / 512.0f);
    const float var = q * (1.0f / 512.0f) - mean * mean;
    const float rstd = rsqrtf(var + EPS);
    float4 w0 = *(const float4*)(w + lane * 4);
    float4 w1 = *(const float4*)(w + 256 + lane * 4);
    float4 b0 = *(const float4*)(b + lane * 4);
    float4 b1 = *(const float4*)(b + 256 + lane * 4);
    float4 o0, o1;
    o0.x = (v0.x - mean) * rstd * w0.x + b0.x;
    o0.y = (v0.y - mean) * rstd * w0.y + b0.y;
    o0.z = (v0.z - mean) * rstd * w0.z + b0.z;
    o0.w = (v0.w - mean) * rstd * w0.w + b0.w;
    o1.x = (v1.x - mean) * rstd * w1.x + b1.x;
    o1.y = (v1.y - mean) * rstd * w1.y + b1.y;
    o1.z = (v1.z - mean) * rstd * w1.z + b1.z;
    o1.w = (v1.w - mean) * rstd * w1.w + b1.w;
    float* orow = out + (size_t)row * 512;
    *(float4*)(orow + lane * 4) = o0;
    *(float4*)(orow + 256 + lane * 4) = o1;
}

__global__ __launch_bounds__(256) void rms_silu_k(
    float* __restrict__ x, const float* __restrict__ w)
{
    const int row = blockIdx.x * 4 + ((int)threadIdx.x >> 6);
    const int lane = (int)threadIdx.x & 63;
    float* xr = x + (size_t)row * 512;
    float4 v0 = *(const float4*)(xr + lane * 4);
    float4 v1 = *(const float4*)(xr + 256 + lane * 4);
    float q = v0.x*v0.x + v0.y*v0.y + v0.z*v0.z + v0.w*v0.w
            + v1.x*v1.x + v1.y*v1.y + v1.z*v1.z + v1.w*v1.w;
#pragma unroll
    for (int o = 32; o; o >>= 1) q += __shfl_xor(q, o, 64);
    const float scale = rsqrtf(q * (1.0f / 512.0f) + EPS);
    float4 w0 = *(const float4*)(w + lane * 4);
    float4 w1 = *(const float4*)(w + 256 + lane * 4);
    float y;
    y = v0.x * scale * w0.x; v0.x = siluf_(y);
    y = v0.y * scale * w0.y; v0.y = siluf_(y);
    y = v0.z * scale * w0.z; v0.z = siluf_(y);
    y = v0.w * scale * w0.w; v0.w = siluf_(y);
    y = v1.x * scale * w1.x; v1.x = siluf_(y);
    y = v1.y * scale * w1.y; v1.y = siluf_(y);
    y = v1.z * scale * w1.z; v1.z = siluf_(y);
    y = v1.w * scale * w1.w; v1.w = siluf_(y);
    *(float4*)(xr + lane * 4) = v0;
    *(float4*)(xr + 256 + lane * 4) = v1;
}

// ---------------------------------------------------------------------------
// In-place causal depthwise conv (k=4) + bias + silu on xz cols [0,1024).
// One thread per (b,d) column, rolling window over L=1024.
// ---------------------------------------------------------------------------
__global__ __launch_bounds__(256) void conv_silu_k(
    float* __restrict__ xz, const float* __restrict__ cw,
    const float* __restrict__ cb)
{
    int t = blockIdx.x * 256 + (int)threadIdx.x;   // 8192 threads
    int d = t & 1023, b = t >> 10;
    float4 w4 = *(const float4*)(cw + (size_t)d * 4);
    float bias = cb[d];
    float x0 = 0.0f, x1 = 0.0f, x2 = 0.0f;
    float* p = xz + (size_t)b * 1024 * 2048 + d;
    for (int l = 0; l < 1024; ++l) {
        float x3 = p[(size_t)l * 2048];
        float v = x0 * w4.x + x1 * w4.y + x2 * w4.z + x3 * w4.w + bias;
        p[(size_t)l * 2048] = siluf_(v);
        x0 = x1; x1 = x2; x2 = x3;
    }
}

// ---------------------------------------------------------------------------
// Selective scan. Thread = (b, d, n); 16 n-lanes per (b,d) group.
// dty holds dt on entry; y (+u*D) is written in place over it.
// ---------------------------------------------------------------------------
__global__ __launch_bounds__(256) void scan_k(
    const float* __restrict__ xz,    // u at cols [0,1024) of (M,2048)
    float* __restrict__ dty,         // (M,1024) dt in / y out
    const float* __restrict__ xdbc,  // (M,64): [0,32) dtp, [32,48) B, [48,64) C
    const float* __restrict__ A_log, // (1024,16)
    const float* __restrict__ Dp)    // (1024)
{
    const int b = blockIdx.x >> 6;                           // 0..7
    const int dg = ((int)blockIdx.x & 63) * 16 + ((int)threadIdx.x >> 4); // 0..1023
    const int n = (int)threadIdx.x & 15;
    const float An = -__expf(A_log[(size_t)dg * 16 + n]);
    const float Dv = Dp[dg];
    float h = 0.0f;
    const size_t base_u = (size_t)b * 1024 * 2048 + dg;
    const size_t base_dt = (size_t)b * 1024 * 1024 + dg;
    const size_t base_bc = (size_t)b * 1024 * 64;
    for (int l = 0; l < 1024; ++l) {
        float dt = dty[base_dt + (size_t)l * 1024];
        float u = xz[base_u + (size_t)l * 2048];
        float Bv = xdbc[base_bc + (size_t)l * 64 + 32 + n];
        float Cv = xdbc[base_bc + (size_t)l * 64 + 48 + n];
        float dA = __expf(dt * An);
        h = dA * h + dt * u * Bv;
        float p = h * Cv;
        p += __shfl_xor(p, 1, 16);
        p += __shfl_xor(p, 2, 16);
        p += __shfl_xor(p, 4, 16);
        p += __shfl_xor(p, 8, 16);
        if (n == 0) dty[base_dt + (size_t)l * 1024] = p + u * Dv;
    }
}

// ---------------------------------------------------------------------------
// Gate: y *= silu(z)   (z = xz cols [1024,2048)), in place on dty
// ---------------------------------------------------------------------------
__global__ __launch_bounds__(256) void gate_k(
    float* __restrict__ y, const float* __restrict__ xz)
{
    int t = blockIdx.x * 256 + (int)threadIdx.x;   // float4 over 8192*1024/4
    int m = t >> 8;
    int d4 = (t & 255) << 2;
    float4 yv = *(const float4*)(y + (size_t)m * 1024 + d4);
    float4 zv = *(const float4*)(xz + (size_t)m * 2048 + 1024 + d4);
    yv.x *= siluf_(zv.x);
    yv.y *= siluf_(zv.y);
    yv.z *= siluf_(zv.z);
    yv.w *= siluf_(zv.w);
    *(float4*)(y + (size_t)m * 1024 + d4) = yv;
}

// ---------------------------------------------------------------------------
extern "C" void kernel_launch(void* const* d_in, const int* in_sizes, int n_in,
                              void* d_out, int out_size, void* d_ws, size_t ws_size,
                              hipStream_t stream)
{
    const float* motion     = (const float*)d_in[0];
    const float* skip       = (const float*)d_in[1];
    const float* embed      = (const float*)d_in[2];
    const float* w_up       = (const float*)d_in[3];
    const float* b_up       = (const float*)d_in[4];
    const float* w1         = (const float*)d_in[5];
    const float* b1         = (const float*)d_in[6];
    const float* rms_w      = (const float*)d_in[7];
    const float* w2         = (const float*)d_in[8];
    const float* b2         = (const float*)d_in[9];
    const float* ln_w       = (const float*)d_in[10];
    const float* ln_b       = (const float*)d_in[11];
    const float* in_proj_w  = (const float*)d_in[12];
    const float* conv_w     = (const float*)d_in[13];
    const float* conv_b     = (const float*)d_in[14];
    const float* x_proj_w   = (const float*)d_in[15];
    const float* dt_proj_w  = (const float*)d_in[16];
    const float* dt_proj_b  = (const float*)d_in[17];
    const float* A_log      = (const float*)d_in[18];
    const float* D_param    = (const float*)d_in[19];
    const float* out_proj_w = (const float*)d_in[20];
    const float* out_proj_b = (const float*)d_in[21];
    const float* norm_f_w   = (const float*)d_in[22];
    const float* norm_f_b   = (const float*)d_in[23];
    float* out = (float*)d_out;
    float* ws = (float*)d_ws;

    // Workspace layout (floats):
    float* xbuf = ws;               //  4M floats (8192 x 512)  persistent x
    float* xln  = ws + 4194304;     //  4M floats (8192 x 512)  xln / t1
    float* xz   = ws + 8388608;     // 16M floats (8192 x 2048) xz / x0
    float* dty  = ws + 25165824;    //  8M floats (8192 x 1024) dt -> y -> gated y
    float* xdbc = ws + 33554432;    // 512K floats (8192 x 64)
    float* wt   = ws + 34078720;    // 512K floats (2 x 512 x 512)
    // total = 34,603,008 floats = 132 MiB

    dim3 blk(256);

    // --- Stage 1: upsample GEMM + concat ---
    transpose_wup<<<dim3(1024), blk, 0, stream>>>(w_up, wt);
    float* x0 = xz;  // (8192 x 1024)
    for (int k = 0; k < 2; ++k) {
        // out[m, o] -> x0[(2m+k)*1024 + o]  == base x0 + k*1024, ldc = 2048
        gemm_tn<0, false, false><<<dim3(8, 64), blk, 0, stream>>>(
            motion, 512, wt + (size_t)k * 262144, 512,
            x0 + (size_t)k * 1024, 2048, 512, 512, b_up, nullptr);
    }
    concat_skip<<<dim3(4096), blk, 0, stream>>>(skip, x0);

    // --- Stage 2: t1 = x0 @ w1^T + b1 ; rmsnorm+silu in place ---
    gemm_tn<0, false, false><<<dim3(8, 128), blk, 0, stream>>>(
        x0, 1024, w1, 1024, xln, 512, 512, 1024, b1, nullptr);
    rms_silu_k<<<dim3(2048), blk, 0, stream>>>(xln, rms_w);

    // --- Stage 3: x = t1 @ w2^T + b2 + embed ---
    gemm_tn<0, false, true><<<dim3(8, 128), blk, 0, stream>>>(
        xln, 512, w2, 512, xbuf, 512, 512, 512, b2, embed);

    // --- Mamba blocks ---
    for (int i = 0; i < 4; ++i) {
        layernorm_k<<<dim3(2048), blk, 0, stream>>>(
            xbuf, xln, ln_w + (size_t)i * 512, ln_b + (size_t)i * 512);
        // xz = xln @ in_proj^T  (8192 x 2048)
        gemm_tn<0, false, false><<<dim3(32, 128), blk, 0, stream>>>(
            xln, 512, in_proj_w + (size_t)i * 2048 * 512, 512,
            xz, 2048, 2048, 512, nullptr, nullptr);
        // causal depthwise conv + silu, in place on xz cols [0,1024)
        conv_silu_k<<<dim3(32), blk, 0, stream>>>(
            xz, conv_w + (size_t)i * 4096, conv_b + (size_t)i * 1024);
        // xdbc = xc @ x_proj^T  (8192 x 64)
        gemm_tn<0, false, false><<<dim3(1, 128), blk, 0, stream>>>(
            xz, 2048, x_proj_w + (size_t)i * 64 * 1024, 1024,
            xdbc, 64, 64, 1024, nullptr, nullptr);
        // dt = softplus(dtp @ dt_proj^T + dtb)  (8192 x 1024)
        gemm_tn<1, false, false><<<dim3(16, 128), blk, 0, stream>>>(
            xdbc, 64, dt_proj_w + (size_t)i * 1024 * 32, 32,
            dty, 1024, 1024, 32, dt_proj_b + (size_t)i * 1024, nullptr);
        // selective scan: y (in place over dt)
        scan_k<<<dim3(512), blk, 0, stream>>>(
            xz, dty, xdbc, A_log + (size_t)i * 16384, D_param + (size_t)i * 1024);
        // y *= silu(z)
        gate_k<<<dim3(8192), blk, 0, stream>>>(dty, xz);
        // x += y @ out_proj^T + ob
        gemm_tn<0, true, false><<<dim3(8, 128), blk, 0, stream>>>(
            dty, 1024, out_proj_w + (size_t)i * 512 * 1024, 1024,
            xbuf, 512, 512, 1024, out_proj_b + (size_t)i * 512, nullptr);
    }

    // --- Final layernorm -> out ---
    layernorm_k<<<dim3(2048), blk, 0, stream>>>(xbuf, out, norm_f_w, norm_f_b);
}

// Round 2
// 1527.833 us; speedup vs baseline: 3.0937x; 3.0937x over previous
//
#include <hip/hip_runtime.h>
#include <cstdint>
#include <cstddef>

#define DEV_INLINE __device__ __forceinline__

static constexpr float EPS = 1e-5f;

DEV_INLINE float sigmoidf_(float x) { return 1.0f / (1.0f + __expf(-x)); }
DEV_INLINE float siluf_(float x) { return x * sigmoidf_(x); }
DEV_INLINE float softplusf_(float x) {
    return fmaxf(x, 0.0f) + log1pf(__expf(-fabsf(x)));
}
DEV_INLINE unsigned short f2bf(float x) {   // RNE f32 -> bf16
    unsigned u = __builtin_bit_cast(unsigned, x);
    u += 0x7FFFu + ((u >> 16) & 1u);
    return (unsigned short)(u >> 16);
}

typedef __attribute__((ext_vector_type(8))) short bf16x8;
typedef __attribute__((ext_vector_type(4))) float f32x4;

// ---------------------------------------------------------------------------
// f32 -> bf16 converter (weights). n8 = elem_count/8.
// ---------------------------------------------------------------------------
__global__ __launch_bounds__(256) void cvt_bf16(
    const float* __restrict__ s, unsigned short* __restrict__ d, int n8)
{
    int t = blockIdx.x * 256 + (int)threadIdx.x;
    if (t >= n8) return;
    float4 f0 = *(const float4*)(s + (size_t)t * 8);
    float4 f1 = *(const float4*)(s + (size_t)t * 8 + 4);
    union { unsigned short u[8]; uint4 v; } pk;
    pk.u[0] = f2bf(f0.x); pk.u[1] = f2bf(f0.y); pk.u[2] = f2bf(f0.z); pk.u[3] = f2bf(f0.w);
    pk.u[4] = f2bf(f1.x); pk.u[5] = f2bf(f1.y); pk.u[6] = f2bf(f1.z); pk.u[7] = f2bf(f1.w);
    *(uint4*)(d + (size_t)t * 8) = pk.v;
}

// w_up (512,512,2) f32 -> wt bf16 [k][o][c] (two 512x512, c contiguous)
__global__ __launch_bounds__(256) void transpose_wup_bf(
    const float* __restrict__ wup, unsigned short* __restrict__ wt)
{
    int t = blockIdx.x * 256 + (int)threadIdx.x;   // t = c*512 + o
    if (t >= 512 * 512) return;
    int c = t >> 9, o = t & 511;
    float2 v = *(const float2*)(wup + (size_t)t * 2);
    wt[(size_t)o * 512 + c] = f2bf(v.x);
    wt[262144 + (size_t)o * 512 + c] = f2bf(v.y);
}

// ---------------------------------------------------------------------------
// MFMA GEMM: C[M,N] (+)= A_f32[M,K] * W_bf16[N,K]^T  (+bias +embed)
// BM=BN=128, BK=64, 256 threads = 4 waves, each wave 64x64 via 4x4 frags of
// 16x16x32 bf16 MFMA. A: f32 loads -> bf16 cvt -> swizzled ds_write.
// W: global_load_lds(16B) with pre-swizzled global source (G21).
// LDS rows = 128B (64 bf16); chunk XOR-swizzle: LDS[r][c] = G[r][c^(r&7)].
// Requires M%128==0, N%128==0, K%64==0, lda%8==0, ldw%8==0.
// ---------------------------------------------------------------------------
template <bool ACC, bool EMBED>
__global__ __launch_bounds__(256) void gemm_mfma(
    const float* __restrict__ A, int lda,
    const unsigned short* __restrict__ W, int ldw,
    float* __restrict__ C, int ldc, int N, int K,
    const float* __restrict__ bias, const float* __restrict__ embed)
{
    __shared__ unsigned short Asm[128 * 64];
    __shared__ unsigned short Wsm[128 * 64];
    const int tid = (int)threadIdx.x;
    const int lane = tid & 63;
    const int wv = tid >> 6;
    const int wm = wv >> 1, wn = wv & 1;
    const int bm = blockIdx.y * 128, bn = blockIdx.x * 128;

    f32x4 acc[4][4] = {};

    // A staging roles (f32 path): 256 threads, thread -> (row, chunk)
    const int ar = tid >> 3;      // 0..31 (row within 32-row group)
    const int ac = tid & 7;       // 16B chunk 0..7
    // W staging roles (global_load_lds): per wave, 8 rows x 8 chunks
    const int l8 = lane >> 3;     // 0..7
    const int wc = lane & 7;
    const int wcg = wc ^ l8;      // pre-swizzled global chunk

    char* aB = (char*)Asm;
    char* bB = (char*)Wsm;

    for (int k0 = 0; k0 < K; k0 += 64) {
        // ---- stage W (bf16) via async global->LDS, linear dest ----
#pragma unroll
        for (int i = 0; i < 4; ++i) {
            int rb = (i * 4 + wv) * 8;
            const unsigned short* src =
                W + (size_t)(bn + rb + l8) * ldw + k0 + wcg * 8;
            __builtin_amdgcn_global_load_lds(
                (const __attribute__((address_space(1))) unsigned int*)src,
                (__attribute__((address_space(3))) unsigned int*)(bB + rb * 128),
                16, 0, 0);
        }
        // ---- stage A: f32 loads, cvt to bf16, swizzled ds_write ----
#pragma unroll
        for (int i = 0; i < 4; ++i) {
            int row = i * 32 + ar;
            int cg = ac ^ (row & 7);
            const float* s = A + (size_t)(bm + row) * lda + k0 + cg * 8;
            float4 f0 = *(const float4*)s;
            float4 f1 = *(const float4*)(s + 4);
            union { bf16x8 v; unsigned short u[8]; } pk;
            pk.u[0] = f2bf(f0.x); pk.u[1] = f2bf(f0.y);
            pk.u[2] = f2bf(f0.z); pk.u[3] = f2bf(f0.w);
            pk.u[4] = f2bf(f1.x); pk.u[5] = f2bf(f1.y);
            pk.u[6] = f2bf(f1.z); pk.u[7] = f2bf(f1.w);
            *(bf16x8*)(aB + row * 128 + ac * 16) = pk.v;
        }
        __syncthreads();

        const int rA = wm * 64 + (lane & 15);
        const int rB = wn * 64 + (lane & 15);
        const int q = lane >> 4;
#pragma unroll
        for (int kk = 0; kk < 2; ++kk) {
            bf16x8 af[4], bfr[4];
#pragma unroll
            for (int mi = 0; mi < 4; ++mi) {
                int row = rA + mi * 16;
                int ch = (kk * 4 + q) ^ (row & 7);
                af[mi] = *(const bf16x8*)(aB + row * 128 + ch * 16);
            }
#pragma unroll
            for (int ni = 0; ni < 4; ++ni) {
                int row = rB + ni * 16;
                int ch = (kk * 4 + q) ^ (row & 7);
                bfr[ni] = *(const bf16x8*)(bB + row * 128 + ch * 16);
            }
#pragma unroll
            for (int mi = 0; mi < 4; ++mi)
#pragma unroll
                for (int ni = 0; ni < 4; ++ni)
                    acc[mi][ni] = __builtin_amdgcn_mfma_f32_16x16x32_bf16(
                        af[mi], bfr[ni], acc[mi][ni], 0, 0, 0);
        }
        __syncthreads();
    }

    // ---- epilogue: D[m = (lane>>4)*4+r][n = lane&15] (m89-verified) ----
    const int cn = lane & 15;
    const int r0 = (lane >> 4) * 4;
    const int eb = EMBED ? (bm >> 10) * N : 0;
#pragma unroll
    for (int ni = 0; ni < 4; ++ni) {
        int col = bn + wn * 64 + ni * 16 + cn;
        float add = bias ? bias[col] : 0.0f;
        if (EMBED) add += embed[eb + col];
#pragma unroll
        for (int mi = 0; mi < 4; ++mi) {
#pragma unroll
            for (int r = 0; r < 4; ++r) {
                int row = bm + wm * 64 + mi * 16 + r0 + r;
                float v = acc[mi][ni][r] + add;
                float* p = C + (size_t)row * ldc + col;
                if (ACC) *p += v; else *p = v;
            }
        }
    }
}

// ---------------------------------------------------------------------------
// fp32 tiled GEMM (kept for small shapes: x_proj N=64, dt_proj K=32)
// ---------------------------------------------------------------------------
template <int ACT, bool ACCB>
__global__ __launch_bounds__(256) void gemm_tn(
    const float* __restrict__ A, int lda,
    const float* __restrict__ W, int ldw,
    float* __restrict__ Cm, int ldc,
    int N, int K, const float* __restrict__ bias)
{
    __shared__ float As[16][64];
    __shared__ float Ws[16][64];
    const int bm = blockIdx.y * 64;
    const int bn = blockIdx.x * 64;
    const int tid = (int)threadIdx.x;
    const int tx = tid & 15;
    const int ty = tid >> 4;
    const int lr = tid >> 2;
    const int lk = (tid & 3) << 2;

    float acc[4][4] = {};
    const float* Aload = A + (size_t)(bm + lr) * lda + lk;
    const float* Wload = W + (size_t)(bn + lr) * ldw + lk;

    for (int k0 = 0; k0 < K; k0 += 16) {
        float4 av = *(const float4*)(Aload + k0);
        float4 wv = *(const float4*)(Wload + k0);
        As[lk + 0][lr] = av.x; As[lk + 1][lr] = av.y;
        As[lk + 2][lr] = av.z; As[lk + 3][lr] = av.w;
        Ws[lk + 0][lr] = wv.x; Ws[lk + 1][lr] = wv.y;
        Ws[lk + 2][lr] = wv.z; Ws[lk + 3][lr] = wv.w;
        __syncthreads();
#pragma unroll
        for (int kk = 0; kk < 16; ++kk) {
            float a[4], w[4];
#pragma unroll
            for (int i = 0; i < 4; ++i) a[i] = As[kk][ty * 4 + i];
#pragma unroll
            for (int j = 0; j < 4; ++j) w[j] = Ws[kk][tx * 4 + j];
#pragma unroll
            for (int i = 0; i < 4; ++i)
#pragma unroll
                for (int j = 0; j < 4; ++j)
                    acc[i][j] += a[i] * w[j];
        }
        __syncthreads();
    }
#pragma unroll
    for (int i = 0; i < 4; ++i) {
        const int row = bm + ty * 4 + i;
#pragma unroll
        for (int j = 0; j < 4; ++j) {
            const int col = bn + tx * 4 + j;
            float v = acc[i][j];
            if (bias) v += bias[col];
            if (ACT == 1) v = softplusf_(v);
            float* cp = Cm + (size_t)row * ldc + col;
            if (ACCB) *cp += v; else *cp = v;
        }
    }
}

// ---------------------------------------------------------------------------
__global__ __launch_bounds__(256) void concat_skip(
    const float* __restrict__ skip, float* __restrict__ x0)
{
    int t = blockIdx.x * 256 + (int)threadIdx.x;
    int row = t >> 7;
    int col4 = (t & 127) << 2;
    float4 v = *(const float4*)(skip + (size_t)row * 512 + col4);
    *(float4*)(x0 + (size_t)row * 1024 + 512 + col4) = v;
}

__global__ __launch_bounds__(256) void layernorm_k(
    const float* __restrict__ x, float* __restrict__ out,
    const float* __restrict__ w, const float* __restrict__ b)
{
    const int row = blockIdx.x * 4 + ((int)threadIdx.x >> 6);
    const int lane = (int)threadIdx.x & 63;
    const float* xr = x + (size_t)row * 512;
    float4 v0 = *(const float4*)(xr + lane * 4);
    float4 v1 = *(const float4*)(xr + 256 + lane * 4);
    float s = v0.x + v0.y + v0.z + v0.w + v1.x + v1.y + v1.z + v1.w;
    float q = v0.x*v0.x + v0.y*v0.y + v0.z*v0.z + v0.w*v0.w
            + v1.x*v1.x + v1.y*v1.y + v1.z*v1.z + v1.w*v1.w;
#pragma unroll
    for (int o = 32; o; o >>= 1) {
        s += __shfl_xor(s, o, 64);
        q += __shfl_xor(q, o, 64);
    }
    const float mean = s * (1.0f / 512.0f);
    const float var = q * (1.0f / 512.0f) - mean * mean;
    const float rstd = rsqrtf(var + EPS);
    float4 w0 = *(const float4*)(w + lane * 4);
    float4 w1 = *(const float4*)(w + 256 + lane * 4);
    float4 b0 = *(const float4*)(b + lane * 4);
    float4 b1 = *(const float4*)(b + 256 + lane * 4);
    float4 o0, o1;
    o0.x = (v0.x - mean) * rstd * w0.x + b0.x;
    o0.y = (v0.y - mean) * rstd * w0.y + b0.y;
    o0.z = (v0.z - mean) * rstd * w0.z + b0.z;
    o0.w = (v0.w - mean) * rstd * w0.w + b0.w;
    o1.x = (v1.x - mean) * rstd * w1.x + b1.x;
    o1.y = (v1.y - mean) * rstd * w1.y + b1.y;
    o1.z = (v1.z - mean) * rstd * w1.z + b1.z;
    o1.w = (v1.w - mean) * rstd * w1.w + b1.w;
    float* orow = out + (size_t)row * 512;
    *(float4*)(orow + lane * 4) = o0;
    *(float4*)(orow + 256 + lane * 4) = o1;
}

__global__ __launch_bounds__(256) void rms_silu_k(
    float* __restrict__ x, const float* __restrict__ w)
{
    const int row = blockIdx.x * 4 + ((int)threadIdx.x >> 6);
    const int lane = (int)threadIdx.x & 63;
    float* xr = x + (size_t)row * 512;
    float4 v0 = *(const float4*)(xr + lane * 4);
    float4 v1 = *(const float4*)(xr + 256 + lane * 4);
    float q = v0.x*v0.x + v0.y*v0.y + v0.z*v0.z + v0.w*v0.w
            + v1.x*v1.x + v1.y*v1.y + v1.z*v1.z + v1.w*v1.w;
#pragma unroll
    for (int o = 32; o; o >>= 1) q += __shfl_xor(q, o, 64);
    const float scale = rsqrtf(q * (1.0f / 512.0f) + EPS);
    float4 w0 = *(const float4*)(w + lane * 4);
    float4 w1 = *(const float4*)(w + 256 + lane * 4);
    float y;
    y = v0.x * scale * w0.x; v0.x = siluf_(y);
    y = v0.y * scale * w0.y; v0.y = siluf_(y);
    y = v0.z * scale * w0.z; v0.z = siluf_(y);
    y = v0.w * scale * w0.w; v0.w = siluf_(y);
    y = v1.x * scale * w1.x; v1.x = siluf_(y);
    y = v1.y * scale * w1.y; v1.y = siluf_(y);
    y = v1.z * scale * w1.z; v1.z = siluf_(y);
    y = v1.w * scale * w1.w; v1.w = siluf_(y);
    *(float4*)(xr + lane * 4) = v0;
    *(float4*)(xr + 256 + lane * 4) = v1;
}

// ---------------------------------------------------------------------------
// Parallel causal depthwise conv(k=4)+bias+silu: xz cols[0,1024) -> ub.
// thread = (b, l-chunk of 128, d); 65536 threads; coalesced in d.
// ---------------------------------------------------------------------------
__global__ __launch_bounds__(256) void conv_silu_k2(
    const float* __restrict__ xz, float* __restrict__ ub,
    const float* __restrict__ cw, const float* __restrict__ cb)
{
    int t = blockIdx.x * 256 + (int)threadIdx.x;
    int d = t & 1023;
    int bc = t >> 10;                // b*8 + chunk
    int b = bc >> 3, ch = bc & 7;
    int l0 = ch * 128;
    float4 w4 = *(const float4*)(cw + (size_t)d * 4);
    float bias = cb[d];
    const float* src = xz + ((size_t)(b * 1024 + l0)) * 2048 + d;
    float* dst = ub + ((size_t)(b * 1024 + l0)) * 1024 + d;
    float x0 = 0.f, x1 = 0.f, x2 = 0.f;
    if (l0 > 0) {
        x0 = src[-(size_t)3 * 2048];
        x1 = src[-(size_t)2 * 2048];
        x2 = src[-(size_t)1 * 2048];
    }
    for (int l = 0; l < 128; ++l) {
        float x3 = src[(size_t)l * 2048];
        float v = fmaf(x0, w4.x, fmaf(x1, w4.y, fmaf(x2, w4.z, fmaf(x3, w4.w, bias))));
        dst[(size_t)l * 1024] = siluf_(v);
        x0 = x1; x1 = x2; x2 = x3;
    }
}

// ---------------------------------------------------------------------------
// Selective scan v2: LDS-staged 64-step chunks, DPP row_ror reduction.
// Block = (b, 16 d's); thread = (dg, n). grid 512 x 256.
// ---------------------------------------------------------------------------
template <int CTRL>
DEV_INLINE float dpp_add(float x) {
    int xi = __builtin_bit_cast(int, x);
    int yi = __builtin_amdgcn_update_dpp(0, xi, CTRL, 0xF, 0xF, false);
    return x + __builtin_bit_cast(float, yi);
}

__global__ __launch_bounds__(256) void scan_k2(
    const float* __restrict__ u,     // (8192,1024)
    float* __restrict__ dty,         // (8192,1024) dt in / y out
    const float* __restrict__ xdbc,  // (8192,64)
    const float* __restrict__ A_log, // (1024,16)
    const float* __restrict__ Dp)    // (1024)
{
    __shared__ float dt_s[64][20], u_s[64][20], B_s[64][20], C_s[64][20];
    __shared__ float y_s[64][20];
    const int b = (int)blockIdx.x >> 6;
    const int dblk = ((int)blockIdx.x & 63) << 4;
    const int tid = (int)threadIdx.x;
    const int dg = tid >> 4;
    const int n = tid & 15;
    const float An = -__expf(A_log[(size_t)(dblk + dg) * 16 + n]);
    const float Dv = Dp[dblk + dg];
    const int sr = tid >> 2;          // staging row 0..63
    const int sc = (tid & 3) << 2;    // staging col 0,4,8,12
    const size_t mbase = (size_t)b * 1024;

    float4 pdt, pu, pB, pC;
    {   // prefetch chunk 0
        size_t row = mbase + sr;
        pdt = *(const float4*)(dty + row * 1024 + dblk + sc);
        pu  = *(const float4*)(u   + row * 1024 + dblk + sc);
        pB  = *(const float4*)(xdbc + row * 64 + 32 + sc);
        pC  = *(const float4*)(xdbc + row * 64 + 48 + sc);
    }
    float h = 0.0f;
    for (int c = 0; c < 16; ++c) {
        *(float4*)&dt_s[sr][sc] = pdt;
        *(float4*)&u_s[sr][sc]  = pu;
        *(float4*)&B_s[sr][sc]  = pB;
        *(float4*)&C_s[sr][sc]  = pC;
        if (c < 15) {   // issue next-chunk loads early (T14)
            size_t row = mbase + (c + 1) * 64 + sr;
            pdt = *(const float4*)(dty + row * 1024 + dblk + sc);
            pu  = *(const float4*)(u   + row * 1024 + dblk + sc);
            pB  = *(const float4*)(xdbc + row * 64 + 32 + sc);
            pC  = *(const float4*)(xdbc + row * 64 + 48 + sc);
        }
        __syncthreads();
        for (int l = 0; l < 64; ++l) {
            float dt = dt_s[l][dg];
            float uu = u_s[l][dg];
            float Bv = B_s[l][n];
            float Cv = C_s[l][n];
            float dA = __expf(dt * An);
            h = fmaf(dA, h, dt * uu * Bv);
            float p = h * Cv;
            p = dpp_add<0x128>(p);   // row_ror:8
            p = dpp_add<0x124>(p);   // row_ror:4
            p = dpp_add<0x122>(p);   // row_ror:2
            p = dpp_add<0x121>(p);   // row_ror:1
            if (n == 0) y_s[l][dg] = p + uu * Dv;
        }
        __syncthreads();
        float4 yv = *(const float4*)&y_s[sr][sc];
        *(float4*)(dty + (mbase + c * 64 + sr) * 1024 + dblk + sc) = yv;
    }
}

// ---------------------------------------------------------------------------
// Gate: y *= silu(z), in place on dty (f32)
// ---------------------------------------------------------------------------
__global__ __launch_bounds__(256) void gate_k(
    float* __restrict__ y, const float* __restrict__ xz)
{
    int t = blockIdx.x * 256 + (int)threadIdx.x;
    int m = t >> 8;
    int d4 = (t & 255) << 2;
    float4 yv = *(const float4*)(y + (size_t)m * 1024 + d4);
    float4 zv = *(const float4*)(xz + (size_t)m * 2048 + 1024 + d4);
    yv.x *= siluf_(zv.x);
    yv.y *= siluf_(zv.y);
    yv.z *= siluf_(zv.z);
    yv.w *= siluf_(zv.w);
    *(float4*)(y + (size_t)m * 1024 + d4) = yv;
}

// ---------------------------------------------------------------------------
extern "C" void kernel_launch(void* const* d_in, const int* in_sizes, int n_in,
                              void* d_out, int out_size, void* d_ws, size_t ws_size,
                              hipStream_t stream)
{
    const float* motion     = (const float*)d_in[0];
    const float* skip       = (const float*)d_in[1];
    const float* embed      = (const float*)d_in[2];
    const float* w_up       = (const float*)d_in[3];
    const float* b_up       = (const float*)d_in[4];
    const float* w1         = (const float*)d_in[5];
    const float* b1         = (const float*)d_in[6];
    const float* rms_w      = (const float*)d_in[7];
    const float* w2         = (const float*)d_in[8];
    const float* b2         = (const float*)d_in[9];
    const float* ln_w       = (const float*)d_in[10];
    const float* ln_b       = (const float*)d_in[11];
    const float* in_proj_w  = (const float*)d_in[12];
    const float* conv_w     = (const float*)d_in[13];
    const float* conv_b     = (const float*)d_in[14];
    const float* x_proj_w   = (const float*)d_in[15];
    const float* dt_proj_w  = (const float*)d_in[16];
    const float* dt_proj_b  = (const float*)d_in[17];
    const float* A_log      = (const float*)d_in[18];
    const float* D_param    = (const float*)d_in[19];
    const float* out_proj_w = (const float*)d_in[20];
    const float* out_proj_b = (const float*)d_in[21];
    const float* norm_f_w   = (const float*)d_in[22];
    const float* norm_f_b   = (const float*)d_in[23];
    float* out = (float*)d_out;
    float* ws = (float*)d_ws;

    // Workspace (floats):
    float* xbuf = ws;                     // 4M   (8192x512)  persistent x
    float* R1   = ws + 4194304;           // 8M   xln (stage2/3+LN) / dty
    float* xz   = ws + 12582912;          // 16M  (8192x2048)
    float* R2   = ws + 29360128;          // 8M   x0 (8192x1024) / u_buf
    float* xdbc = ws + 37748736;          // 512K (8192x64)
    unsigned short* warena = (unsigned short*)(ws + 38273024); // 1M bf16
    float* xln = R1;
    float* dty = R1;
    float* x0  = R2;
    float* ub  = R2;

    dim3 blk(256);

    // --- Stage 1: upsample (MFMA) + concat ---
    transpose_wup_bf<<<dim3(1024), blk, 0, stream>>>(w_up, warena);
    for (int k = 0; k < 2; ++k) {
        gemm_mfma<false, false><<<dim3(4, 32), blk, 0, stream>>>(
            motion, 512, warena + (size_t)k * 262144, 512,
            x0 + (size_t)k * 1024, 2048, 512, 512, b_up, nullptr);
    }
    concat_skip<<<dim3(4096), blk, 0, stream>>>(skip, x0);

    // --- Stage 2: xln = x0 @ w1^T + b1 ; rmsnorm+silu in place ---
    cvt_bf16<<<dim3(256), blk, 0, stream>>>(w1, warena, 65536);
    gemm_mfma<false, false><<<dim3(4, 64), blk, 0, stream>>>(
        x0, 1024, warena, 1024, xln, 512, 512, 1024, b1, nullptr);
    rms_silu_k<<<dim3(2048), blk, 0, stream>>>(xln, rms_w);

    // --- Stage 3: xbuf = xln @ w2^T + b2 + embed ---
    cvt_bf16<<<dim3(128), blk, 0, stream>>>(w2, warena, 32768);
    gemm_mfma<false, true><<<dim3(4, 64), blk, 0, stream>>>(
        xln, 512, warena, 512, xbuf, 512, 512, 512, b2, embed);

    // --- Mamba blocks ---
    for (int i = 0; i < 4; ++i) {
        layernorm_k<<<dim3(2048), blk, 0, stream>>>(
            xbuf, xln, ln_w + (size_t)i * 512, ln_b + (size_t)i * 512);
        // xz = xln @ in_proj^T
        cvt_bf16<<<dim3(512), blk, 0, stream>>>(
            in_proj_w + (size_t)i * 1048576, warena, 131072);
        gemm_mfma<false, false><<<dim3(16, 64), blk, 0, stream>>>(
            xln, 512, warena, 512, xz, 2048, 2048, 512, nullptr, nullptr);
        // conv + silu -> ub
        conv_silu_k2<<<dim3(256), blk, 0, stream>>>(
            xz, ub, conv_w + (size_t)i * 4096, conv_b + (size_t)i * 1024);
        // xdbc = xc @ x_proj^T  (fp32, N=64)
        gemm_tn<0, false><<<dim3(1, 128), blk, 0, stream>>>(
            ub, 1024, x_proj_w + (size_t)i * 65536, 1024,
            xdbc, 64, 64, 1024, nullptr);
        // dt = softplus(dtp @ dt_proj^T + dtb)  (fp32, K=32) -> dty
        gemm_tn<1, false><<<dim3(16, 128), blk, 0, stream>>>(
            xdbc, 64, dt_proj_w + (size_t)i * 32768, 32,
            dty, 1024, 1024, 32, dt_proj_b + (size_t)i * 1024);
        // selective scan (y in place over dt)
        scan_k2<<<dim3(512), blk, 0, stream>>>(
            ub, dty, xdbc, A_log + (size_t)i * 16384, D_param + (size_t)i * 1024);
        // y *= silu(z)
        gate_k<<<dim3(8192), blk, 0, stream>>>(dty, xz);
        // xbuf += y @ out_proj^T + ob
        cvt_bf16<<<dim3(256), blk, 0, stream>>>(
            out_proj_w + (size_t)i * 524288, warena, 65536);
        gemm_mfma<true, false><<<dim3(4, 64), blk, 0, stream>>>(
            dty, 1024, warena, 1024, xbuf, 512, 512, 1024,
            out_proj_b + (size_t)i * 512, nullptr);
    }

    // --- Final layernorm -> out ---
    layernorm_k<<<dim3(2048), blk, 0, stream>>>(xbuf, out, norm_f_w, norm_f_b);
}

// Round 3
// 1293.569 us; speedup vs baseline: 3.6539x; 1.1811x over previous
//
#include <hip/hip_runtime.h>
#include <cstdint>
#include <cstddef>

#define DEV_INLINE __device__ __forceinline__

static constexpr float EPS = 1e-5f;

DEV_INLINE float sigmoidf_(float x) { return 1.0f / (1.0f + __expf(-x)); }
DEV_INLINE float siluf_(float x) { return x * sigmoidf_(x); }
DEV_INLINE float softplusf_(float x) {
    return fmaxf(x, 0.0f) + log1pf(__expf(-fabsf(x)));
}
DEV_INLINE unsigned short f2bf(float x) {   // RNE f32 -> bf16
    unsigned u = __builtin_bit_cast(unsigned, x);
    u += 0x7FFFu + ((u >> 16) & 1u);
    return (unsigned short)(u >> 16);
}
DEV_INLINE float bf2f(unsigned short s) {
    unsigned u = ((unsigned)s) << 16;
    return __builtin_bit_cast(float, u);
}

typedef __attribute__((ext_vector_type(8))) short bf16x8;
typedef __attribute__((ext_vector_type(4))) float f32x4;

DEV_INLINE void gload16(const unsigned short* src, char* ldsdst) {
    __builtin_amdgcn_global_load_lds(
        (const __attribute__((address_space(1))) unsigned int*)src,
        (__attribute__((address_space(3))) unsigned int*)ldsdst, 16, 0, 0);
}

DEV_INLINE void cvt8(const float* __restrict__ s, unsigned short* __restrict__ d, int t) {
    float4 f0 = *(const float4*)(s + (size_t)t * 8);
    float4 f1 = *(const float4*)(s + (size_t)t * 8 + 4);
    union { unsigned short u[8]; uint4 v; } pk;
    pk.u[0] = f2bf(f0.x); pk.u[1] = f2bf(f0.y); pk.u[2] = f2bf(f0.z); pk.u[3] = f2bf(f0.w);
    pk.u[4] = f2bf(f1.x); pk.u[5] = f2bf(f1.y); pk.u[6] = f2bf(f1.z); pk.u[7] = f2bf(f1.w);
    *(uint4*)(d + (size_t)t * 8) = pk.v;
}

// ---------------------------------------------------------------------------
__global__ __launch_bounds__(256) void cvt_bf16(
    const float* __restrict__ s, unsigned short* __restrict__ d, int n8)
{
    int t = blockIdx.x * 256 + (int)threadIdx.x;
    if (t >= n8) return;
    cvt8(s, d, t);
}

// w_up (512,512,2) f32 -> wt bf16 [k][o][c]
__global__ __launch_bounds__(256) void transpose_wup_bf(
    const float* __restrict__ wup, unsigned short* __restrict__ wt)
{
    int t = blockIdx.x * 256 + (int)threadIdx.x;   // t = c*512 + o
    if (t >= 512 * 512) return;
    int c = t >> 9, o = t & 511;
    float2 v = *(const float2*)(wup + (size_t)t * 2);
    wt[(size_t)o * 512 + c] = f2bf(v.x);
    wt[262144 + (size_t)o * 512 + c] = f2bf(v.y);
}

// ---------------------------------------------------------------------------
// Per-mamba-block weight prep (one launch): W_dt composite + 3 bf16 converts.
// grid = 4096 (wdt) + 512 (in_proj) + 256 (out_proj) + 16 (xp_bc) = 4880
// ---------------------------------------------------------------------------
__global__ __launch_bounds__(256) void prep_w(
    const float* __restrict__ in_proj_w,   // (2048,512)
    const float* __restrict__ out_proj_w,  // (512,1024)
    const float* __restrict__ x_proj_w,    // (64,1024)
    const float* __restrict__ dt_proj_w,   // (1024,32)
    unsigned short* __restrict__ ipw,
    unsigned short* __restrict__ opw,
    unsigned short* __restrict__ xpb,
    unsigned short* __restrict__ wdt)
{
    int bid = (int)blockIdx.x, tid = (int)threadIdx.x;
    if (bid < 4096) {
        // wdt[d][j] = sum_{r<32} dtw[d][r] * xpw[r][j]
        int t = bid * 256 + tid;
        int dd = t >> 10, j = t & 1023;
        const float* dr = dt_proj_w + (size_t)dd * 32;
        float acc = 0.0f;
#pragma unroll 8
        for (int r = 0; r < 32; ++r)
            acc = fmaf(dr[r], x_proj_w[(size_t)r * 1024 + j], acc);
        wdt[t] = f2bf(acc);
    } else if (bid < 4608) {
        cvt8(in_proj_w, ipw, (bid - 4096) * 256 + tid);
    } else if (bid < 4864) {
        cvt8(out_proj_w, opw, (bid - 4608) * 256 + tid);
    } else {
        cvt8(x_proj_w + 32768, xpb, (bid - 4864) * 256 + tid);  // rows 32..63
    }
}

// ---------------------------------------------------------------------------
// MFMA GEMM: C[M,N] (+)= A[M,K] * W_bf16[N,K]^T  (+bias +embed, ACT=softplus)
// BM=BN=128, BK=64, 4 waves. ABF: A is bf16 (global_load_lds path), else f32.
// ---------------------------------------------------------------------------
template <int ACT, bool ACC, bool EMBED, bool ABF>
__global__ __launch_bounds__(256) void gemm_mfma(
    const void* __restrict__ Av, int lda,
    const unsigned short* __restrict__ W, int ldw,
    float* __restrict__ C, int ldc, int N, int K,
    const float* __restrict__ bias, const float* __restrict__ embed)
{
    __shared__ unsigned short Asm[128 * 64];
    __shared__ unsigned short Wsm[128 * 64];
    const int tid = (int)threadIdx.x;
    const int lane = tid & 63;
    const int wv = tid >> 6;
    const int wm = wv >> 1, wn = wv & 1;
    const int bm = blockIdx.y * 128, bn = blockIdx.x * 128;

    f32x4 acc[4][4] = {};

    const int ar = tid >> 3;      // f32 path: row-in-32, chunk
    const int ac = tid & 7;
    const int l8 = lane >> 3;     // gload path
    const int wc = lane & 7;
    const int wcg = wc ^ l8;

    char* aB = (char*)Asm;
    char* bB = (char*)Wsm;

    for (int k0 = 0; k0 < K; k0 += 64) {
        // ---- stage W via async global->LDS, pre-swizzled source ----
#pragma unroll
        for (int i = 0; i < 4; ++i) {
            int rb = (i * 4 + wv) * 8;
            gload16(W + (size_t)(bn + rb + l8) * ldw + k0 + wcg * 8, bB + rb * 128);
        }
        if (ABF) {
            const unsigned short* A = (const unsigned short*)Av;
#pragma unroll
            for (int i = 0; i < 4; ++i) {
                int rb = (i * 4 + wv) * 8;
                gload16(A + (size_t)(bm + rb + l8) * lda + k0 + wcg * 8, aB + rb * 128);
            }
        } else {
            const float* A = (const float*)Av;
#pragma unroll
            for (int i = 0; i < 4; ++i) {
                int row = i * 32 + ar;
                int cg = ac ^ (row & 7);
                const float* s = A + (size_t)(bm + row) * lda + k0 + cg * 8;
                float4 f0 = *(const float4*)s;
                float4 f1 = *(const float4*)(s + 4);
                union { bf16x8 v; unsigned short u[8]; } pk;
                pk.u[0] = f2bf(f0.x); pk.u[1] = f2bf(f0.y);
                pk.u[2] = f2bf(f0.z); pk.u[3] = f2bf(f0.w);
                pk.u[4] = f2bf(f1.x); pk.u[5] = f2bf(f1.y);
                pk.u[6] = f2bf(f1.z); pk.u[7] = f2bf(f1.w);
                *(bf16x8*)(aB + row * 128 + ac * 16) = pk.v;
            }
        }
        __syncthreads();

        const int rA = wm * 64 + (lane & 15);
        const int rB = wn * 64 + (lane & 15);
        const int q = lane >> 4;
#pragma unroll
        for (int kk = 0; kk < 2; ++kk) {
            bf16x8 af[4], bfr[4];
#pragma unroll
            for (int mi = 0; mi < 4; ++mi) {
                int row = rA + mi * 16;
                int ch = (kk * 4 + q) ^ (row & 7);
                af[mi] = *(const bf16x8*)(aB + row * 128 + ch * 16);
            }
#pragma unroll
            for (int ni = 0; ni < 4; ++ni) {
                int row = rB + ni * 16;
                int ch = (kk * 4 + q) ^ (row & 7);
                bfr[ni] = *(const bf16x8*)(bB + row * 128 + ch * 16);
            }
#pragma unroll
            for (int mi = 0; mi < 4; ++mi)
#pragma unroll
                for (int ni = 0; ni < 4; ++ni)
                    acc[mi][ni] = __builtin_amdgcn_mfma_f32_16x16x32_bf16(
                        af[mi], bfr[ni], acc[mi][ni], 0, 0, 0);
        }
        __syncthreads();
    }

    const int cn = lane & 15;
    const int r0 = (lane >> 4) * 4;
    const int eb = EMBED ? (bm >> 10) * N : 0;
#pragma unroll
    for (int ni = 0; ni < 4; ++ni) {
        int col = bn + wn * 64 + ni * 16 + cn;
        float add = bias ? bias[col] : 0.0f;
        if (EMBED) add += embed[eb + col];
#pragma unroll
        for (int mi = 0; mi < 4; ++mi) {
#pragma unroll
            for (int r = 0; r < 4; ++r) {
                int row = bm + wm * 64 + mi * 16 + r0 + r;
                float v = acc[mi][ni][r] + add;
                if (ACT == 1) v = softplusf_(v);
                float* p = C + (size_t)row * ldc + col;
                if (ACC) *p += v; else *p = v;
            }
        }
    }
}

// ---------------------------------------------------------------------------
// Skinny MFMA GEMM for B/C: C[M,32] = A_bf16[M,1024] * W_bf16[32,1024]^T
// BM=64, BN=32, BK=64, 128 threads (2 waves), grid = M/64.
// ---------------------------------------------------------------------------
__global__ __launch_bounds__(128) void gemm_bc(
    const unsigned short* __restrict__ A,
    const unsigned short* __restrict__ W,
    float* __restrict__ C)
{
    __shared__ unsigned short Asm[64 * 64];
    __shared__ unsigned short Wsm[32 * 64];
    const int tid = (int)threadIdx.x;
    const int lane = tid & 63;
    const int w = tid >> 6;
    const int bm = blockIdx.x * 64;
    const int l8 = lane >> 3, wc = lane & 7, wcg = wc ^ l8;
    char* aB = (char*)Asm;
    char* bB = (char*)Wsm;

    f32x4 acc[2][2] = {};

    for (int k0 = 0; k0 < 1024; k0 += 64) {
#pragma unroll
        for (int i = 0; i < 4; ++i) {
            int rb = (i * 2 + w) * 8;
            gload16(A + (size_t)(bm + rb + l8) * 1024 + k0 + wcg * 8, aB + rb * 128);
        }
#pragma unroll
        for (int i = 0; i < 2; ++i) {
            int rb = (i * 2 + w) * 8;
            gload16(W + (size_t)(rb + l8) * 1024 + k0 + wcg * 8, bB + rb * 128);
        }
        __syncthreads();
        const int rA = w * 32 + (lane & 15);
        const int rB = (lane & 15);
        const int q = lane >> 4;
#pragma unroll
        for (int kk = 0; kk < 2; ++kk) {
            bf16x8 af[2], bfr[2];
#pragma unroll
            for (int mi = 0; mi < 2; ++mi) {
                int row = rA + mi * 16;
                int ch = (kk * 4 + q) ^ (row & 7);
                af[mi] = *(const bf16x8*)(aB + row * 128 + ch * 16);
            }
#pragma unroll
            for (int ni = 0; ni < 2; ++ni) {
                int row = rB + ni * 16;
                int ch = (kk * 4 + q) ^ (row & 7);
                bfr[ni] = *(const bf16x8*)(bB + row * 128 + ch * 16);
            }
#pragma unroll
            for (int mi = 0; mi < 2; ++mi)
#pragma unroll
                for (int ni = 0; ni < 2; ++ni)
                    acc[mi][ni] = __builtin_amdgcn_mfma_f32_16x16x32_bf16(
                        af[mi], bfr[ni], acc[mi][ni], 0, 0, 0);
        }
        __syncthreads();
    }
    const int cn = lane & 15;
    const int r0 = (lane >> 4) * 4;
#pragma unroll
    for (int mi = 0; mi < 2; ++mi)
#pragma unroll
        for (int ni = 0; ni < 2; ++ni)
#pragma unroll
            for (int r = 0; r < 4; ++r) {
                int row = bm + w * 32 + mi * 16 + r0 + r;
                C[(size_t)row * 32 + ni * 16 + cn] = acc[mi][ni][r];
            }
}

// ---------------------------------------------------------------------------
__global__ __launch_bounds__(256) void concat_skip(
    const float* __restrict__ skip, float* __restrict__ x0)
{
    int t = blockIdx.x * 256 + (int)threadIdx.x;
    int row = t >> 7;
    int col4 = (t & 127) << 2;
    float4 v = *(const float4*)(skip + (size_t)row * 512 + col4);
    *(float4*)(x0 + (size_t)row * 1024 + 512 + col4) = v;
}

// ---------------------------------------------------------------------------
// LayerNorm, f32 out (final) and bf16 out (mamba pre-norm)
// ---------------------------------------------------------------------------
template <bool BFOUT>
__global__ __launch_bounds__(256) void layernorm_k(
    const float* __restrict__ x, void* __restrict__ outp,
    const float* __restrict__ w, const float* __restrict__ b)
{
    const int row = blockIdx.x * 4 + ((int)threadIdx.x >> 6);
    const int lane = (int)threadIdx.x & 63;
    const float* xr = x + (size_t)row * 512;
    float4 v0 = *(const float4*)(xr + lane * 4);
    float4 v1 = *(const float4*)(xr + 256 + lane * 4);
    float s = v0.x + v0.y + v0.z + v0.w + v1.x + v1.y + v1.z + v1.w;
    float q = v0.x*v0.x + v0.y*v0.y + v0.z*v0.z + v0.w*v0.w
            + v1.x*v1.x + v1.y*v1.y + v1.z*v1.z + v1.w*v1.w;
#pragma unroll
    for (int o = 32; o; o >>= 1) {
        s += __shfl_xor(s, o, 64);
        q += __shfl_xor(q, o, 64);
    }
    const float mean = s * (1.0f / 512.0f);
    const float var = q * (1.0f / 512.0f) - mean * mean;
    const float rstd = rsqrtf(var + EPS);
    float4 w0 = *(const float4*)(w + lane * 4);
    float4 w1 = *(const float4*)(w + 256 + lane * 4);
    float4 b0 = *(const float4*)(b + lane * 4);
    float4 b1 = *(const float4*)(b + 256 + lane * 4);
    float4 o0, o1;
    o0.x = (v0.x - mean) * rstd * w0.x + b0.x;
    o0.y = (v0.y - mean) * rstd * w0.y + b0.y;
    o0.z = (v0.z - mean) * rstd * w0.z + b0.z;
    o0.w = (v0.w - mean) * rstd * w0.w + b0.w;
    o1.x = (v1.x - mean) * rstd * w1.x + b1.x;
    o1.y = (v1.y - mean) * rstd * w1.y + b1.y;
    o1.z = (v1.z - mean) * rstd * w1.z + b1.z;
    o1.w = (v1.w - mean) * rstd * w1.w + b1.w;
    if (BFOUT) {
        unsigned short* ob = (unsigned short*)outp + (size_t)row * 512;
        union { unsigned short u[4]; uint2 v; } p0, p1;
        p0.u[0] = f2bf(o0.x); p0.u[1] = f2bf(o0.y); p0.u[2] = f2bf(o0.z); p0.u[3] = f2bf(o0.w);
        p1.u[0] = f2bf(o1.x); p1.u[1] = f2bf(o1.y); p1.u[2] = f2bf(o1.z); p1.u[3] = f2bf(o1.w);
        *(uint2*)(ob + lane * 4) = p0.v;
        *(uint2*)(ob + 256 + lane * 4) = p1.v;
    } else {
        float* orow = (float*)outp + (size_t)row * 512;
        *(float4*)(orow + lane * 4) = o0;
        *(float4*)(orow + 256 + lane * 4) = o1;
    }
}

__global__ __launch_bounds__(256) void rms_silu_k(
    float* __restrict__ x, const float* __restrict__ w)
{
    const int row = blockIdx.x * 4 + ((int)threadIdx.x >> 6);
    const int lane = (int)threadIdx.x & 63;
    float* xr = x + (size_t)row * 512;
    float4 v0 = *(const float4*)(xr + lane * 4);
    float4 v1 = *(const float4*)(xr + 256 + lane * 4);
    float q = v0.x*v0.x + v0.y*v0.y + v0.z*v0.z + v0.w*v0.w
            + v1.x*v1.x + v1.y*v1.y + v1.z*v1.z + v1.w*v1.w;
#pragma unroll
    for (int o = 32; o; o >>= 1) q += __shfl_xor(q, o, 64);
    const float scale = rsqrtf(q * (1.0f / 512.0f) + EPS);
    float4 w0 = *(const float4*)(w + lane * 4);
    float4 w1 = *(const float4*)(w + 256 + lane * 4);
    float y;
    y = v0.x * scale * w0.x; v0.x = siluf_(y);
    y = v0.y * scale * w0.y; v0.y = siluf_(y);
    y = v0.z * scale * w0.z; v0.z = siluf_(y);
    y = v0.w * scale * w0.w; v0.w = siluf_(y);
    y = v1.x * scale * w1.x; v1.x = siluf_(y);
    y = v1.y * scale * w1.y; v1.y = siluf_(y);
    y = v1.z * scale * w1.z; v1.z = siluf_(y);
    y = v1.w * scale * w1.w; v1.w = siluf_(y);
    *(float4*)(xr + lane * 4) = v0;
    *(float4*)(xr + 256 + lane * 4) = v1;
}

// ---------------------------------------------------------------------------
// Causal depthwise conv(k=4)+bias+silu: xz cols[0,1024) -> u_bf (bf16).
// thread = (b, l-chunk of 64, d); grid 512.
// ---------------------------------------------------------------------------
__global__ __launch_bounds__(256) void conv_silu_k2(
    const float* __restrict__ xz, unsigned short* __restrict__ ub,
    const float* __restrict__ cw, const float* __restrict__ cb)
{
    int t = blockIdx.x * 256 + (int)threadIdx.x;
    int d = t & 1023;
    int bc = t >> 10;                // b*16 + chunk
    int b = bc >> 4, ch = bc & 15;
    int l0 = ch * 64;
    float4 w4 = *(const float4*)(cw + (size_t)d * 4);
    float bias = cb[d];
    const float* src = xz + ((size_t)(b * 1024 + l0)) * 2048 + d;
    unsigned short* dst = ub + ((size_t)(b * 1024 + l0)) * 1024 + d;
    float x0 = 0.f, x1 = 0.f, x2 = 0.f;
    if (l0 > 0) {
        x0 = src[-(size_t)3 * 2048];
        x1 = src[-(size_t)2 * 2048];
        x2 = src[-(size_t)1 * 2048];
    }
    for (int l = 0; l < 64; ++l) {
        float x3 = src[(size_t)l * 2048];
        float v = fmaf(x0, w4.x, fmaf(x1, w4.y, fmaf(x2, w4.z, fmaf(x3, w4.w, bias))));
        dst[(size_t)l * 1024] = f2bf(siluf_(v));
        x0 = x1; x1 = x2; x2 = x3;
    }
}

// ---------------------------------------------------------------------------
// Split-L selective scan. 8 chunks of 128 steps.
// PHASE 1: per-chunk (h_out, prod dA) -> hp.  PHASE 2: exact scan from
// combined h_in, y = (sum_n h C) + u*D, fused gate y*silu(z), bf16 out.
// Block = (b, chunk, 16 d's); thread = (dg, n); grid 4096.
// ---------------------------------------------------------------------------
template <int CTRL>
DEV_INLINE float dpp_add(float x) {
    int xi = __builtin_bit_cast(int, x);
    int yi = __builtin_amdgcn_update_dpp(0, xi, CTRL, 0xF, 0xF, false);
    return x + __builtin_bit_cast(float, yi);
}

template <int PHASE>
__global__ __launch_bounds__(256) void scan3(
    const float* __restrict__ dtp,        // (8192,1024) dt
    const unsigned short* ubf,            // (8192,1024) u bf16 (aliases ybf)
    unsigned short* ybf,                  // phase2 out (gated y)
    const float* __restrict__ bc,         // (8192,32)
    const float* __restrict__ xz,         // z at cols [1024,2048)
    float* __restrict__ hp,               // (8192*8*16) float2 {h,prod}
    const float* __restrict__ A_log,
    const float* __restrict__ Dp)
{
    __shared__ float dtu[128][36];
    __shared__ float BCs[128][36];
    __shared__ float ys[PHASE == 2 ? 128 : 1][20];

    const int g = (int)blockIdx.x & 63;
    const int r = (int)blockIdx.x >> 6;
    const int c = r & 7, b = r >> 3;
    if (PHASE == 1 && c == 7) return;
    const int tid = (int)threadIdx.x;
    const int dg = tid >> 4, n = tid & 15;
    const int dblk = g << 4;
    const int d = dblk + dg;
    const int m0 = b * 1024 + c * 128;

    const float An = -__expf(A_log[(size_t)d * 16 + n]);
    const float Dv = (PHASE == 2) ? Dp[d] : 0.0f;

    // ---- stage dt/u (interleaved) and B/C (interleaved) ----
#pragma unroll
    for (int j = 0; j < 2; ++j) {
        int task = tid + j * 256;
        int row = task >> 2, q = task & 3;
        size_t gr = (size_t)(m0 + row);
        float4 dt4 = *(const float4*)(dtp + gr * 1024 + dblk + q * 4);
        uint2 uu = *(const uint2*)(ubf + gr * 1024 + dblk + q * 4);
        float u0 = bf2f((unsigned short)(uu.x & 0xffff));
        float u1 = bf2f((unsigned short)(uu.x >> 16));
        float u2 = bf2f((unsigned short)(uu.y & 0xffff));
        float u3 = bf2f((unsigned short)(uu.y >> 16));
        float4 lo = {dt4.x, u0, dt4.y, u1};
        float4 hi = {dt4.z, u2, dt4.w, u3};
        *(float4*)&dtu[row][q * 8] = lo;
        *(float4*)&dtu[row][q * 8 + 4] = hi;
        float4 B4 = *(const float4*)(bc + gr * 32 + q * 4);
        float4 C4 = *(const float4*)(bc + gr * 32 + 16 + q * 4);
        float4 blo = {B4.x, C4.x, B4.y, C4.y};
        float4 bhi = {B4.z, C4.z, B4.w, C4.w};
        *(float4*)&BCs[row][q * 8] = blo;
        *(float4*)&BCs[row][q * 8 + 4] = bhi;
    }

    float h = 0.0f, prod = 1.0f;
    if (PHASE == 2) {
        for (int cc = 0; cc < c; ++cc) {
            float2 v = *(const float2*)(hp +
                ((((size_t)b * 1024 + d) * 8 + cc) * 16 + n) * 2);
            h = fmaf(v.y, h, v.x);
        }
    }
    __syncthreads();

    for (int l = 0; l < 128; ++l) {
        float2 du = *(const float2*)&dtu[l][2 * dg];
        float2 bcv = *(const float2*)&BCs[l][2 * n];
        float dA = __expf(du.x * An);
        if (PHASE == 1) prod *= dA;
        h = fmaf(dA, h, du.x * du.y * bcv.x);
        if (PHASE == 2) {
            float p = h * bcv.y;
            p = dpp_add<0x128>(p);   // row_ror:8
            p = dpp_add<0x124>(p);   // row_ror:4
            p = dpp_add<0x122>(p);   // row_ror:2
            p = dpp_add<0x121>(p);   // row_ror:1
            if (n == 0) ys[l][dg] = fmaf(du.y, Dv, p);
        }
    }

    if (PHASE == 1) {
        float2 o = {h, prod};
        *(float2*)(hp + ((((size_t)b * 1024 + d) * 8 + c) * 16 + n) * 2) = o;
    } else {
        __syncthreads();
#pragma unroll
        for (int j = 0; j < 2; ++j) {
            int task = tid + j * 256;
            int row = task >> 2, q = task & 3;
            size_t gr = (size_t)(m0 + row);
            float4 y4 = *(const float4*)&ys[row][q * 4];
            float4 z4 = *(const float4*)(xz + gr * 2048 + 1024 + dblk + q * 4);
            y4.x *= siluf_(z4.x); y4.y *= siluf_(z4.y);
            y4.z *= siluf_(z4.z); y4.w *= siluf_(z4.w);
            union { unsigned short u[4]; uint2 v; } pk;
            pk.u[0] = f2bf(y4.x); pk.u[1] = f2bf(y4.y);
            pk.u[2] = f2bf(y4.z); pk.u[3] = f2bf(y4.w);
            *(uint2*)(ybf + gr * 1024 + dblk + q * 4) = pk.v;
        }
    }
}

// ---------------------------------------------------------------------------
extern "C" void kernel_launch(void* const* d_in, const int* in_sizes, int n_in,
                              void* d_out, int out_size, void* d_ws, size_t ws_size,
                              hipStream_t stream)
{
    const float* motion     = (const float*)d_in[0];
    const float* skip       = (const float*)d_in[1];
    const float* embed      = (const float*)d_in[2];
    const float* w_up       = (const float*)d_in[3];
    const float* b_up       = (const float*)d_in[4];
    const float* w1         = (const float*)d_in[5];
    const float* b1         = (const float*)d_in[6];
    const float* rms_w      = (const float*)d_in[7];
    const float* w2         = (const float*)d_in[8];
    const float* b2         = (const float*)d_in[9];
    const float* ln_w       = (const float*)d_in[10];
    const float* ln_b       = (const float*)d_in[11];
    const float* in_proj_w  = (const float*)d_in[12];
    const float* conv_w     = (const float*)d_in[13];
    const float* conv_b     = (const float*)d_in[14];
    const float* x_proj_w   = (const float*)d_in[15];
    const float* dt_proj_w  = (const float*)d_in[16];
    const float* dt_proj_b  = (const float*)d_in[17];
    const float* A_log      = (const float*)d_in[18];
    const float* D_param    = (const float*)d_in[19];
    const float* out_proj_w = (const float*)d_in[20];
    const float* out_proj_b = (const float*)d_in[21];
    const float* norm_f_w   = (const float*)d_in[22];
    const float* norm_f_b   = (const float*)d_in[23];
    float* out = (float*)d_out;
    float* ws = (float*)d_ws;

    // Workspace (float offsets), total ~149 MB:
    float* xbuf = ws;                               // (8192x512) f32
    float* R1   = ws + 4194304;                     // xln f32 / xln_bf / dty
    float* xz   = ws + 12582912;                    // (8192x2048) f32; x0 = first 8M
    unsigned short* ubf = (unsigned short*)(ws + 29360128);  // (8192x1024) bf16; y after scan
    float* bc   = ws + 33554432;                    // (8192x32) f32
    float* hp   = ws + 33816576;                    // 2M f {h,prod}
    unsigned short* ipw = (unsigned short*)(ws + 35913728);  // 1M bf16 slotA
    unsigned short* wdt = (unsigned short*)(ws + 36438016);  // 1M bf16 slotW
    unsigned short* opw = (unsigned short*)(ws + 36962304);  // 512K bf16 slotB
    unsigned short* xpb = (unsigned short*)(ws + 37224448);  // 32K bf16 slotC

    float* xln = R1;                        // f32 (pre-loop)
    unsigned short* xln_bf = (unsigned short*)R1;
    float* dty = R1;
    float* x0  = xz;                        // (8192x1024), dead after stage2

    dim3 blk(256);

    // --- Stage 1: upsample (MFMA) + concat ---
    transpose_wup_bf<<<dim3(1024), blk, 0, stream>>>(w_up, ipw);
    for (int k = 0; k < 2; ++k) {
        gemm_mfma<0, false, false, false><<<dim3(4, 32), blk, 0, stream>>>(
            motion, 512, ipw + (size_t)k * 262144, 512,
            x0 + (size_t)k * 1024, 2048, 512, 512, b_up, nullptr);
    }
    concat_skip<<<dim3(4096), blk, 0, stream>>>(skip, x0);

    // --- Stage 2: xln = x0 @ w1^T + b1 ; rmsnorm+silu in place ---
    cvt_bf16<<<dim3(256), blk, 0, stream>>>(w1, ipw, 65536);
    gemm_mfma<0, false, false, false><<<dim3(4, 64), blk, 0, stream>>>(
        x0, 1024, ipw, 1024, xln, 512, 512, 1024, b1, nullptr);
    rms_silu_k<<<dim3(2048), blk, 0, stream>>>(xln, rms_w);

    // --- Stage 3: xbuf = xln @ w2^T + b2 + embed ---
    cvt_bf16<<<dim3(128), blk, 0, stream>>>(w2, ipw, 32768);
    gemm_mfma<0, false, true, false><<<dim3(4, 64), blk, 0, stream>>>(
        xln, 512, ipw, 512, xbuf, 512, 512, 512, b2, embed);

    // --- Mamba blocks ---
    for (int i = 0; i < 4; ++i) {
        layernorm_k<true><<<dim3(2048), blk, 0, stream>>>(
            xbuf, xln_bf, ln_w + (size_t)i * 512, ln_b + (size_t)i * 512);
        prep_w<<<dim3(4880), blk, 0, stream>>>(
            in_proj_w + (size_t)i * 1048576, out_proj_w + (size_t)i * 524288,
            x_proj_w + (size_t)i * 65536, dt_proj_w + (size_t)i * 32768,
            ipw, opw, xpb, wdt);
        // xz = xln @ in_proj^T
        gemm_mfma<0, false, false, true><<<dim3(16, 64), blk, 0, stream>>>(
            xln_bf, 512, ipw, 512, xz, 2048, 2048, 512, nullptr, nullptr);
        // conv + silu -> u (bf16)
        conv_silu_k2<<<dim3(512), blk, 0, stream>>>(
            xz, ubf, conv_w + (size_t)i * 4096, conv_b + (size_t)i * 1024);
        // bc = u @ xp_bc^T  (8192x32)
        gemm_bc<<<dim3(128), dim3(128), 0, stream>>>(ubf, xpb, bc);
        // dt = softplus(u @ W_dt^T + dtb) -> dty
        gemm_mfma<1, false, false, true><<<dim3(8, 64), blk, 0, stream>>>(
            ubf, 1024, wdt, 1024, dty, 1024, 1024, 1024,
            dt_proj_b + (size_t)i * 1024, nullptr);
        // selective scan: phase1 (chunk summaries), phase2 (y + gate, bf16)
        scan3<1><<<dim3(4096), blk, 0, stream>>>(
            dty, ubf, nullptr, bc, xz, hp,
            A_log + (size_t)i * 16384, D_param + (size_t)i * 1024);
        scan3<2><<<dim3(4096), blk, 0, stream>>>(
            dty, ubf, ubf, bc, xz, hp,
            A_log + (size_t)i * 16384, D_param + (size_t)i * 1024);
        // xbuf += y @ out_proj^T + ob
        gemm_mfma<0, true, false, true><<<dim3(4, 64), blk, 0, stream>>>(
            ubf, 1024, opw, 1024, xbuf, 512, 512, 1024,
            out_proj_b + (size_t)i * 512, nullptr);
    }

    // --- Final layernorm -> out ---
    layernorm_k<false><<<dim3(2048), blk, 0, stream>>>(xbuf, out, norm_f_w, norm_f_b);
}

// Round 4
// 1205.462 us; speedup vs baseline: 3.9210x; 1.0731x over previous
//
#include <hip/hip_runtime.h>
#include <cstdint>
#include <cstddef>

#define DEV_INLINE __device__ __forceinline__

static constexpr float EPS = 1e-5f;

DEV_INLINE float sigmoidf_(float x) { return 1.0f / (1.0f + __expf(-x)); }
DEV_INLINE float siluf_(float x) { return x * sigmoidf_(x); }
DEV_INLINE float softplusf_(float x) {
    return fmaxf(x, 0.0f) + log1pf(__expf(-fabsf(x)));
}
DEV_INLINE unsigned short f2bf(float x) {   // RNE f32 -> bf16
    unsigned u = __builtin_bit_cast(unsigned, x);
    u += 0x7FFFu + ((u >> 16) & 1u);
    return (unsigned short)(u >> 16);
}
DEV_INLINE float bf2f(unsigned short s) {
    unsigned u = ((unsigned)s) << 16;
    return __builtin_bit_cast(float, u);
}

typedef __attribute__((ext_vector_type(8))) short bf16x8;
typedef __attribute__((ext_vector_type(4))) float f32x4;

DEV_INLINE void gload16(const unsigned short* src, char* ldsdst) {
    __builtin_amdgcn_global_load_lds(
        (const __attribute__((address_space(1))) unsigned int*)src,
        (__attribute__((address_space(3))) unsigned int*)ldsdst, 16, 0, 0);
}

DEV_INLINE void cvt8(const float* __restrict__ s, unsigned short* __restrict__ d, int t) {
    float4 f0 = *(const float4*)(s + (size_t)t * 8);
    float4 f1 = *(const float4*)(s + (size_t)t * 8 + 4);
    union { unsigned short u[8]; uint4 v; } pk;
    pk.u[0] = f2bf(f0.x); pk.u[1] = f2bf(f0.y); pk.u[2] = f2bf(f0.z); pk.u[3] = f2bf(f0.w);
    pk.u[4] = f2bf(f1.x); pk.u[5] = f2bf(f1.y); pk.u[6] = f2bf(f1.z); pk.u[7] = f2bf(f1.w);
    *(uint4*)(d + (size_t)t * 8) = pk.v;
}

// ---------------------------------------------------------------------------
__global__ __launch_bounds__(256) void cvt_bf16(
    const float* __restrict__ s, unsigned short* __restrict__ d, int n8)
{
    int t = blockIdx.x * 256 + (int)threadIdx.x;
    if (t >= n8) return;
    cvt8(s, d, t);
}

// w_up (512,512,2) f32 -> wt bf16 [k][o][c]
__global__ __launch_bounds__(256) void transpose_wup_bf(
    const float* __restrict__ wup, unsigned short* __restrict__ wt)
{
    int t = blockIdx.x * 256 + (int)threadIdx.x;   // t = c*512 + o
    if (t >= 512 * 512) return;
    int c = t >> 9, o = t & 511;
    float2 v = *(const float2*)(wup + (size_t)t * 2);
    wt[(size_t)o * 512 + c] = f2bf(v.x);
    wt[262144 + (size_t)o * 512 + c] = f2bf(v.y);
}

// ---------------------------------------------------------------------------
// Per-mamba-block weight prep: W_dt composite + 3 bf16 converts.
// ---------------------------------------------------------------------------
__global__ __launch_bounds__(256) void prep_w(
    const float* __restrict__ in_proj_w,   // (2048,512)
    const float* __restrict__ out_proj_w,  // (512,1024)
    const float* __restrict__ x_proj_w,    // (64,1024)
    const float* __restrict__ dt_proj_w,   // (1024,32)
    unsigned short* __restrict__ ipw,
    unsigned short* __restrict__ opw,
    unsigned short* __restrict__ xpb,
    unsigned short* __restrict__ wdt)
{
    int bid = (int)blockIdx.x, tid = (int)threadIdx.x;
    if (bid < 4096) {
        int t = bid * 256 + tid;
        int dd = t >> 10, j = t & 1023;
        const float* dr = dt_proj_w + (size_t)dd * 32;
        float acc = 0.0f;
#pragma unroll 8
        for (int r = 0; r < 32; ++r)
            acc = fmaf(dr[r], x_proj_w[(size_t)r * 1024 + j], acc);
        wdt[t] = f2bf(acc);
    } else if (bid < 4608) {
        cvt8(in_proj_w, ipw, (bid - 4096) * 256 + tid);
    } else if (bid < 4864) {
        cvt8(out_proj_w, opw, (bid - 4608) * 256 + tid);
    } else {
        cvt8(x_proj_w + 32768, xpb, (bid - 4864) * 256 + tid);  // rows 32..63
    }
}

// ---------------------------------------------------------------------------
// MFMA GEMM: C[M,N] (+)= A_bf16[M,K] * W_bf16[N,K]^T  (+bias +embed +softplus)
// BM=BN=128, BK=64, 4 waves. Double-buffered LDS (prefetch tile t+1 while
// computing t; one barrier per K-step). 1D grid with XCD-contiguous remap:
// each XCD gets a contiguous stripe of M-panels (A + W L2-resident per XCD).
// OBF: write bf16 output. Requires gridDim.x % 8 == 0.
// ---------------------------------------------------------------------------
template <int ACT, bool ACC, bool EMBED, bool OBF>
__global__ __launch_bounds__(256) void gemm_mfma(
    const unsigned short* __restrict__ A, int lda,
    const unsigned short* __restrict__ W, int ldw,
    void* __restrict__ Cv, int ldc, int N, int K, int gx,
    const float* __restrict__ bias, const float* __restrict__ embed)
{
    __shared__ unsigned short Asm[2][128 * 64];
    __shared__ unsigned short Wsm[2][128 * 64];
    const int tid = (int)threadIdx.x;
    const int lane = tid & 63;
    const int wv = tid >> 6;
    const int wm = wv >> 1, wn = wv & 1;

    // XCD-contiguous bijective remap (nwg % 8 == 0)
    const int nwg = (int)gridDim.x;
    const int lin = (int)blockIdx.x;
    const int logical = (lin & 7) * (nwg >> 3) + (lin >> 3);
    const int by = logical / gx;
    const int bx = logical - by * gx;
    const int bm = by * 128, bn = bx * 128;

    f32x4 acc[4][4] = {};

    const int l8 = lane >> 3;
    const int wc = lane & 7;
    const int wcg = wc ^ l8;           // pre-swizzled source chunk

    const int NT = K >> 6;

    {   // prologue: stage tile 0 into buf 0
        char* aB = (char*)Asm[0];
        char* bB = (char*)Wsm[0];
#pragma unroll
        for (int i = 0; i < 4; ++i) {
            int rb = (i * 4 + wv) * 8;
            gload16(W + (size_t)(bn + rb + l8) * ldw + wcg * 8, bB + rb * 128);
            gload16(A + (size_t)(bm + rb + l8) * lda + wcg * 8, aB + rb * 128);
        }
    }
    __syncthreads();

    for (int t = 0; t < NT; ++t) {
        const int cur = t & 1;
        if (t + 1 < NT) {   // prefetch next tile into other buffer
            const int k1 = (t + 1) << 6;
            char* aB = (char*)Asm[cur ^ 1];
            char* bB = (char*)Wsm[cur ^ 1];
#pragma unroll
            for (int i = 0; i < 4; ++i) {
                int rb = (i * 4 + wv) * 8;
                gload16(W + (size_t)(bn + rb + l8) * ldw + k1 + wcg * 8, bB + rb * 128);
                gload16(A + (size_t)(bm + rb + l8) * lda + k1 + wcg * 8, aB + rb * 128);
            }
        }
        const char* aB = (const char*)Asm[cur];
        const char* bB = (const char*)Wsm[cur];
        const int rA = wm * 64 + (lane & 15);
        const int rB = wn * 64 + (lane & 15);
        const int q = lane >> 4;
#pragma unroll
        for (int kk = 0; kk < 2; ++kk) {
            bf16x8 af[4], bfr[4];
#pragma unroll
            for (int mi = 0; mi < 4; ++mi) {
                int row = rA + mi * 16;
                int ch = (kk * 4 + q) ^ (row & 7);
                af[mi] = *(const bf16x8*)(aB + row * 128 + ch * 16);
            }
#pragma unroll
            for (int ni = 0; ni < 4; ++ni) {
                int row = rB + ni * 16;
                int ch = (kk * 4 + q) ^ (row & 7);
                bfr[ni] = *(const bf16x8*)(bB + row * 128 + ch * 16);
            }
#pragma unroll
            for (int mi = 0; mi < 4; ++mi)
#pragma unroll
                for (int ni = 0; ni < 4; ++ni)
                    acc[mi][ni] = __builtin_amdgcn_mfma_f32_16x16x32_bf16(
                        af[mi], bfr[ni], acc[mi][ni], 0, 0, 0);
        }
        __syncthreads();   // drains prefetch (vmcnt) + protects buffer reuse
    }

    // ---- epilogue: D[m = (lane>>4)*4+r][n = lane&15] ----
    const int cn = lane & 15;
    const int r0 = (lane >> 4) * 4;
    const int eb = EMBED ? (bm >> 10) * N : 0;
#pragma unroll
    for (int ni = 0; ni < 4; ++ni) {
        int col = bn + wn * 64 + ni * 16 + cn;
        float add = bias ? bias[col] : 0.0f;
        if (EMBED) add += embed[eb + col];
#pragma unroll
        for (int mi = 0; mi < 4; ++mi) {
#pragma unroll
            for (int r = 0; r < 4; ++r) {
                int row = bm + wm * 64 + mi * 16 + r0 + r;
                float v = acc[mi][ni][r] + add;
                if (ACT == 1) v = softplusf_(v);
                if (OBF) {
                    ((unsigned short*)Cv)[(size_t)row * ldc + col] = f2bf(v);
                } else {
                    float* p = (float*)Cv + (size_t)row * ldc + col;
                    if (ACC) *p += v; else *p = v;
                }
            }
        }
    }
}

// ---------------------------------------------------------------------------
// Skinny MFMA GEMM for B/C: C[M,32] = A_bf16[M,1024] * W_bf16[32,1024]^T
// ---------------------------------------------------------------------------
__global__ __launch_bounds__(128) void gemm_bc(
    const unsigned short* __restrict__ A,
    const unsigned short* __restrict__ W,
    float* __restrict__ C)
{
    __shared__ unsigned short Asm[64 * 64];
    __shared__ unsigned short Wsm[32 * 64];
    const int tid = (int)threadIdx.x;
    const int lane = tid & 63;
    const int w = tid >> 6;
    const int bm = blockIdx.x * 64;
    const int l8 = lane >> 3, wc = lane & 7, wcg = wc ^ l8;
    char* aB = (char*)Asm;
    char* bB = (char*)Wsm;

    f32x4 acc[2][2] = {};

    for (int k0 = 0; k0 < 1024; k0 += 64) {
#pragma unroll
        for (int i = 0; i < 4; ++i) {
            int rb = (i * 2 + w) * 8;
            gload16(A + (size_t)(bm + rb + l8) * 1024 + k0 + wcg * 8, aB + rb * 128);
        }
#pragma unroll
        for (int i = 0; i < 2; ++i) {
            int rb = (i * 2 + w) * 8;
            gload16(W + (size_t)(rb + l8) * 1024 + k0 + wcg * 8, bB + rb * 128);
        }
        __syncthreads();
        const int rA = w * 32 + (lane & 15);
        const int rB = (lane & 15);
        const int q = lane >> 4;
#pragma unroll
        for (int kk = 0; kk < 2; ++kk) {
            bf16x8 af[2], bfr[2];
#pragma unroll
            for (int mi = 0; mi < 2; ++mi) {
                int row = rA + mi * 16;
                int ch = (kk * 4 + q) ^ (row & 7);
                af[mi] = *(const bf16x8*)(aB + row * 128 + ch * 16);
            }
#pragma unroll
            for (int ni = 0; ni < 2; ++ni) {
                int row = rB + ni * 16;
                int ch = (kk * 4 + q) ^ (row & 7);
                bfr[ni] = *(const bf16x8*)(bB + row * 128 + ch * 16);
            }
#pragma unroll
            for (int mi = 0; mi < 2; ++mi)
#pragma unroll
                for (int ni = 0; ni < 2; ++ni)
                    acc[mi][ni] = __builtin_amdgcn_mfma_f32_16x16x32_bf16(
                        af[mi], bfr[ni], acc[mi][ni], 0, 0, 0);
        }
        __syncthreads();
    }
    const int cn = lane & 15;
    const int r0 = (lane >> 4) * 4;
#pragma unroll
    for (int mi = 0; mi < 2; ++mi)
#pragma unroll
        for (int ni = 0; ni < 2; ++ni)
#pragma unroll
            for (int r = 0; r < 4; ++r) {
                int row = bm + w * 32 + mi * 16 + r0 + r;
                C[(size_t)row * 32 + ni * 16 + cn] = acc[mi][ni][r];
            }
}

// ---------------------------------------------------------------------------
// Concat skip (f32) into x0 bf16 cols [512,1024)
// ---------------------------------------------------------------------------
__global__ __launch_bounds__(256) void concat_skip(
    const float* __restrict__ skip, unsigned short* __restrict__ x0)
{
    int t = blockIdx.x * 256 + (int)threadIdx.x;   // 8192*512/8 tasks
    int row = t >> 6;
    int c8 = (t & 63) << 3;
    const float* s = skip + (size_t)row * 512 + c8;
    float4 f0 = *(const float4*)s;
    float4 f1 = *(const float4*)(s + 4);
    union { unsigned short u[8]; uint4 v; } pk;
    pk.u[0] = f2bf(f0.x); pk.u[1] = f2bf(f0.y); pk.u[2] = f2bf(f0.z); pk.u[3] = f2bf(f0.w);
    pk.u[4] = f2bf(f1.x); pk.u[5] = f2bf(f1.y); pk.u[6] = f2bf(f1.z); pk.u[7] = f2bf(f1.w);
    *(uint4*)(x0 + (size_t)row * 1024 + 512 + c8) = pk.v;
}

// ---------------------------------------------------------------------------
// LayerNorm: BFOUT -> bf16, else f32
// ---------------------------------------------------------------------------
template <bool BFOUT>
__global__ __launch_bounds__(256) void layernorm_k(
    const float* __restrict__ x, void* __restrict__ outp,
    const float* __restrict__ w, const float* __restrict__ b)
{
    const int row = blockIdx.x * 4 + ((int)threadIdx.x >> 6);
    const int lane = (int)threadIdx.x & 63;
    const float* xr = x + (size_t)row * 512;
    float4 v0 = *(const float4*)(xr + lane * 4);
    float4 v1 = *(const float4*)(xr + 256 + lane * 4);
    float s = v0.x + v0.y + v0.z + v0.w + v1.x + v1.y + v1.z + v1.w;
    float q = v0.x*v0.x + v0.y*v0.y + v0.z*v0.z + v0.w*v0.w
            + v1.x*v1.x + v1.y*v1.y + v1.z*v1.z + v1.w*v1.w;
#pragma unroll
    for (int o = 32; o; o >>= 1) {
        s += __shfl_xor(s, o, 64);
        q += __shfl_xor(q, o, 64);
    }
    const float mean = s * (1.0f / 512.0f);
    const float var = q * (1.0f / 512.0f) - mean * mean;
    const float rstd = rsqrtf(var + EPS);
    float4 w0 = *(const float4*)(w + lane * 4);
    float4 w1 = *(const float4*)(w + 256 + lane * 4);
    float4 b0 = *(const float4*)(b + lane * 4);
    float4 b1 = *(const float4*)(b + 256 + lane * 4);
    float4 o0, o1;
    o0.x = (v0.x - mean) * rstd * w0.x + b0.x;
    o0.y = (v0.y - mean) * rstd * w0.y + b0.y;
    o0.z = (v0.z - mean) * rstd * w0.z + b0.z;
    o0.w = (v0.w - mean) * rstd * w0.w + b0.w;
    o1.x = (v1.x - mean) * rstd * w1.x + b1.x;
    o1.y = (v1.y - mean) * rstd * w1.y + b1.y;
    o1.z = (v1.z - mean) * rstd * w1.z + b1.z;
    o1.w = (v1.w - mean) * rstd * w1.w + b1.w;
    if (BFOUT) {
        unsigned short* ob = (unsigned short*)outp + (size_t)row * 512;
        union { unsigned short u[4]; uint2 v; } p0, p1;
        p0.u[0] = f2bf(o0.x); p0.u[1] = f2bf(o0.y); p0.u[2] = f2bf(o0.z); p0.u[3] = f2bf(o0.w);
        p1.u[0] = f2bf(o1.x); p1.u[1] = f2bf(o1.y); p1.u[2] = f2bf(o1.z); p1.u[3] = f2bf(o1.w);
        *(uint2*)(ob + lane * 4) = p0.v;
        *(uint2*)(ob + 256 + lane * 4) = p1.v;
    } else {
        float* orow = (float*)outp + (size_t)row * 512;
        *(float4*)(orow + lane * 4) = o0;
        *(float4*)(orow + 256 + lane * 4) = o1;
    }
}

// rmsnorm + silu: f32 in -> bf16 out
__global__ __launch_bounds__(256) void rms_silu_k(
    const float* __restrict__ x, unsigned short* __restrict__ o,
    const float* __restrict__ w)
{
    const int row = blockIdx.x * 4 + ((int)threadIdx.x >> 6);
    const int lane = (int)threadIdx.x & 63;
    const float* xr = x + (size_t)row * 512;
    float4 v0 = *(const float4*)(xr + lane * 4);
    float4 v1 = *(const float4*)(xr + 256 + lane * 4);
    float q = v0.x*v0.x + v0.y*v0.y + v0.z*v0.z + v0.w*v0.w
            + v1.x*v1.x + v1.y*v1.y + v1.z*v1.z + v1.w*v1.w;
#pragma unroll
    for (int of = 32; of; of >>= 1) q += __shfl_xor(q, of, 64);
    const float scale = rsqrtf(q * (1.0f / 512.0f) + EPS);
    float4 w0 = *(const float4*)(w + lane * 4);
    float4 w1 = *(const float4*)(w + 256 + lane * 4);
    union { unsigned short u[4]; uint2 v; } p0, p1;
    p0.u[0] = f2bf(siluf_(v0.x * scale * w0.x));
    p0.u[1] = f2bf(siluf_(v0.y * scale * w0.y));
    p0.u[2] = f2bf(siluf_(v0.z * scale * w0.z));
    p0.u[3] = f2bf(siluf_(v0.w * scale * w0.w));
    p1.u[0] = f2bf(siluf_(v1.x * scale * w1.x));
    p1.u[1] = f2bf(siluf_(v1.y * scale * w1.y));
    p1.u[2] = f2bf(siluf_(v1.z * scale * w1.z));
    p1.u[3] = f2bf(siluf_(v1.w * scale * w1.w));
    unsigned short* ob = o + (size_t)row * 512;
    *(uint2*)(ob + lane * 4) = p0.v;
    *(uint2*)(ob + 256 + lane * 4) = p1.v;
}

// ---------------------------------------------------------------------------
// Causal depthwise conv(k=4)+bias+silu: xz bf16 cols[0,1024) -> u bf16.
// ---------------------------------------------------------------------------
__global__ __launch_bounds__(256) void conv_silu_k2(
    const unsigned short* __restrict__ xz, unsigned short* __restrict__ ub,
    const float* __restrict__ cw, const float* __restrict__ cb)
{
    int t = blockIdx.x * 256 + (int)threadIdx.x;
    int d = t & 1023;
    int bc = t >> 10;                // b*16 + chunk
    int b = bc >> 4, ch = bc & 15;
    int l0 = ch * 64;
    float4 w4 = *(const float4*)(cw + (size_t)d * 4);
    float bias = cb[d];
    const unsigned short* src = xz + ((size_t)(b * 1024 + l0)) * 2048 + d;
    unsigned short* dst = ub + ((size_t)(b * 1024 + l0)) * 1024 + d;
    float x0 = 0.f, x1 = 0.f, x2 = 0.f;
    if (l0 > 0) {
        x0 = bf2f(src[-(size_t)3 * 2048]);
        x1 = bf2f(src[-(size_t)2 * 2048]);
        x2 = bf2f(src[-(size_t)1 * 2048]);
    }
    for (int l = 0; l < 64; ++l) {
        float x3 = bf2f(src[(size_t)l * 2048]);
        float v = fmaf(x0, w4.x, fmaf(x1, w4.y, fmaf(x2, w4.z, fmaf(x3, w4.w, bias))));
        dst[(size_t)l * 1024] = f2bf(siluf_(v));
        x0 = x1; x1 = x2; x2 = x3;
    }
}

// ---------------------------------------------------------------------------
// Split-L selective scan (8 chunks x 128). dt/u/z bf16; gate fused in p2.
// ---------------------------------------------------------------------------
template <int CTRL>
DEV_INLINE float dpp_add(float x) {
    int xi = __builtin_bit_cast(int, x);
    int yi = __builtin_amdgcn_update_dpp(0, xi, CTRL, 0xF, 0xF, false);
    return x + __builtin_bit_cast(float, yi);
}

template <int PHASE>
__global__ __launch_bounds__(256) void scan3(
    const unsigned short* __restrict__ dtp,  // (8192,1024) bf16 dt
    const unsigned short* ubf,               // (8192,1024) bf16 u (aliases ybf)
    unsigned short* ybf,                     // phase2 out (gated y)
    const float* __restrict__ bc,            // (8192,32)
    const unsigned short* __restrict__ zbf,  // z = xz bf16 cols [1024,2048)
    float* __restrict__ hp,                  // (8192*8*16) float2 {h,prod}
    const float* __restrict__ A_log,
    const float* __restrict__ Dp)
{
    __shared__ float dtu[128][36];
    __shared__ float BCs[128][36];
    __shared__ float ys[PHASE == 2 ? 128 : 1][20];

    const int g = (int)blockIdx.x & 63;
    const int r = (int)blockIdx.x >> 6;
    const int c = r & 7, b = r >> 3;
    if (PHASE == 1 && c == 7) return;
    const int tid = (int)threadIdx.x;
    const int dg = tid >> 4, n = tid & 15;
    const int dblk = g << 4;
    const int d = dblk + dg;
    const int m0 = b * 1024 + c * 128;

    const float An = -__expf(A_log[(size_t)d * 16 + n]);
    const float Dv = (PHASE == 2) ? Dp[d] : 0.0f;

#pragma unroll
    for (int j = 0; j < 2; ++j) {
        int task = tid + j * 256;
        int row = task >> 2, q = task & 3;
        size_t gr = (size_t)(m0 + row);
        uint2 dd = *(const uint2*)(dtp + gr * 1024 + dblk + q * 4);
        uint2 uu = *(const uint2*)(ubf + gr * 1024 + dblk + q * 4);
        float4 lo = {bf2f((unsigned short)(dd.x & 0xffff)),
                     bf2f((unsigned short)(uu.x & 0xffff)),
                     bf2f((unsigned short)(dd.x >> 16)),
                     bf2f((unsigned short)(uu.x >> 16))};
        float4 hi = {bf2f((unsigned short)(dd.y & 0xffff)),
                     bf2f((unsigned short)(uu.y & 0xffff)),
                     bf2f((unsigned short)(dd.y >> 16)),
                     bf2f((unsigned short)(uu.y >> 16))};
        *(float4*)&dtu[row][q * 8] = lo;
        *(float4*)&dtu[row][q * 8 + 4] = hi;
        float4 B4 = *(const float4*)(bc + gr * 32 + q * 4);
        float4 C4 = *(const float4*)(bc + gr * 32 + 16 + q * 4);
        float4 blo = {B4.x, C4.x, B4.y, C4.y};
        float4 bhi = {B4.z, C4.z, B4.w, C4.w};
        *(float4*)&BCs[row][q * 8] = blo;
        *(float4*)&BCs[row][q * 8 + 4] = bhi;
    }

    float h = 0.0f, prod = 1.0f;
    if (PHASE == 2) {
        for (int cc = 0; cc < c; ++cc) {
            float2 v = *(const float2*)(hp +
                ((((size_t)b * 1024 + d) * 8 + cc) * 16 + n) * 2);
            h = fmaf(v.y, h, v.x);
        }
    }
    __syncthreads();

    for (int l = 0; l < 128; ++l) {
        float2 du = *(const float2*)&dtu[l][2 * dg];
        float2 bcv = *(const float2*)&BCs[l][2 * n];
        float dA = __expf(du.x * An);
        if (PHASE == 1) prod *= dA;
        h = fmaf(dA, h, du.x * du.y * bcv.x);
        if (PHASE == 2) {
            float p = h * bcv.y;
            p = dpp_add<0x128>(p);   // row_ror:8
            p = dpp_add<0x124>(p);   // row_ror:4
            p = dpp_add<0x122>(p);   // row_ror:2
            p = dpp_add<0x121>(p);   // row_ror:1
            if (n == 0) ys[l][dg] = fmaf(du.y, Dv, p);
        }
    }

    if (PHASE == 1) {
        float2 o = {h, prod};
        *(float2*)(hp + ((((size_t)b * 1024 + d) * 8 + c) * 16 + n) * 2) = o;
    } else {
        __syncthreads();
#pragma unroll
        for (int j = 0; j < 2; ++j) {
            int task = tid + j * 256;
            int row = task >> 2, q = task & 3;
            size_t gr = (size_t)(m0 + row);
            float4 y4 = *(const float4*)&ys[row][q * 4];
            uint2 zz = *(const uint2*)(zbf + gr * 2048 + 1024 + dblk + q * 4);
            y4.x *= siluf_(bf2f((unsigned short)(zz.x & 0xffff)));
            y4.y *= siluf_(bf2f((unsigned short)(zz.x >> 16)));
            y4.z *= siluf_(bf2f((unsigned short)(zz.y & 0xffff)));
            y4.w *= siluf_(bf2f((unsigned short)(zz.y >> 16)));
            union { unsigned short u[4]; uint2 v; } pk;
            pk.u[0] = f2bf(y4.x); pk.u[1] = f2bf(y4.y);
            pk.u[2] = f2bf(y4.z); pk.u[3] = f2bf(y4.w);
            *(uint2*)(ybf + gr * 1024 + dblk + q * 4) = pk.v;
        }
    }
}

// ---------------------------------------------------------------------------
extern "C" void kernel_launch(void* const* d_in, const int* in_sizes, int n_in,
                              void* d_out, int out_size, void* d_ws, size_t ws_size,
                              hipStream_t stream)
{
    const float* motion     = (const float*)d_in[0];
    const float* skip       = (const float*)d_in[1];
    const float* embed      = (const float*)d_in[2];
    const float* w_up       = (const float*)d_in[3];
    const float* b_up       = (const float*)d_in[4];
    const float* w1         = (const float*)d_in[5];
    const float* b1         = (const float*)d_in[6];
    const float* rms_w      = (const float*)d_in[7];
    const float* w2         = (const float*)d_in[8];
    const float* b2         = (const float*)d_in[9];
    const float* ln_w       = (const float*)d_in[10];
    const float* ln_b       = (const float*)d_in[11];
    const float* in_proj_w  = (const float*)d_in[12];
    const float* conv_w     = (const float*)d_in[13];
    const float* conv_b     = (const float*)d_in[14];
    const float* x_proj_w   = (const float*)d_in[15];
    const float* dt_proj_w  = (const float*)d_in[16];
    const float* dt_proj_b  = (const float*)d_in[17];
    const float* A_log      = (const float*)d_in[18];
    const float* D_param    = (const float*)d_in[19];
    const float* out_proj_w = (const float*)d_in[20];
    const float* out_proj_b = (const float*)d_in[21];
    const float* norm_f_w   = (const float*)d_in[22];
    const float* norm_f_b   = (const float*)d_in[23];
    float* out = (float*)d_out;
    float* ws = (float*)d_ws;

    // Workspace (float offsets), total ~128 MB:
    float* xbuf = ws;                                        // (8192x512) f32
    float* xlnf = ws + 4194304;                              // (8192x512) f32 stage-2 temp
    unsigned short* xzbf  = (unsigned short*)(ws + 8388608); // (8192x2048) bf16
    unsigned short* ubf   = (unsigned short*)(ws + 16777216);// (8192x1024) bf16, u -> y
    unsigned short* dtybf = (unsigned short*)(ws + 20971520);// (8192x1024) bf16 dt
    float* bc  = ws + 25165824;                              // (8192x32) f32
    float* hp  = ws + 25427968;                              // 2M f {h,prod}
    unsigned short* xsbf = (unsigned short*)(ws + 27525120); // (8192x512) bf16 activations
    unsigned short* mbf  = (unsigned short*)(ws + 29622272); // motion bf16 (2M elems)
    unsigned short* ipw  = (unsigned short*)(ws + 30670848); // 1M bf16
    unsigned short* wdt  = (unsigned short*)(ws + 31195136); // 1M bf16
    unsigned short* opw  = (unsigned short*)(ws + 31719424); // 512K bf16
    unsigned short* xpb  = (unsigned short*)(ws + 31981568); // 32K bf16

    unsigned short* x0bf = xzbf;   // (8192x1024) bf16, dead after stage 2

    dim3 blk(256);

    // --- Stage 1: upsample (MFMA, bf16) + concat ---
    cvt_bf16<<<dim3(1024), blk, 0, stream>>>(motion, mbf, 262144);
    transpose_wup_bf<<<dim3(1024), blk, 0, stream>>>(w_up, ipw);
    for (int k = 0; k < 2; ++k) {
        gemm_mfma<0, false, false, true><<<dim3(128), blk, 0, stream>>>(
            mbf, 512, ipw + (size_t)k * 262144, 512,
            x0bf + (size_t)k * 1024, 2048, 512, 512, 4, b_up, nullptr);
    }
    concat_skip<<<dim3(2048), blk, 0, stream>>>(skip, x0bf);

    // --- Stage 2: xlnf = x0 @ w1^T + b1 ; rmsnorm+silu -> xsbf ---
    cvt_bf16<<<dim3(256), blk, 0, stream>>>(w1, ipw, 65536);
    gemm_mfma<0, false, false, false><<<dim3(256), blk, 0, stream>>>(
        x0bf, 1024, ipw, 1024, xlnf, 512, 512, 1024, 4, b1, nullptr);
    rms_silu_k<<<dim3(2048), blk, 0, stream>>>(xlnf, xsbf, rms_w);

    // --- Stage 3: xbuf = xs @ w2^T + b2 + embed ---
    cvt_bf16<<<dim3(128), blk, 0, stream>>>(w2, ipw, 32768);
    gemm_mfma<0, false, true, false><<<dim3(256), blk, 0, stream>>>(
        xsbf, 512, ipw, 512, xbuf, 512, 512, 512, 4, b2, embed);

    // --- Mamba blocks ---
    for (int i = 0; i < 4; ++i) {
        layernorm_k<true><<<dim3(2048), blk, 0, stream>>>(
            xbuf, xsbf, ln_w + (size_t)i * 512, ln_b + (size_t)i * 512);
        prep_w<<<dim3(4880), blk, 0, stream>>>(
            in_proj_w + (size_t)i * 1048576, out_proj_w + (size_t)i * 524288,
            x_proj_w + (size_t)i * 65536, dt_proj_w + (size_t)i * 32768,
            ipw, opw, xpb, wdt);
        // xz = xln @ in_proj^T  (bf16 out)
        gemm_mfma<0, false, false, true><<<dim3(1024), blk, 0, stream>>>(
            xsbf, 512, ipw, 512, xzbf, 2048, 2048, 512, 16, nullptr, nullptr);
        // conv + silu -> u (bf16)
        conv_silu_k2<<<dim3(512), blk, 0, stream>>>(
            xzbf, ubf, conv_w + (size_t)i * 4096, conv_b + (size_t)i * 1024);
        // bc = u @ xp_bc^T  (8192x32, f32)
        gemm_bc<<<dim3(128), dim3(128), 0, stream>>>(ubf, xpb, bc);
        // dt = softplus(u @ W_dt^T + dtb) -> bf16
        gemm_mfma<1, false, false, true><<<dim3(512), blk, 0, stream>>>(
            ubf, 1024, wdt, 1024, dtybf, 1024, 1024, 1024, 8,
            dt_proj_b + (size_t)i * 1024, nullptr);
        // selective scan: phase1 (chunk summaries), phase2 (y + gate, bf16)
        scan3<1><<<dim3(4096), blk, 0, stream>>>(
            dtybf, ubf, nullptr, bc, xzbf, hp,
            A_log + (size_t)i * 16384, D_param + (size_t)i * 1024);
        scan3<2><<<dim3(4096), blk, 0, stream>>>(
            dtybf, ubf, ubf, bc, xzbf, hp,
            A_log + (size_t)i * 16384, D_param + (size_t)i * 1024);
        // xbuf += y @ out_proj^T + ob
        gemm_mfma<0, true, false, false><<<dim3(256), blk, 0, stream>>>(
            ubf, 1024, opw, 1024, xbuf, 512, 512, 1024, 4,
            out_proj_b + (size_t)i * 512, nullptr);
    }

    // --- Final layernorm -> out ---
    layernorm_k<false><<<dim3(2048), blk, 0, stream>>>(xbuf, out, norm_f_w, norm_f_b);
}

// Round 5
// 1077.322 us; speedup vs baseline: 4.3874x; 1.1189x over previous
//
#include <hip/hip_runtime.h>
#include <cstdint>
#include <cstddef>

#define DEV_INLINE __device__ __forceinline__

static constexpr float EPS = 1e-5f;

DEV_INLINE float sigmoidf_(float x) { return 1.0f / (1.0f + __expf(-x)); }
DEV_INLINE float siluf_(float x) { return x * sigmoidf_(x); }
DEV_INLINE float softplusf_(float x) {
    return fmaxf(x, 0.0f) + log1pf(__expf(-fabsf(x)));
}
DEV_INLINE unsigned short f2bf(float x) {   // RNE f32 -> bf16
    unsigned u = __builtin_bit_cast(unsigned, x);
    u += 0x7FFFu + ((u >> 16) & 1u);
    return (unsigned short)(u >> 16);
}
DEV_INLINE float bf2f(unsigned short s) {
    unsigned u = ((unsigned)s) << 16;
    return __builtin_bit_cast(float, u);
}

typedef __attribute__((ext_vector_type(8))) short bf16x8;
typedef __attribute__((ext_vector_type(4))) float f32x4;

DEV_INLINE void gload16(const unsigned short* src, char* ldsdst) {
    __builtin_amdgcn_global_load_lds(
        (const __attribute__((address_space(1))) unsigned int*)src,
        (__attribute__((address_space(3))) unsigned int*)ldsdst, 16, 0, 0);
}

DEV_INLINE void cvt8(const float* __restrict__ s, unsigned short* __restrict__ d, int t) {
    float4 f0 = *(const float4*)(s + (size_t)t * 8);
    float4 f1 = *(const float4*)(s + (size_t)t * 8 + 4);
    union { unsigned short u[8]; uint4 v; } pk;
    pk.u[0] = f2bf(f0.x); pk.u[1] = f2bf(f0.y); pk.u[2] = f2bf(f0.z); pk.u[3] = f2bf(f0.w);
    pk.u[4] = f2bf(f1.x); pk.u[5] = f2bf(f1.y); pk.u[6] = f2bf(f1.z); pk.u[7] = f2bf(f1.w);
    *(uint4*)(d + (size_t)t * 8) = pk.v;
}

// ---------------------------------------------------------------------------
__global__ __launch_bounds__(256) void cvt_bf16(
    const float* __restrict__ s, unsigned short* __restrict__ d, int n8)
{
    int t = blockIdx.x * 256 + (int)threadIdx.x;
    if (t >= n8) return;
    cvt8(s, d, t);
}

// w_up (512,512,2) f32 -> wt bf16 [k][o][c]
__global__ __launch_bounds__(256) void transpose_wup_bf(
    const float* __restrict__ wup, unsigned short* __restrict__ wt)
{
    int t = blockIdx.x * 256 + (int)threadIdx.x;   // t = c*512 + o
    if (t >= 512 * 512) return;
    int c = t >> 9, o = t & 511;
    float2 v = *(const float2*)(wup + (size_t)t * 2);
    wt[(size_t)o * 512 + c] = f2bf(v.x);
    wt[262144 + (size_t)o * 512 + c] = f2bf(v.y);
}

// ---------------------------------------------------------------------------
// Per-mamba-block weight prep: zero-padded dt weight (1024x64) + bf16 converts.
// grid = 256 (wdt64) + 512 (ipw) + 256 (opw) + 32 (xpw full) = 1056
// ---------------------------------------------------------------------------
__global__ __launch_bounds__(256) void prep_w(
    const float* __restrict__ in_proj_w,   // (2048,512)
    const float* __restrict__ out_proj_w,  // (512,1024)
    const float* __restrict__ x_proj_w,    // (64,1024)
    const float* __restrict__ dt_proj_w,   // (1024,32)
    unsigned short* __restrict__ ipw,
    unsigned short* __restrict__ opw,
    unsigned short* __restrict__ xpw,      // (64,1024) bf16
    unsigned short* __restrict__ wdt64)    // (1024,64) bf16, cols 32..63 = 0
{
    int bid = (int)blockIdx.x, tid = (int)threadIdx.x;
    if (bid < 256) {
        int t = bid * 256 + tid;           // t = n*64 + k
        int n = t >> 6, k = t & 63;
        wdt64[t] = (k < 32) ? f2bf(dt_proj_w[(size_t)n * 32 + k]) : (unsigned short)0;
    } else if (bid < 768) {
        cvt8(in_proj_w, ipw, (bid - 256) * 256 + tid);
    } else if (bid < 1024) {
        cvt8(out_proj_w, opw, (bid - 768) * 256 + tid);
    } else {
        cvt8(x_proj_w, xpw, (bid - 1024) * 256 + tid);
    }
}

// ---------------------------------------------------------------------------
// MFMA GEMM: C[M,N] (+)= A_bf16[M,K] * W_bf16[N,K]^T  (+bias +embed +softplus)
// BM=BN=128, BK=64, 4 waves, double-buffered LDS, XCD-contiguous block remap.
// ---------------------------------------------------------------------------
template <int ACT, bool ACC, bool EMBED, bool OBF>
__global__ __launch_bounds__(256) void gemm_mfma(
    const unsigned short* __restrict__ A, int lda,
    const unsigned short* __restrict__ W, int ldw,
    void* __restrict__ Cv, int ldc, int N, int K, int gx,
    const float* __restrict__ bias, const float* __restrict__ embed)
{
    __shared__ unsigned short Asm[2][128 * 64];
    __shared__ unsigned short Wsm[2][128 * 64];
    const int tid = (int)threadIdx.x;
    const int lane = tid & 63;
    const int wv = tid >> 6;
    const int wm = wv >> 1, wn = wv & 1;

    const int nwg = (int)gridDim.x;
    const int lin = (int)blockIdx.x;
    const int logical = (lin & 7) * (nwg >> 3) + (lin >> 3);
    const int by = logical / gx;
    const int bx = logical - by * gx;
    const int bm = by * 128, bn = bx * 128;

    f32x4 acc[4][4] = {};

    const int l8 = lane >> 3;
    const int wc = lane & 7;
    const int wcg = wc ^ l8;

    const int NT = K >> 6;

    {
        char* aB = (char*)Asm[0];
        char* bB = (char*)Wsm[0];
#pragma unroll
        for (int i = 0; i < 4; ++i) {
            int rb = (i * 4 + wv) * 8;
            gload16(W + (size_t)(bn + rb + l8) * ldw + wcg * 8, bB + rb * 128);
            gload16(A + (size_t)(bm + rb + l8) * lda + wcg * 8, aB + rb * 128);
        }
    }
    __syncthreads();

    for (int t = 0; t < NT; ++t) {
        const int cur = t & 1;
        if (t + 1 < NT) {
            const int k1 = (t + 1) << 6;
            char* aB = (char*)Asm[cur ^ 1];
            char* bB = (char*)Wsm[cur ^ 1];
#pragma unroll
            for (int i = 0; i < 4; ++i) {
                int rb = (i * 4 + wv) * 8;
                gload16(W + (size_t)(bn + rb + l8) * ldw + k1 + wcg * 8, bB + rb * 128);
                gload16(A + (size_t)(bm + rb + l8) * lda + k1 + wcg * 8, aB + rb * 128);
            }
        }
        const char* aB = (const char*)Asm[cur];
        const char* bB = (const char*)Wsm[cur];
        const int rA = wm * 64 + (lane & 15);
        const int rB = wn * 64 + (lane & 15);
        const int q = lane >> 4;
#pragma unroll
        for (int kk = 0; kk < 2; ++kk) {
            bf16x8 af[4], bfr[4];
#pragma unroll
            for (int mi = 0; mi < 4; ++mi) {
                int row = rA + mi * 16;
                int ch = (kk * 4 + q) ^ (row & 7);
                af[mi] = *(const bf16x8*)(aB + row * 128 + ch * 16);
            }
#pragma unroll
            for (int ni = 0; ni < 4; ++ni) {
                int row = rB + ni * 16;
                int ch = (kk * 4 + q) ^ (row & 7);
                bfr[ni] = *(const bf16x8*)(bB + row * 128 + ch * 16);
            }
#pragma unroll
            for (int mi = 0; mi < 4; ++mi)
#pragma unroll
                for (int ni = 0; ni < 4; ++ni)
                    acc[mi][ni] = __builtin_amdgcn_mfma_f32_16x16x32_bf16(
                        af[mi], bfr[ni], acc[mi][ni], 0, 0, 0);
        }
        __syncthreads();
    }

    const int cn = lane & 15;
    const int r0 = (lane >> 4) * 4;
    const int eb = EMBED ? (bm >> 10) * N : 0;
#pragma unroll
    for (int ni = 0; ni < 4; ++ni) {
        int col = bn + wn * 64 + ni * 16 + cn;
        float add = bias ? bias[col] : 0.0f;
        if (EMBED) add += embed[eb + col];
#pragma unroll
        for (int mi = 0; mi < 4; ++mi) {
#pragma unroll
            for (int r = 0; r < 4; ++r) {
                int row = bm + wm * 64 + mi * 16 + r0 + r;
                float v = acc[mi][ni][r] + add;
                if (ACT == 1) v = softplusf_(v);
                if (OBF) {
                    ((unsigned short*)Cv)[(size_t)row * ldc + col] = f2bf(v);
                } else {
                    float* p = (float*)Cv + (size_t)row * ldc + col;
                    if (ACC) *p += v; else *p = v;
                }
            }
        }
    }
}

// ---------------------------------------------------------------------------
// Skinny MFMA GEMM: xdbc[M,64] = u_bf16[M,1024] * xpw_bf16[64,1024]^T (bf16 out)
// BM=64, BN=64, BK=64, 128 threads (2 waves), grid = M/64.
// ---------------------------------------------------------------------------
__global__ __launch_bounds__(128) void gemm_xdbc(
    const unsigned short* __restrict__ A,
    const unsigned short* __restrict__ W,
    unsigned short* __restrict__ C)
{
    __shared__ unsigned short Asm[64 * 64];
    __shared__ unsigned short Wsm[64 * 64];
    const int tid = (int)threadIdx.x;
    const int lane = tid & 63;
    const int w = tid >> 6;
    const int bm = blockIdx.x * 64;
    const int l8 = lane >> 3, wc = lane & 7, wcg = wc ^ l8;
    char* aB = (char*)Asm;
    char* bB = (char*)Wsm;

    f32x4 acc[2][4] = {};

    for (int k0 = 0; k0 < 1024; k0 += 64) {
#pragma unroll
        for (int i = 0; i < 4; ++i) {
            int rb = (i * 2 + w) * 8;
            gload16(A + (size_t)(bm + rb + l8) * 1024 + k0 + wcg * 8, aB + rb * 128);
            gload16(W + (size_t)(rb + l8) * 1024 + k0 + wcg * 8, bB + rb * 128);
        }
        __syncthreads();
        const int rA = w * 32 + (lane & 15);
        const int rB = (lane & 15);
        const int q = lane >> 4;
#pragma unroll
        for (int kk = 0; kk < 2; ++kk) {
            bf16x8 af[2], bfr[4];
#pragma unroll
            for (int mi = 0; mi < 2; ++mi) {
                int row = rA + mi * 16;
                int ch = (kk * 4 + q) ^ (row & 7);
                af[mi] = *(const bf16x8*)(aB + row * 128 + ch * 16);
            }
#pragma unroll
            for (int ni = 0; ni < 4; ++ni) {
                int row = rB + ni * 16;
                int ch = (kk * 4 + q) ^ (row & 7);
                bfr[ni] = *(const bf16x8*)(bB + row * 128 + ch * 16);
            }
#pragma unroll
            for (int mi = 0; mi < 2; ++mi)
#pragma unroll
                for (int ni = 0; ni < 4; ++ni)
                    acc[mi][ni] = __builtin_amdgcn_mfma_f32_16x16x32_bf16(
                        af[mi], bfr[ni], acc[mi][ni], 0, 0, 0);
        }
        __syncthreads();
    }
    const int cn = lane & 15;
    const int r0 = (lane >> 4) * 4;
#pragma unroll
    for (int mi = 0; mi < 2; ++mi)
#pragma unroll
        for (int ni = 0; ni < 4; ++ni)
#pragma unroll
            for (int r = 0; r < 4; ++r) {
                int row = bm + w * 32 + mi * 16 + r0 + r;
                C[(size_t)row * 64 + ni * 16 + cn] = f2bf(acc[mi][ni][r]);
            }
}

// ---------------------------------------------------------------------------
// Concat skip (f32) into x0 bf16 cols [512,1024)
// ---------------------------------------------------------------------------
__global__ __launch_bounds__(256) void concat_skip(
    const float* __restrict__ skip, unsigned short* __restrict__ x0)
{
    int t = blockIdx.x * 256 + (int)threadIdx.x;
    int row = t >> 6;
    int c8 = (t & 63) << 3;
    const float* s = skip + (size_t)row * 512 + c8;
    float4 f0 = *(const float4*)s;
    float4 f1 = *(const float4*)(s + 4);
    union { unsigned short u[8]; uint4 v; } pk;
    pk.u[0] = f2bf(f0.x); pk.u[1] = f2bf(f0.y); pk.u[2] = f2bf(f0.z); pk.u[3] = f2bf(f0.w);
    pk.u[4] = f2bf(f1.x); pk.u[5] = f2bf(f1.y); pk.u[6] = f2bf(f1.z); pk.u[7] = f2bf(f1.w);
    *(uint4*)(x0 + (size_t)row * 1024 + 512 + c8) = pk.v;
}

// ---------------------------------------------------------------------------
template <bool BFOUT>
__global__ __launch_bounds__(256) void layernorm_k(
    const float* __restrict__ x, void* __restrict__ outp,
    const float* __restrict__ w, const float* __restrict__ b)
{
    const int row = blockIdx.x * 4 + ((int)threadIdx.x >> 6);
    const int lane = (int)threadIdx.x & 63;
    const float* xr = x + (size_t)row * 512;
    float4 v0 = *(const float4*)(xr + lane * 4);
    float4 v1 = *(const float4*)(xr + 256 + lane * 4);
    float s = v0.x + v0.y + v0.z + v0.w + v1.x + v1.y + v1.z + v1.w;
    float q = v0.x*v0.x + v0.y*v0.y + v0.z*v0.z + v0.w*v0.w
            + v1.x*v1.x + v1.y*v1.y + v1.z*v1.z + v1.w*v1.w;
#pragma unroll
    for (int o = 32; o; o >>= 1) {
        s += __shfl_xor(s, o, 64);
        q += __shfl_xor(q, o, 64);
    }
    const float mean = s * (1.0f / 512.0f);
    const float var = q * (1.0f / 512.0f) - mean * mean;
    const float rstd = rsqrtf(var + EPS);
    float4 w0 = *(const float4*)(w + lane * 4);
    float4 w1 = *(const float4*)(w + 256 + lane * 4);
    float4 b0 = *(const float4*)(b + lane * 4);
    float4 b1 = *(const float4*)(b + 256 + lane * 4);
    float4 o0, o1;
    o0.x = (v0.x - mean) * rstd * w0.x + b0.x;
    o0.y = (v0.y - mean) * rstd * w0.y + b0.y;
    o0.z = (v0.z - mean) * rstd * w0.z + b0.z;
    o0.w = (v0.w - mean) * rstd * w0.w + b0.w;
    o1.x = (v1.x - mean) * rstd * w1.x + b1.x;
    o1.y = (v1.y - mean) * rstd * w1.y + b1.y;
    o1.z = (v1.z - mean) * rstd * w1.z + b1.z;
    o1.w = (v1.w - mean) * rstd * w1.w + b1.w;
    if (BFOUT) {
        unsigned short* ob = (unsigned short*)outp + (size_t)row * 512;
        union { unsigned short u[4]; uint2 v; } p0, p1;
        p0.u[0] = f2bf(o0.x); p0.u[1] = f2bf(o0.y); p0.u[2] = f2bf(o0.z); p0.u[3] = f2bf(o0.w);
        p1.u[0] = f2bf(o1.x); p1.u[1] = f2bf(o1.y); p1.u[2] = f2bf(o1.z); p1.u[3] = f2bf(o1.w);
        *(uint2*)(ob + lane * 4) = p0.v;
        *(uint2*)(ob + 256 + lane * 4) = p1.v;
    } else {
        float* orow = (float*)outp + (size_t)row * 512;
        *(float4*)(orow + lane * 4) = o0;
        *(float4*)(orow + 256 + lane * 4) = o1;
    }
}

__global__ __launch_bounds__(256) void rms_silu_k(
    const float* __restrict__ x, unsigned short* __restrict__ o,
    const float* __restrict__ w)
{
    const int row = blockIdx.x * 4 + ((int)threadIdx.x >> 6);
    const int lane = (int)threadIdx.x & 63;
    const float* xr = x + (size_t)row * 512;
    float4 v0 = *(const float4*)(xr + lane * 4);
    float4 v1 = *(const float4*)(xr + 256 + lane * 4);
    float q = v0.x*v0.x + v0.y*v0.y + v0.z*v0.z + v0.w*v0.w
            + v1.x*v1.x + v1.y*v1.y + v1.z*v1.z + v1.w*v1.w;
#pragma unroll
    for (int of = 32; of; of >>= 1) q += __shfl_xor(q, of, 64);
    const float scale = rsqrtf(q * (1.0f / 512.0f) + EPS);
    float4 w0 = *(const float4*)(w + lane * 4);
    float4 w1 = *(const float4*)(w + 256 + lane * 4);
    union { unsigned short u[4]; uint2 v; } p0, p1;
    p0.u[0] = f2bf(siluf_(v0.x * scale * w0.x));
    p0.u[1] = f2bf(siluf_(v0.y * scale * w0.y));
    p0.u[2] = f2bf(siluf_(v0.z * scale * w0.z));
    p0.u[3] = f2bf(siluf_(v0.w * scale * w0.w));
    p1.u[0] = f2bf(siluf_(v1.x * scale * w1.x));
    p1.u[1] = f2bf(siluf_(v1.y * scale * w1.y));
    p1.u[2] = f2bf(siluf_(v1.z * scale * w1.z));
    p1.u[3] = f2bf(siluf_(v1.w * scale * w1.w));
    unsigned short* ob = o + (size_t)row * 512;
    *(uint2*)(ob + lane * 4) = p0.v;
    *(uint2*)(ob + 256 + lane * 4) = p1.v;
}

// ---------------------------------------------------------------------------
// Causal depthwise conv(k=4)+bias+silu: xz bf16 cols[0,1024) -> u bf16.
// ---------------------------------------------------------------------------
__global__ __launch_bounds__(256) void conv_silu_k2(
    const unsigned short* __restrict__ xz, unsigned short* __restrict__ ub,
    const float* __restrict__ cw, const float* __restrict__ cb)
{
    int t = blockIdx.x * 256 + (int)threadIdx.x;
    int d = t & 1023;
    int bc = t >> 10;
    int b = bc >> 4, ch = bc & 15;
    int l0 = ch * 64;
    float4 w4 = *(const float4*)(cw + (size_t)d * 4);
    float bias = cb[d];
    const unsigned short* src = xz + ((size_t)(b * 1024 + l0)) * 2048 + d;
    unsigned short* dst = ub + ((size_t)(b * 1024 + l0)) * 1024 + d;
    float x0 = 0.f, x1 = 0.f, x2 = 0.f;
    if (l0 > 0) {
        x0 = bf2f(src[-(size_t)3 * 2048]);
        x1 = bf2f(src[-(size_t)2 * 2048]);
        x2 = bf2f(src[-(size_t)1 * 2048]);
    }
    for (int l = 0; l < 64; ++l) {
        float x3 = bf2f(src[(size_t)l * 2048]);
        float v = fmaf(x0, w4.x, fmaf(x1, w4.y, fmaf(x2, w4.z, fmaf(x3, w4.w, bias))));
        dst[(size_t)l * 1024] = f2bf(siluf_(v));
        x0 = x1; x1 = x2; x2 = x3;
    }
}

// ---------------------------------------------------------------------------
// Split-L selective scan (8 chunks x 128). dt/u/z/B/C bf16; gate fused in p2.
// XCD-contiguous remap: all 64 d-slice blocks of one (b,c) share an XCD.
// ---------------------------------------------------------------------------
template <int CTRL>
DEV_INLINE float dpp_add(float x) {
    int xi = __builtin_bit_cast(int, x);
    int yi = __builtin_amdgcn_update_dpp(0, xi, CTRL, 0xF, 0xF, false);
    return x + __builtin_bit_cast(float, yi);
}

template <int PHASE>
__global__ __launch_bounds__(256) void scan3(
    const unsigned short* __restrict__ dtp,  // (8192,1024) bf16 dt
    const unsigned short* ubf,               // (8192,1024) bf16 u (aliases ybf)
    unsigned short* ybf,                     // phase2 out (gated y)
    const unsigned short* __restrict__ xdbc, // (8192,64) bf16: dtp|B|C
    const unsigned short* __restrict__ zbf,  // z = xz bf16 cols [1024,2048)
    float* __restrict__ hp,                  // (8192*8*16) float2 {h,prod}
    const float* __restrict__ A_log,
    const float* __restrict__ Dp)
{
    __shared__ float dtu[128][36];
    __shared__ float BCs[128][36];
    __shared__ float ys[PHASE == 2 ? 128 : 1][20];

    // bijective XCD remap (nwg = 4096): XCD k gets logical [k*512,(k+1)*512)
    const int lin = (int)blockIdx.x;
    const int logical = (lin & 7) * 512 + (lin >> 3);
    const int g = logical & 63;
    const int r = logical >> 6;
    const int c = r & 7, b = r >> 3;
    if (PHASE == 1 && c == 7) return;
    const int tid = (int)threadIdx.x;
    const int dg = tid >> 4, n = tid & 15;
    const int dblk = g << 4;
    const int d = dblk + dg;
    const int m0 = b * 1024 + c * 128;

    const float An = -__expf(A_log[(size_t)d * 16 + n]);
    const float Dv = (PHASE == 2) ? Dp[d] : 0.0f;

#pragma unroll
    for (int j = 0; j < 2; ++j) {
        int task = tid + j * 256;
        int row = task >> 2, q = task & 3;
        size_t gr = (size_t)(m0 + row);
        uint2 dd = *(const uint2*)(dtp + gr * 1024 + dblk + q * 4);
        uint2 uu = *(const uint2*)(ubf + gr * 1024 + dblk + q * 4);
        float4 lo = {bf2f((unsigned short)(dd.x & 0xffff)),
                     bf2f((unsigned short)(uu.x & 0xffff)),
                     bf2f((unsigned short)(dd.x >> 16)),
                     bf2f((unsigned short)(uu.x >> 16))};
        float4 hi = {bf2f((unsigned short)(dd.y & 0xffff)),
                     bf2f((unsigned short)(uu.y & 0xffff)),
                     bf2f((unsigned short)(dd.y >> 16)),
                     bf2f((unsigned short)(uu.y >> 16))};
        *(float4*)&dtu[row][q * 8] = lo;
        *(float4*)&dtu[row][q * 8 + 4] = hi;
        uint2 Bu = *(const uint2*)(xdbc + gr * 64 + 32 + q * 4);
        float b0 = bf2f((unsigned short)(Bu.x & 0xffff));
        float b1 = bf2f((unsigned short)(Bu.x >> 16));
        float b2 = bf2f((unsigned short)(Bu.y & 0xffff));
        float b3 = bf2f((unsigned short)(Bu.y >> 16));
        float c0 = 0.f, c1 = 0.f, c2 = 0.f, c3 = 0.f;
        if (PHASE == 2) {
            uint2 Cu = *(const uint2*)(xdbc + gr * 64 + 48 + q * 4);
            c0 = bf2f((unsigned short)(Cu.x & 0xffff));
            c1 = bf2f((unsigned short)(Cu.x >> 16));
            c2 = bf2f((unsigned short)(Cu.y & 0xffff));
            c3 = bf2f((unsigned short)(Cu.y >> 16));
        }
        float4 blo = {b0, c0, b1, c1};
        float4 bhi = {b2, c2, b3, c3};
        *(float4*)&BCs[row][q * 8] = blo;
        *(float4*)&BCs[row][q * 8 + 4] = bhi;
    }

    float h = 0.0f, prod = 1.0f;
    if (PHASE == 2) {
        for (int cc = 0; cc < c; ++cc) {
            float2 v = *(const float2*)(hp +
                ((((size_t)b * 1024 + d) * 8 + cc) * 16 + n) * 2);
            h = fmaf(v.y, h, v.x);
        }
    }
    __syncthreads();

    for (int l = 0; l < 128; ++l) {
        float2 du = *(const float2*)&dtu[l][2 * dg];
        float2 bcv = *(const float2*)&BCs[l][2 * n];
        float dA = __expf(du.x * An);
        if (PHASE == 1) prod *= dA;
        h = fmaf(dA, h, du.x * du.y * bcv.x);
        if (PHASE == 2) {
            float p = h * bcv.y;
            p = dpp_add<0x128>(p);   // row_ror:8
            p = dpp_add<0x124>(p);   // row_ror:4
            p = dpp_add<0x122>(p);   // row_ror:2
            p = dpp_add<0x121>(p);   // row_ror:1
            if (n == 0) ys[l][dg] = fmaf(du.y, Dv, p);
        }
    }

    if (PHASE == 1) {
        float2 o = {h, prod};
        *(float2*)(hp + ((((size_t)b * 1024 + d) * 8 + c) * 16 + n) * 2) = o;
    } else {
        __syncthreads();
#pragma unroll
        for (int j = 0; j < 2; ++j) {
            int task = tid + j * 256;
            int row = task >> 2, q = task & 3;
            size_t gr = (size_t)(m0 + row);
            float4 y4 = *(const float4*)&ys[row][q * 4];
            uint2 zz = *(const uint2*)(zbf + gr * 2048 + 1024 + dblk + q * 4);
            y4.x *= siluf_(bf2f((unsigned short)(zz.x & 0xffff)));
            y4.y *= siluf_(bf2f((unsigned short)(zz.x >> 16)));
            y4.z *= siluf_(bf2f((unsigned short)(zz.y & 0xffff)));
            y4.w *= siluf_(bf2f((unsigned short)(zz.y >> 16)));
            union { unsigned short u[4]; uint2 v; } pk;
            pk.u[0] = f2bf(y4.x); pk.u[1] = f2bf(y4.y);
            pk.u[2] = f2bf(y4.z); pk.u[3] = f2bf(y4.w);
            *(uint2*)(ybf + gr * 1024 + dblk + q * 4) = pk.v;
        }
    }
}

// ---------------------------------------------------------------------------
extern "C" void kernel_launch(void* const* d_in, const int* in_sizes, int n_in,
                              void* d_out, int out_size, void* d_ws, size_t ws_size,
                              hipStream_t stream)
{
    const float* motion     = (const float*)d_in[0];
    const float* skip       = (const float*)d_in[1];
    const float* embed      = (const float*)d_in[2];
    const float* w_up       = (const float*)d_in[3];
    const float* b_up       = (const float*)d_in[4];
    const float* w1         = (const float*)d_in[5];
    const float* b1         = (const float*)d_in[6];
    const float* rms_w      = (const float*)d_in[7];
    const float* w2         = (const float*)d_in[8];
    const float* b2         = (const float*)d_in[9];
    const float* ln_w       = (const float*)d_in[10];
    const float* ln_b       = (const float*)d_in[11];
    const float* in_proj_w  = (const float*)d_in[12];
    const float* conv_w     = (const float*)d_in[13];
    const float* conv_b     = (const float*)d_in[14];
    const float* x_proj_w   = (const float*)d_in[15];
    const float* dt_proj_w  = (const float*)d_in[16];
    const float* dt_proj_b  = (const float*)d_in[17];
    const float* A_log      = (const float*)d_in[18];
    const float* D_param    = (const float*)d_in[19];
    const float* out_proj_w = (const float*)d_in[20];
    const float* out_proj_b = (const float*)d_in[21];
    const float* norm_f_w   = (const float*)d_in[22];
    const float* norm_f_b   = (const float*)d_in[23];
    float* out = (float*)d_out;
    float* ws = (float*)d_ws;

    // Workspace (float offsets):
    float* xbuf = ws;                                        // (8192x512) f32
    float* xlnf = ws + 4194304;                              // (8192x512) f32 temp
    unsigned short* xzbf  = (unsigned short*)(ws + 8388608); // (8192x2048) bf16
    unsigned short* ubf   = (unsigned short*)(ws + 16777216);// (8192x1024) bf16, u -> y
    unsigned short* dtybf = (unsigned short*)(ws + 20971520);// (8192x1024) bf16 dt
    unsigned short* xdbc  = (unsigned short*)(ws + 25165824);// (8192x64) bf16
    float* hp  = ws + 25427968;                              // 2M f {h,prod}
    unsigned short* xsbf = (unsigned short*)(ws + 27525120); // (8192x512) bf16
    unsigned short* mbf  = (unsigned short*)(ws + 29622272); // motion bf16
    unsigned short* ipw  = (unsigned short*)(ws + 30670848); // 1M elems bf16
    unsigned short* wdt64= (unsigned short*)(ws + 31195136); // 64K elems bf16
    unsigned short* opw  = (unsigned short*)(ws + 31227904); // 512K elems bf16
    unsigned short* xpw  = (unsigned short*)(ws + 31490048); // 64K elems bf16

    unsigned short* x0bf = xzbf;   // (8192x1024) bf16, dead after stage 2

    dim3 blk(256);

    // --- Stage 1: upsample (MFMA, bf16) + concat ---
    cvt_bf16<<<dim3(1024), blk, 0, stream>>>(motion, mbf, 262144);
    transpose_wup_bf<<<dim3(1024), blk, 0, stream>>>(w_up, ipw);
    for (int k = 0; k < 2; ++k) {
        gemm_mfma<0, false, false, true><<<dim3(128), blk, 0, stream>>>(
            mbf, 512, ipw + (size_t)k * 262144, 512,
            x0bf + (size_t)k * 1024, 2048, 512, 512, 4, b_up, nullptr);
    }
    concat_skip<<<dim3(2048), blk, 0, stream>>>(skip, x0bf);

    // --- Stage 2: xlnf = x0 @ w1^T + b1 ; rmsnorm+silu -> xsbf ---
    cvt_bf16<<<dim3(256), blk, 0, stream>>>(w1, ipw, 65536);
    gemm_mfma<0, false, false, false><<<dim3(256), blk, 0, stream>>>(
        x0bf, 1024, ipw, 1024, xlnf, 512, 512, 1024, 4, b1, nullptr);
    rms_silu_k<<<dim3(2048), blk, 0, stream>>>(xlnf, xsbf, rms_w);

    // --- Stage 3: xbuf = xs @ w2^T + b2 + embed ---
    cvt_bf16<<<dim3(128), blk, 0, stream>>>(w2, ipw, 32768);
    gemm_mfma<0, false, true, false><<<dim3(256), blk, 0, stream>>>(
        xsbf, 512, ipw, 512, xbuf, 512, 512, 512, 4, b2, embed);

    // --- Mamba blocks ---
    for (int i = 0; i < 4; ++i) {
        layernorm_k<true><<<dim3(2048), blk, 0, stream>>>(
            xbuf, xsbf, ln_w + (size_t)i * 512, ln_b + (size_t)i * 512);
        prep_w<<<dim3(1056), blk, 0, stream>>>(
            in_proj_w + (size_t)i * 1048576, out_proj_w + (size_t)i * 524288,
            x_proj_w + (size_t)i * 65536, dt_proj_w + (size_t)i * 32768,
            ipw, opw, xpw, wdt64);
        // xz = xln @ in_proj^T  (bf16 out)
        gemm_mfma<0, false, false, true><<<dim3(1024), blk, 0, stream>>>(
            xsbf, 512, ipw, 512, xzbf, 2048, 2048, 512, 16, nullptr, nullptr);
        // conv + silu -> u (bf16)
        conv_silu_k2<<<dim3(512), blk, 0, stream>>>(
            xzbf, ubf, conv_w + (size_t)i * 4096, conv_b + (size_t)i * 1024);
        // xdbc = u @ x_proj^T  (8192x64, bf16)
        gemm_xdbc<<<dim3(128), dim3(128), 0, stream>>>(ubf, xpw, xdbc);
        // dt = softplus(xdbc @ wdt64^T + dtb)  (K=64, cols 32..63 of W are 0)
        gemm_mfma<1, false, false, true><<<dim3(512), blk, 0, stream>>>(
            xdbc, 64, wdt64, 64, dtybf, 1024, 1024, 64, 8,
            dt_proj_b + (size_t)i * 1024, nullptr);
        // selective scan: phase1 (chunk summaries), phase2 (y + gate, bf16)
        scan3<1><<<dim3(4096), blk, 0, stream>>>(
            dtybf, ubf, nullptr, xdbc, xzbf, hp,
            A_log + (size_t)i * 16384, D_param + (size_t)i * 1024);
        scan3<2><<<dim3(4096), blk, 0, stream>>>(
            dtybf, ubf, ubf, xdbc, xzbf, hp,
            A_log + (size_t)i * 16384, D_param + (size_t)i * 1024);
        // xbuf += y @ out_proj^T + ob
        gemm_mfma<0, true, false, false><<<dim3(256), blk, 0, stream>>>(
            ubf, 1024, opw, 1024, xbuf, 512, 512, 1024, 4,
            out_proj_b + (size_t)i * 512, nullptr);
    }

    // --- Final layernorm -> out ---
    layernorm_k<false><<<dim3(2048), blk, 0, stream>>>(xbuf, out, norm_f_w, norm_f_b);
}

// Round 6
// 1035.395 us; speedup vs baseline: 4.5650x; 1.0405x over previous
//
#include <hip/hip_runtime.h>
#include <cstdint>
#include <cstddef>

#define DEV_INLINE __device__ __forceinline__

static constexpr float EPS = 1e-5f;

DEV_INLINE float sigmoidf_(float x) { return 1.0f / (1.0f + __expf(-x)); }
DEV_INLINE float siluf_(float x) { return x * sigmoidf_(x); }
DEV_INLINE float softplusf_(float x) {
    return fmaxf(x, 0.0f) + log1pf(__expf(-fabsf(x)));
}
DEV_INLINE unsigned short f2bf(float x) {   // RNE f32 -> bf16
    unsigned u = __builtin_bit_cast(unsigned, x);
    u += 0x7FFFu + ((u >> 16) & 1u);
    return (unsigned short)(u >> 16);
}
DEV_INLINE float bf2f(unsigned short s) {
    unsigned u = ((unsigned)s) << 16;
    return __builtin_bit_cast(float, u);
}

typedef __attribute__((ext_vector_type(8))) short bf16x8;
typedef __attribute__((ext_vector_type(4))) float f32x4;

DEV_INLINE void gload16(const unsigned short* src, char* ldsdst) {
    __builtin_amdgcn_global_load_lds(
        (const __attribute__((address_space(1))) unsigned int*)src,
        (__attribute__((address_space(3))) unsigned int*)ldsdst, 16, 0, 0);
}

DEV_INLINE void cvt8(const float* __restrict__ s, unsigned short* __restrict__ d, int t) {
    float4 f0 = *(const float4*)(s + (size_t)t * 8);
    float4 f1 = *(const float4*)(s + (size_t)t * 8 + 4);
    union { unsigned short u[8]; uint4 v; } pk;
    pk.u[0] = f2bf(f0.x); pk.u[1] = f2bf(f0.y); pk.u[2] = f2bf(f0.z); pk.u[3] = f2bf(f0.w);
    pk.u[4] = f2bf(f1.x); pk.u[5] = f2bf(f1.y); pk.u[6] = f2bf(f1.z); pk.u[7] = f2bf(f1.w);
    *(uint4*)(d + (size_t)t * 8) = pk.v;
}

// ---------------------------------------------------------------------------
__global__ __launch_bounds__(256) void cvt_bf16(
    const float* __restrict__ s, unsigned short* __restrict__ d, int n8)
{
    int t = blockIdx.x * 256 + (int)threadIdx.x;
    if (t >= n8) return;
    cvt8(s, d, t);
}

// w_up (512,512,2) f32 -> wt bf16 [k][o][c]
__global__ __launch_bounds__(256) void transpose_wup_bf(
    const float* __restrict__ wup, unsigned short* __restrict__ wt)
{
    int t = blockIdx.x * 256 + (int)threadIdx.x;   // t = c*512 + o
    if (t >= 512 * 512) return;
    int c = t >> 9, o = t & 511;
    float2 v = *(const float2*)(wup + (size_t)t * 2);
    wt[(size_t)o * 512 + c] = f2bf(v.x);
    wt[262144 + (size_t)o * 512 + c] = f2bf(v.y);
}

// ---------------------------------------------------------------------------
// Per-mamba-block weight prep: zero-padded dt weight (1024x64) + bf16 converts.
// ---------------------------------------------------------------------------
__global__ __launch_bounds__(256) void prep_w(
    const float* __restrict__ in_proj_w,   // (2048,512)
    const float* __restrict__ out_proj_w,  // (512,1024)
    const float* __restrict__ x_proj_w,    // (64,1024)
    const float* __restrict__ dt_proj_w,   // (1024,32)
    unsigned short* __restrict__ ipw,
    unsigned short* __restrict__ opw,
    unsigned short* __restrict__ xpw,      // (64,1024) bf16
    unsigned short* __restrict__ wdt64)    // (1024,64) bf16, cols 32..63 = 0
{
    int bid = (int)blockIdx.x, tid = (int)threadIdx.x;
    if (bid < 256) {
        int t = bid * 256 + tid;           // t = n*64 + k
        int n = t >> 6, k = t & 63;
        wdt64[t] = (k < 32) ? f2bf(dt_proj_w[(size_t)n * 32 + k]) : (unsigned short)0;
    } else if (bid < 768) {
        cvt8(in_proj_w, ipw, (bid - 256) * 256 + tid);
    } else if (bid < 1024) {
        cvt8(out_proj_w, opw, (bid - 768) * 256 + tid);
    } else {
        cvt8(x_proj_w, xpw, (bid - 1024) * 256 + tid);
    }
}

// ---------------------------------------------------------------------------
// MFMA GEMM: C[M,N] (+)= A_bf16[M,K] * W_bf16[N,K]^T  (+bias +embed +softplus)
// BM=BN=128, BK=64, 4 waves, double-buffered LDS, XCD-contiguous block remap.
// ---------------------------------------------------------------------------
template <int ACT, bool ACC, bool EMBED, bool OBF>
__global__ __launch_bounds__(256) void gemm_mfma(
    const unsigned short* __restrict__ A, int lda,
    const unsigned short* __restrict__ W, int ldw,
    void* __restrict__ Cv, int ldc, int N, int K, int gx,
    const float* __restrict__ bias, const float* __restrict__ embed)
{
    __shared__ unsigned short Asm[2][128 * 64];
    __shared__ unsigned short Wsm[2][128 * 64];
    const int tid = (int)threadIdx.x;
    const int lane = tid & 63;
    const int wv = tid >> 6;
    const int wm = wv >> 1, wn = wv & 1;

    const int nwg = (int)gridDim.x;
    const int lin = (int)blockIdx.x;
    const int logical = (lin & 7) * (nwg >> 3) + (lin >> 3);
    const int by = logical / gx;
    const int bx = logical - by * gx;
    const int bm = by * 128, bn = bx * 128;

    f32x4 acc[4][4] = {};

    const int l8 = lane >> 3;
    const int wc = lane & 7;
    const int wcg = wc ^ l8;

    const int NT = K >> 6;

    {
        char* aB = (char*)Asm[0];
        char* bB = (char*)Wsm[0];
#pragma unroll
        for (int i = 0; i < 4; ++i) {
            int rb = (i * 4 + wv) * 8;
            gload16(W + (size_t)(bn + rb + l8) * ldw + wcg * 8, bB + rb * 128);
            gload16(A + (size_t)(bm + rb + l8) * lda + wcg * 8, aB + rb * 128);
        }
    }
    __syncthreads();

    for (int t = 0; t < NT; ++t) {
        const int cur = t & 1;
        if (t + 1 < NT) {
            const int k1 = (t + 1) << 6;
            char* aB = (char*)Asm[cur ^ 1];
            char* bB = (char*)Wsm[cur ^ 1];
#pragma unroll
            for (int i = 0; i < 4; ++i) {
                int rb = (i * 4 + wv) * 8;
                gload16(W + (size_t)(bn + rb + l8) * ldw + k1 + wcg * 8, bB + rb * 128);
                gload16(A + (size_t)(bm + rb + l8) * lda + k1 + wcg * 8, aB + rb * 128);
            }
        }
        const char* aB = (const char*)Asm[cur];
        const char* bB = (const char*)Wsm[cur];
        const int rA = wm * 64 + (lane & 15);
        const int rB = wn * 64 + (lane & 15);
        const int q = lane >> 4;
#pragma unroll
        for (int kk = 0; kk < 2; ++kk) {
            bf16x8 af[4], bfr[4];
#pragma unroll
            for (int mi = 0; mi < 4; ++mi) {
                int row = rA + mi * 16;
                int ch = (kk * 4 + q) ^ (row & 7);
                af[mi] = *(const bf16x8*)(aB + row * 128 + ch * 16);
            }
#pragma unroll
            for (int ni = 0; ni < 4; ++ni) {
                int row = rB + ni * 16;
                int ch = (kk * 4 + q) ^ (row & 7);
                bfr[ni] = *(const bf16x8*)(bB + row * 128 + ch * 16);
            }
#pragma unroll
            for (int mi = 0; mi < 4; ++mi)
#pragma unroll
                for (int ni = 0; ni < 4; ++ni)
                    acc[mi][ni] = __builtin_amdgcn_mfma_f32_16x16x32_bf16(
                        af[mi], bfr[ni], acc[mi][ni], 0, 0, 0);
        }
        __syncthreads();
    }

    const int cn = lane & 15;
    const int r0 = (lane >> 4) * 4;
    const int eb = EMBED ? (bm >> 10) * N : 0;
#pragma unroll
    for (int ni = 0; ni < 4; ++ni) {
        int col = bn + wn * 64 + ni * 16 + cn;
        float add = bias ? bias[col] : 0.0f;
        if (EMBED) add += embed[eb + col];
#pragma unroll
        for (int mi = 0; mi < 4; ++mi) {
#pragma unroll
            for (int r = 0; r < 4; ++r) {
                int row = bm + wm * 64 + mi * 16 + r0 + r;
                float v = acc[mi][ni][r] + add;
                if (ACT == 1) v = softplusf_(v);
                if (OBF) {
                    ((unsigned short*)Cv)[(size_t)row * ldc + col] = f2bf(v);
                } else {
                    float* p = (float*)Cv + (size_t)row * ldc + col;
                    if (ACC) *p += v; else *p = v;
                }
            }
        }
    }
}

// ---------------------------------------------------------------------------
// Skinny MFMA GEMM: xdbc[M,64] = u_bf16[M,1024] * xpw_bf16[64,1024]^T (bf16 out)
// ---------------------------------------------------------------------------
__global__ __launch_bounds__(128) void gemm_xdbc(
    const unsigned short* __restrict__ A,
    const unsigned short* __restrict__ W,
    unsigned short* __restrict__ C)
{
    __shared__ unsigned short Asm[64 * 64];
    __shared__ unsigned short Wsm[64 * 64];
    const int tid = (int)threadIdx.x;
    const int lane = tid & 63;
    const int w = tid >> 6;
    const int bm = blockIdx.x * 64;
    const int l8 = lane >> 3, wc = lane & 7, wcg = wc ^ l8;
    char* aB = (char*)Asm;
    char* bB = (char*)Wsm;

    f32x4 acc[2][4] = {};

    for (int k0 = 0; k0 < 1024; k0 += 64) {
#pragma unroll
        for (int i = 0; i < 4; ++i) {
            int rb = (i * 2 + w) * 8;
            gload16(A + (size_t)(bm + rb + l8) * 1024 + k0 + wcg * 8, aB + rb * 128);
            gload16(W + (size_t)(rb + l8) * 1024 + k0 + wcg * 8, bB + rb * 128);
        }
        __syncthreads();
        const int rA = w * 32 + (lane & 15);
        const int rB = (lane & 15);
        const int q = lane >> 4;
#pragma unroll
        for (int kk = 0; kk < 2; ++kk) {
            bf16x8 af[2], bfr[4];
#pragma unroll
            for (int mi = 0; mi < 2; ++mi) {
                int row = rA + mi * 16;
                int ch = (kk * 4 + q) ^ (row & 7);
                af[mi] = *(const bf16x8*)(aB + row * 128 + ch * 16);
            }
#pragma unroll
            for (int ni = 0; ni < 4; ++ni) {
                int row = rB + ni * 16;
                int ch = (kk * 4 + q) ^ (row & 7);
                bfr[ni] = *(const bf16x8*)(bB + row * 128 + ch * 16);
            }
#pragma unroll
            for (int mi = 0; mi < 2; ++mi)
#pragma unroll
                for (int ni = 0; ni < 4; ++ni)
                    acc[mi][ni] = __builtin_amdgcn_mfma_f32_16x16x32_bf16(
                        af[mi], bfr[ni], acc[mi][ni], 0, 0, 0);
        }
        __syncthreads();
    }
    const int cn = lane & 15;
    const int r0 = (lane >> 4) * 4;
#pragma unroll
    for (int mi = 0; mi < 2; ++mi)
#pragma unroll
        for (int ni = 0; ni < 4; ++ni)
#pragma unroll
            for (int r = 0; r < 4; ++r) {
                int row = bm + w * 32 + mi * 16 + r0 + r;
                C[(size_t)row * 64 + ni * 16 + cn] = f2bf(acc[mi][ni][r]);
            }
}

// ---------------------------------------------------------------------------
__global__ __launch_bounds__(256) void concat_skip(
    const float* __restrict__ skip, unsigned short* __restrict__ x0)
{
    int t = blockIdx.x * 256 + (int)threadIdx.x;
    int row = t >> 6;
    int c8 = (t & 63) << 3;
    const float* s = skip + (size_t)row * 512 + c8;
    float4 f0 = *(const float4*)s;
    float4 f1 = *(const float4*)(s + 4);
    union { unsigned short u[8]; uint4 v; } pk;
    pk.u[0] = f2bf(f0.x); pk.u[1] = f2bf(f0.y); pk.u[2] = f2bf(f0.z); pk.u[3] = f2bf(f0.w);
    pk.u[4] = f2bf(f1.x); pk.u[5] = f2bf(f1.y); pk.u[6] = f2bf(f1.z); pk.u[7] = f2bf(f1.w);
    *(uint4*)(x0 + (size_t)row * 1024 + 512 + c8) = pk.v;
}

// ---------------------------------------------------------------------------
template <bool BFOUT>
__global__ __launch_bounds__(256) void layernorm_k(
    const float* __restrict__ x, void* __restrict__ outp,
    const float* __restrict__ w, const float* __restrict__ b)
{
    const int row = blockIdx.x * 4 + ((int)threadIdx.x >> 6);
    const int lane = (int)threadIdx.x & 63;
    const float* xr = x + (size_t)row * 512;
    float4 v0 = *(const float4*)(xr + lane * 4);
    float4 v1 = *(const float4*)(xr + 256 + lane * 4);
    float s = v0.x + v0.y + v0.z + v0.w + v1.x + v1.y + v1.z + v1.w;
    float q = v0.x*v0.x + v0.y*v0.y + v0.z*v0.z + v0.w*v0.w
            + v1.x*v1.x + v1.y*v1.y + v1.z*v1.z + v1.w*v1.w;
#pragma unroll
    for (int o = 32; o; o >>= 1) {
        s += __shfl_xor(s, o, 64);
        q += __shfl_xor(q, o, 64);
    }
    const float mean = s * (1.0f / 512.0f);
    const float var = q * (1.0f / 512.0f) - mean * mean;
    const float rstd = rsqrtf(var + EPS);
    float4 w0 = *(const float4*)(w + lane * 4);
    float4 w1 = *(const float4*)(w + 256 + lane * 4);
    float4 b0 = *(const float4*)(b + lane * 4);
    float4 b1 = *(const float4*)(b + 256 + lane * 4);
    float4 o0, o1;
    o0.x = (v0.x - mean) * rstd * w0.x + b0.x;
    o0.y = (v0.y - mean) * rstd * w0.y + b0.y;
    o0.z = (v0.z - mean) * rstd * w0.z + b0.z;
    o0.w = (v0.w - mean) * rstd * w0.w + b0.w;
    o1.x = (v1.x - mean) * rstd * w1.x + b1.x;
    o1.y = (v1.y - mean) * rstd * w1.y + b1.y;
    o1.z = (v1.z - mean) * rstd * w1.z + b1.z;
    o1.w = (v1.w - mean) * rstd * w1.w + b1.w;
    if (BFOUT) {
        unsigned short* ob = (unsigned short*)outp + (size_t)row * 512;
        union { unsigned short u[4]; uint2 v; } p0, p1;
        p0.u[0] = f2bf(o0.x); p0.u[1] = f2bf(o0.y); p0.u[2] = f2bf(o0.z); p0.u[3] = f2bf(o0.w);
        p1.u[0] = f2bf(o1.x); p1.u[1] = f2bf(o1.y); p1.u[2] = f2bf(o1.z); p1.u[3] = f2bf(o1.w);
        *(uint2*)(ob + lane * 4) = p0.v;
        *(uint2*)(ob + 256 + lane * 4) = p1.v;
    } else {
        float* orow = (float*)outp + (size_t)row * 512;
        *(float4*)(orow + lane * 4) = o0;
        *(float4*)(orow + 256 + lane * 4) = o1;
    }
}

__global__ __launch_bounds__(256) void rms_silu_k(
    const float* __restrict__ x, unsigned short* __restrict__ o,
    const float* __restrict__ w)
{
    const int row = blockIdx.x * 4 + ((int)threadIdx.x >> 6);
    const int lane = (int)threadIdx.x & 63;
    const float* xr = x + (size_t)row * 512;
    float4 v0 = *(const float4*)(xr + lane * 4);
    float4 v1 = *(const float4*)(xr + 256 + lane * 4);
    float q = v0.x*v0.x + v0.y*v0.y + v0.z*v0.z + v0.w*v0.w
            + v1.x*v1.x + v1.y*v1.y + v1.z*v1.z + v1.w*v1.w;
#pragma unroll
    for (int of = 32; of; of >>= 1) q += __shfl_xor(q, of, 64);
    const float scale = rsqrtf(q * (1.0f / 512.0f) + EPS);
    float4 w0 = *(const float4*)(w + lane * 4);
    float4 w1 = *(const float4*)(w + 256 + lane * 4);
    union { unsigned short u[4]; uint2 v; } p0, p1;
    p0.u[0] = f2bf(siluf_(v0.x * scale * w0.x));
    p0.u[1] = f2bf(siluf_(v0.y * scale * w0.y));
    p0.u[2] = f2bf(siluf_(v0.z * scale * w0.z));
    p0.u[3] = f2bf(siluf_(v0.w * scale * w0.w));
    p1.u[0] = f2bf(siluf_(v1.x * scale * w1.x));
    p1.u[1] = f2bf(siluf_(v1.y * scale * w1.y));
    p1.u[2] = f2bf(siluf_(v1.z * scale * w1.z));
    p1.u[3] = f2bf(siluf_(v1.w * scale * w1.w));
    unsigned short* ob = o + (size_t)row * 512;
    *(uint2*)(ob + lane * 4) = p0.v;
    *(uint2*)(ob + 256 + lane * 4) = p1.v;
}

// ---------------------------------------------------------------------------
// Causal depthwise conv(k=4)+bias+silu: xz bf16 cols[0,1024) -> u bf16.
// ---------------------------------------------------------------------------
__global__ __launch_bounds__(256) void conv_silu_k2(
    const unsigned short* __restrict__ xz, unsigned short* __restrict__ ub,
    const float* __restrict__ cw, const float* __restrict__ cb)
{
    int t = blockIdx.x * 256 + (int)threadIdx.x;
    int d = t & 1023;
    int bc = t >> 10;
    int b = bc >> 4, ch = bc & 15;
    int l0 = ch * 64;
    float4 w4 = *(const float4*)(cw + (size_t)d * 4);
    float bias = cb[d];
    const unsigned short* src = xz + ((size_t)(b * 1024 + l0)) * 2048 + d;
    unsigned short* dst = ub + ((size_t)(b * 1024 + l0)) * 1024 + d;
    float x0 = 0.f, x1 = 0.f, x2 = 0.f;
    if (l0 > 0) {
        x0 = bf2f(src[-(size_t)3 * 2048]);
        x1 = bf2f(src[-(size_t)2 * 2048]);
        x2 = bf2f(src[-(size_t)1 * 2048]);
    }
    for (int l = 0; l < 64; ++l) {
        float x3 = bf2f(src[(size_t)l * 2048]);
        float v = fmaf(x0, w4.x, fmaf(x1, w4.y, fmaf(x2, w4.z, fmaf(x3, w4.w, bias))));
        dst[(size_t)l * 1024] = f2bf(siluf_(v));
        x0 = x1; x1 = x2; x2 = x3;
    }
}

// ---------------------------------------------------------------------------
// Split-L selective scan v4: 4 states per lane, 64 d's per block.
// Block = (b, chunk, 64 d's); thread = (dl, q); q owns n = 4q..4q+3.
// Sub-chunks of 32 l staged in LDS with pre-multiplied {dt, dt*u}.
// Quad-lane DPP reduction (2 adds). Grid 1024, XCD-contiguous remap.
// ---------------------------------------------------------------------------
template <int CTRL>
DEV_INLINE float dpp_f(float x) {
    int yi = __builtin_amdgcn_update_dpp(
        0, __builtin_bit_cast(int, x), CTRL, 0xF, 0xF, true);
    return __builtin_bit_cast(float, yi);
}

template <int PHASE>
__global__ __launch_bounds__(256) void scan4(
    const unsigned short* __restrict__ dtp,  // (8192,1024) bf16 dt
    const unsigned short* ubf,               // (8192,1024) bf16 u (aliases ybf)
    unsigned short* ybf,                     // phase2 out (gated y)
    const unsigned short* __restrict__ xdbc, // (8192,64) bf16: dtp|B|C
    const unsigned short* __restrict__ zbf,  // z = xz bf16 cols [1024,2048)
    float* __restrict__ hp,                  // per (b,d,c,n): {h,prod}
    const float* __restrict__ A_log,
    const float* __restrict__ Dp)
{
    __shared__ float SDT[32][132];           // {dt, dt*u} pairs per d
    __shared__ float SB[32][20];
    __shared__ float SC[PHASE == 2 ? 32 : 1][20];
    __shared__ float YS[PHASE == 2 ? 32 : 1][68];

    const int lin = (int)blockIdx.x;
    const int logical = (lin & 7) * 128 + (lin >> 3);
    const int gg = logical & 15;             // d-group (64 d's)
    const int rr0 = logical >> 4;            // b*8 + c
    const int c = rr0 & 7, b = rr0 >> 3;
    if (PHASE == 1 && c == 7) return;
    const int tid = (int)threadIdx.x;
    const int dl = tid >> 2, q = tid & 3;
    const int dblk = gg << 6;
    const int d = dblk + dl;
    const int m0 = b * 1024 + c * 128;

    float An[4];
#pragma unroll
    for (int j = 0; j < 4; ++j)
        An[j] = -__expf(A_log[(size_t)d * 16 + q * 4 + j]);

    float h[4] = {};
    float prod[4] = {1.f, 1.f, 1.f, 1.f};
    if (PHASE == 2) {
        const float* hpb = hp + ((size_t)(b * 1024 + d)) * 256 + q * 8;
        for (int cc = 0; cc < c; ++cc) {
            float4 v0 = *(const float4*)(hpb + cc * 32);
            float4 v1 = *(const float4*)(hpb + cc * 32 + 4);
            h[0] = fmaf(v0.y, h[0], v0.x);
            h[1] = fmaf(v0.w, h[1], v0.z);
            h[2] = fmaf(v1.y, h[2], v1.x);
            h[3] = fmaf(v1.w, h[3], v1.z);
        }
    }

    const int sr = tid >> 3;                 // staging row 0..31
    const int c8 = tid & 7;                  // 8-wide column group
    const int bcr = (tid & 127) >> 2;        // B/C row
    const int bne = (tid & 3) << 2;          // B/C n-offset

    for (int s = 0; s < 4; ++s) {
        const int lbase = s * 32;
        // ---- stage dt & dt*u ----
        {
            size_t gr = (size_t)(m0 + lbase + sr);
            uint4 d8 = *(const uint4*)(dtp + gr * 1024 + dblk + c8 * 8);
            uint4 u8 = *(const uint4*)(ubf + gr * 1024 + dblk + c8 * 8);
            const unsigned* dw = (const unsigned*)&d8;
            const unsigned* uw = (const unsigned*)&u8;
#pragma unroll
            for (int k = 0; k < 4; ++k) {
                float dt0 = bf2f((unsigned short)(dw[k] & 0xffff));
                float dt1 = bf2f((unsigned short)(dw[k] >> 16));
                float uu0 = bf2f((unsigned short)(uw[k] & 0xffff));
                float uu1 = bf2f((unsigned short)(uw[k] >> 16));
                float4 wv = {dt0, dt0 * uu0, dt1, dt1 * uu1};
                *(float4*)&SDT[sr][c8 * 16 + k * 4] = wv;
            }
        }
        // ---- stage B (threads 0..127) / C (threads 128..255, p2) ----
        {
            size_t gr = (size_t)(m0 + lbase + bcr);
            if (tid < 128) {
                uint2 Bu = *(const uint2*)(xdbc + gr * 64 + 32 + bne);
                SB[bcr][bne + 0] = bf2f((unsigned short)(Bu.x & 0xffff));
                SB[bcr][bne + 1] = bf2f((unsigned short)(Bu.x >> 16));
                SB[bcr][bne + 2] = bf2f((unsigned short)(Bu.y & 0xffff));
                SB[bcr][bne + 3] = bf2f((unsigned short)(Bu.y >> 16));
            } else if (PHASE == 2) {
                uint2 Cu = *(const uint2*)(xdbc + gr * 64 + 48 + bne);
                SC[bcr][bne + 0] = bf2f((unsigned short)(Cu.x & 0xffff));
                SC[bcr][bne + 1] = bf2f((unsigned short)(Cu.x >> 16));
                SC[bcr][bne + 2] = bf2f((unsigned short)(Cu.y & 0xffff));
                SC[bcr][bne + 3] = bf2f((unsigned short)(Cu.y >> 16));
            }
        }
        __syncthreads();

        // ---- scan 32 steps ----
        for (int l = 0; l < 32; ++l) {
            float2 dd = *(const float2*)&SDT[l][2 * dl];
            float4 Bv = *(const float4*)&SB[l][q * 4];
            float p = 0.0f;
            float4 Cv;
            if (PHASE == 2) Cv = *(const float4*)&SC[l][q * 4];
            const float* Bp = (const float*)&Bv;
            const float* Cp = (const float*)&Cv;
#pragma unroll
            for (int j = 0; j < 4; ++j) {
                float e = __expf(dd.x * An[j]);
                if (PHASE == 1) prod[j] *= e;
                h[j] = fmaf(e, h[j], dd.y * Bp[j]);
                if (PHASE == 2) p = fmaf(h[j], Cp[j], p);
            }
            if (PHASE == 2) {
                p += dpp_f<0xB1>(p);     // quad_perm [1,0,3,2]
                p += dpp_f<0x4E>(p);     // quad_perm [2,3,0,1]
                if (q == 0) YS[l][dl] = p;
            }
        }
        __syncthreads();

        // ---- store y = (p + u*D) * silu(z), bf16 (p2) ----
        if (PHASE == 2) {
#pragma unroll
            for (int j2 = 0; j2 < 2; ++j2) {
                int task = tid + j2 * 256;
                int rw = task >> 4;
                int e4 = (task & 15) << 2;
                size_t gr = (size_t)(m0 + lbase + rw);
                float4 p4 = *(const float4*)&YS[rw][e4];
                uint2 uu = *(const uint2*)(ubf + gr * 1024 + dblk + e4);
                uint2 zz = *(const uint2*)(zbf + gr * 2048 + 1024 + dblk + e4);
                float4 Dv = *(const float4*)(Dp + dblk + e4);
                float y0 = fmaf(bf2f((unsigned short)(uu.x & 0xffff)), Dv.x, p4.x)
                         * siluf_(bf2f((unsigned short)(zz.x & 0xffff)));
                float y1 = fmaf(bf2f((unsigned short)(uu.x >> 16)), Dv.y, p4.y)
                         * siluf_(bf2f((unsigned short)(zz.x >> 16)));
                float y2 = fmaf(bf2f((unsigned short)(uu.y & 0xffff)), Dv.z, p4.z)
                         * siluf_(bf2f((unsigned short)(zz.y & 0xffff)));
                float y3 = fmaf(bf2f((unsigned short)(uu.y >> 16)), Dv.w, p4.w)
                         * siluf_(bf2f((unsigned short)(zz.y >> 16)));
                union { unsigned short u[4]; uint2 v; } pk;
                pk.u[0] = f2bf(y0); pk.u[1] = f2bf(y1);
                pk.u[2] = f2bf(y2); pk.u[3] = f2bf(y3);
                *(uint2*)(ybf + gr * 1024 + dblk + e4) = pk.v;
            }
        }
    }

    if (PHASE == 1) {
        float* hpo = hp + ((size_t)(b * 1024 + d)) * 256 + c * 32 + q * 8;
        float4 o0 = {h[0], prod[0], h[1], prod[1]};
        float4 o1 = {h[2], prod[2], h[3], prod[3]};
        *(float4*)hpo = o0;
        *(float4*)(hpo + 4) = o1;
    }
}

// ---------------------------------------------------------------------------
extern "C" void kernel_launch(void* const* d_in, const int* in_sizes, int n_in,
                              void* d_out, int out_size, void* d_ws, size_t ws_size,
                              hipStream_t stream)
{
    const float* motion     = (const float*)d_in[0];
    const float* skip       = (const float*)d_in[1];
    const float* embed      = (const float*)d_in[2];
    const float* w_up       = (const float*)d_in[3];
    const float* b_up       = (const float*)d_in[4];
    const float* w1         = (const float*)d_in[5];
    const float* b1         = (const float*)d_in[6];
    const float* rms_w      = (const float*)d_in[7];
    const float* w2         = (const float*)d_in[8];
    const float* b2         = (const float*)d_in[9];
    const float* ln_w       = (const float*)d_in[10];
    const float* ln_b       = (const float*)d_in[11];
    const float* in_proj_w  = (const float*)d_in[12];
    const float* conv_w     = (const float*)d_in[13];
    const float* conv_b     = (const float*)d_in[14];
    const float* x_proj_w   = (const float*)d_in[15];
    const float* dt_proj_w  = (const float*)d_in[16];
    const float* dt_proj_b  = (const float*)d_in[17];
    const float* A_log      = (const float*)d_in[18];
    const float* D_param    = (const float*)d_in[19];
    const float* out_proj_w = (const float*)d_in[20];
    const float* out_proj_b = (const float*)d_in[21];
    const float* norm_f_w   = (const float*)d_in[22];
    const float* norm_f_b   = (const float*)d_in[23];
    float* out = (float*)d_out;
    float* ws = (float*)d_ws;

    // Workspace (float offsets):
    float* xbuf = ws;                                        // (8192x512) f32
    float* xlnf = ws + 4194304;                              // (8192x512) f32 temp
    unsigned short* xzbf  = (unsigned short*)(ws + 8388608); // (8192x2048) bf16
    unsigned short* ubf   = (unsigned short*)(ws + 16777216);// (8192x1024) bf16, u -> y
    unsigned short* dtybf = (unsigned short*)(ws + 20971520);// (8192x1024) bf16 dt
    unsigned short* xdbc  = (unsigned short*)(ws + 25165824);// (8192x64) bf16
    float* hp  = ws + 25427968;                              // 2M f {h,prod}
    unsigned short* xsbf = (unsigned short*)(ws + 27525120); // (8192x512) bf16
    unsigned short* mbf  = (unsigned short*)(ws + 29622272); // motion bf16
    unsigned short* ipw  = (unsigned short*)(ws + 30670848); // 1M elems bf16
    unsigned short* wdt64= (unsigned short*)(ws + 31195136); // 64K elems bf16
    unsigned short* opw  = (unsigned short*)(ws + 31227904); // 512K elems bf16
    unsigned short* xpw  = (unsigned short*)(ws + 31490048); // 64K elems bf16

    unsigned short* x0bf = xzbf;   // (8192x1024) bf16, dead after stage 2

    dim3 blk(256);

    // --- Stage 1: upsample (MFMA, bf16) + concat ---
    cvt_bf16<<<dim3(1024), blk, 0, stream>>>(motion, mbf, 262144);
    transpose_wup_bf<<<dim3(1024), blk, 0, stream>>>(w_up, ipw);
    for (int k = 0; k < 2; ++k) {
        gemm_mfma<0, false, false, true><<<dim3(128), blk, 0, stream>>>(
            mbf, 512, ipw + (size_t)k * 262144, 512,
            x0bf + (size_t)k * 1024, 2048, 512, 512, 4, b_up, nullptr);
    }
    concat_skip<<<dim3(2048), blk, 0, stream>>>(skip, x0bf);

    // --- Stage 2: xlnf = x0 @ w1^T + b1 ; rmsnorm+silu -> xsbf ---
    cvt_bf16<<<dim3(256), blk, 0, stream>>>(w1, ipw, 65536);
    gemm_mfma<0, false, false, false><<<dim3(256), blk, 0, stream>>>(
        x0bf, 1024, ipw, 1024, xlnf, 512, 512, 1024, 4, b1, nullptr);
    rms_silu_k<<<dim3(2048), blk, 0, stream>>>(xlnf, xsbf, rms_w);

    // --- Stage 3: xbuf = xs @ w2^T + b2 + embed ---
    cvt_bf16<<<dim3(128), blk, 0, stream>>>(w2, ipw, 32768);
    gemm_mfma<0, false, true, false><<<dim3(256), blk, 0, stream>>>(
        xsbf, 512, ipw, 512, xbuf, 512, 512, 512, 4, b2, embed);

    // --- Mamba blocks ---
    for (int i = 0; i < 4; ++i) {
        layernorm_k<true><<<dim3(2048), blk, 0, stream>>>(
            xbuf, xsbf, ln_w + (size_t)i * 512, ln_b + (size_t)i * 512);
        prep_w<<<dim3(1056), blk, 0, stream>>>(
            in_proj_w + (size_t)i * 1048576, out_proj_w + (size_t)i * 524288,
            x_proj_w + (size_t)i * 65536, dt_proj_w + (size_t)i * 32768,
            ipw, opw, xpw, wdt64);
        // xz = xln @ in_proj^T  (bf16 out)
        gemm_mfma<0, false, false, true><<<dim3(1024), blk, 0, stream>>>(
            xsbf, 512, ipw, 512, xzbf, 2048, 2048, 512, 16, nullptr, nullptr);
        // conv + silu -> u (bf16)
        conv_silu_k2<<<dim3(512), blk, 0, stream>>>(
            xzbf, ubf, conv_w + (size_t)i * 4096, conv_b + (size_t)i * 1024);
        // xdbc = u @ x_proj^T  (8192x64, bf16)
        gemm_xdbc<<<dim3(128), dim3(128), 0, stream>>>(ubf, xpw, xdbc);
        // dt = softplus(xdbc @ wdt64^T + dtb)  (K=64, cols 32..63 of W are 0)
        gemm_mfma<1, false, false, true><<<dim3(512), blk, 0, stream>>>(
            xdbc, 64, wdt64, 64, dtybf, 1024, 1024, 64, 8,
            dt_proj_b + (size_t)i * 1024, nullptr);
        // selective scan: phase1 (chunk summaries), phase2 (y + gate, bf16)
        scan4<1><<<dim3(1024), blk, 0, stream>>>(
            dtybf, ubf, nullptr, xdbc, xzbf, hp,
            A_log + (size_t)i * 16384, D_param + (size_t)i * 1024);
        scan4<2><<<dim3(1024), blk, 0, stream>>>(
            dtybf, ubf, ubf, xdbc, xzbf, hp,
            A_log + (size_t)i * 16384, D_param + (size_t)i * 1024);
        // xbuf += y @ out_proj^T + ob
        gemm_mfma<0, true, false, false><<<dim3(256), blk, 0, stream>>>(
            ubf, 1024, opw, 1024, xbuf, 512, 512, 1024, 4,
            out_proj_b + (size_t)i * 512, nullptr);
    }

    // --- Final layernorm -> out ---
    layernorm_k<false><<<dim3(2048), blk, 0, stream>>>(xbuf, out, norm_f_w, norm_f_b);
}

// Round 7
// 738.213 us; speedup vs baseline: 6.4027x; 1.4026x over previous
//
#include <hip/hip_runtime.h>
#include <cstdint>
#include <cstddef>

#define DEV_INLINE __device__ __forceinline__

static constexpr float EPS = 1e-5f;

DEV_INLINE float sigmoidf_(float x) { return 1.0f / (1.0f + __expf(-x)); }
DEV_INLINE float siluf_(float x) { return x * sigmoidf_(x); }
DEV_INLINE float softplus_fast(float x) {   // HW exp/log; error ~1e-7 abs
    return fmaxf(x, 0.0f) + __logf(1.0f + __expf(-fabsf(x)));
}
DEV_INLINE unsigned short f2bf(float x) {   // RNE f32 -> bf16
    unsigned u = __builtin_bit_cast(unsigned, x);
    u += 0x7FFFu + ((u >> 16) & 1u);
    return (unsigned short)(u >> 16);
}
DEV_INLINE float bf2f(unsigned short s) {
    unsigned u = ((unsigned)s) << 16;
    return __builtin_bit_cast(float, u);
}

typedef __attribute__((ext_vector_type(8))) short bf16x8;
typedef __attribute__((ext_vector_type(4))) float f32x4;

DEV_INLINE void gload16(const unsigned short* src, char* ldsdst) {
    __builtin_amdgcn_global_load_lds(
        (const __attribute__((address_space(1))) unsigned int*)src,
        (__attribute__((address_space(3))) unsigned int*)ldsdst, 16, 0, 0);
}

DEV_INLINE void cvt8(const float* __restrict__ s, unsigned short* __restrict__ d, int t) {
    float4 f0 = *(const float4*)(s + (size_t)t * 8);
    float4 f1 = *(const float4*)(s + (size_t)t * 8 + 4);
    union { unsigned short u[8]; uint4 v; } pk;
    pk.u[0] = f2bf(f0.x); pk.u[1] = f2bf(f0.y); pk.u[2] = f2bf(f0.z); pk.u[3] = f2bf(f0.w);
    pk.u[4] = f2bf(f1.x); pk.u[5] = f2bf(f1.y); pk.u[6] = f2bf(f1.z); pk.u[7] = f2bf(f1.w);
    *(uint4*)(d + (size_t)t * 8) = pk.v;
}

// ---------------------------------------------------------------------------
__global__ __launch_bounds__(256) void cvt_bf16(
    const float* __restrict__ s, unsigned short* __restrict__ d, int n8)
{
    int t = blockIdx.x * 256 + (int)threadIdx.x;
    if (t >= n8) return;
    cvt8(s, d, t);
}

// w_up (512,512,2) f32 -> wt bf16 [k][o][c]
__global__ __launch_bounds__(256) void transpose_wup_bf(
    const float* __restrict__ wup, unsigned short* __restrict__ wt)
{
    int t = blockIdx.x * 256 + (int)threadIdx.x;   // t = c*512 + o
    if (t >= 512 * 512) return;
    int c = t >> 9, o = t & 511;
    float2 v = *(const float2*)(wup + (size_t)t * 2);
    wt[(size_t)o * 512 + c] = f2bf(v.x);
    wt[262144 + (size_t)o * 512 + c] = f2bf(v.y);
}

// ---------------------------------------------------------------------------
// Per-mamba-block weight prep: bf16 converts (incl. true dt_proj 1024x32).
// grid = 16 (wdt32) + 512 (ipw) + 256 (opw) + 32 (xpw) = 816
// ---------------------------------------------------------------------------
__global__ __launch_bounds__(256) void prep_w(
    const float* __restrict__ in_proj_w,   // (2048,512)
    const float* __restrict__ out_proj_w,  // (512,1024)
    const float* __restrict__ x_proj_w,    // (64,1024)
    const float* __restrict__ dt_proj_w,   // (1024,32)
    unsigned short* __restrict__ ipw,
    unsigned short* __restrict__ opw,
    unsigned short* __restrict__ xpw,      // (64,1024) bf16
    unsigned short* __restrict__ wdt32)    // (1024,32) bf16
{
    int bid = (int)blockIdx.x, tid = (int)threadIdx.x;
    if (bid < 16) {
        cvt8(dt_proj_w, wdt32, bid * 256 + tid);
    } else if (bid < 528) {
        cvt8(in_proj_w, ipw, (bid - 16) * 256 + tid);
    } else if (bid < 784) {
        cvt8(out_proj_w, opw, (bid - 528) * 256 + tid);
    } else {
        cvt8(x_proj_w, xpw, (bid - 784) * 256 + tid);
    }
}

// ---------------------------------------------------------------------------
// MFMA GEMM 128x128: C[M,N] (+)= A_bf16[M,K] * W_bf16[N,K]^T
// BK=64, 4 waves, double-buffered LDS, XCD-contiguous block remap.
// ---------------------------------------------------------------------------
template <int ACT, bool ACC, bool EMBED, bool OBF>
__global__ __launch_bounds__(256) void gemm_mfma(
    const unsigned short* __restrict__ A, int lda,
    const unsigned short* __restrict__ W, int ldw,
    void* __restrict__ Cv, int ldc, int N, int K, int gx,
    const float* __restrict__ bias, const float* __restrict__ embed)
{
    __shared__ unsigned short Asm[2][128 * 64];
    __shared__ unsigned short Wsm[2][128 * 64];
    const int tid = (int)threadIdx.x;
    const int lane = tid & 63;
    const int wv = tid >> 6;
    const int wm = wv >> 1, wn = wv & 1;

    const int nwg = (int)gridDim.x;
    const int lin = (int)blockIdx.x;
    const int logical = (lin & 7) * (nwg >> 3) + (lin >> 3);
    const int by = logical / gx;
    const int bx = logical - by * gx;
    const int bm = by * 128, bn = bx * 128;

    f32x4 acc[4][4] = {};

    const int l8 = lane >> 3;
    const int wc = lane & 7;
    const int wcg = wc ^ l8;

    const int NT = K >> 6;

    {
        char* aB = (char*)Asm[0];
        char* bB = (char*)Wsm[0];
#pragma unroll
        for (int i = 0; i < 4; ++i) {
            int rb = (i * 4 + wv) * 8;
            gload16(W + (size_t)(bn + rb + l8) * ldw + wcg * 8, bB + rb * 128);
            gload16(A + (size_t)(bm + rb + l8) * lda + wcg * 8, aB + rb * 128);
        }
    }
    __syncthreads();

    for (int t = 0; t < NT; ++t) {
        const int cur = t & 1;
        if (t + 1 < NT) {
            const int k1 = (t + 1) << 6;
            char* aB = (char*)Asm[cur ^ 1];
            char* bB = (char*)Wsm[cur ^ 1];
#pragma unroll
            for (int i = 0; i < 4; ++i) {
                int rb = (i * 4 + wv) * 8;
                gload16(W + (size_t)(bn + rb + l8) * ldw + k1 + wcg * 8, bB + rb * 128);
                gload16(A + (size_t)(bm + rb + l8) * lda + k1 + wcg * 8, aB + rb * 128);
            }
        }
        const char* aB = (const char*)Asm[cur];
        const char* bB = (const char*)Wsm[cur];
        const int rA = wm * 64 + (lane & 15);
        const int rB = wn * 64 + (lane & 15);
        const int q = lane >> 4;
#pragma unroll
        for (int kk = 0; kk < 2; ++kk) {
            bf16x8 af[4], bfr[4];
#pragma unroll
            for (int mi = 0; mi < 4; ++mi) {
                int row = rA + mi * 16;
                int ch = (kk * 4 + q) ^ (row & 7);
                af[mi] = *(const bf16x8*)(aB + row * 128 + ch * 16);
            }
#pragma unroll
            for (int ni = 0; ni < 4; ++ni) {
                int row = rB + ni * 16;
                int ch = (kk * 4 + q) ^ (row & 7);
                bfr[ni] = *(const bf16x8*)(bB + row * 128 + ch * 16);
            }
#pragma unroll
            for (int mi = 0; mi < 4; ++mi)
#pragma unroll
                for (int ni = 0; ni < 4; ++ni)
                    acc[mi][ni] = __builtin_amdgcn_mfma_f32_16x16x32_bf16(
                        af[mi], bfr[ni], acc[mi][ni], 0, 0, 0);
        }
        __syncthreads();
    }

    const int cn = lane & 15;
    const int r0 = (lane >> 4) * 4;
    const int eb = EMBED ? (bm >> 10) * N : 0;
#pragma unroll
    for (int ni = 0; ni < 4; ++ni) {
        int col = bn + wn * 64 + ni * 16 + cn;
        float add = bias ? bias[col] : 0.0f;
        if (EMBED) add += embed[eb + col];
#pragma unroll
        for (int mi = 0; mi < 4; ++mi) {
#pragma unroll
            for (int r = 0; r < 4; ++r) {
                int row = bm + wm * 64 + mi * 16 + r0 + r;
                float v = acc[mi][ni][r] + add;
                if (ACT == 1) v = softplus_fast(v);
                if (OBF) {
                    ((unsigned short*)Cv)[(size_t)row * ldc + col] = f2bf(v);
                } else {
                    float* p = (float*)Cv + (size_t)row * ldc + col;
                    if (ACC) *p += v; else *p = v;
                }
            }
        }
    }
}

// ---------------------------------------------------------------------------
// MFMA GEMM 64x64: same semantics, higher occupancy (32 KB LDS, grid 4x).
// For the N=512 GEMMs that were running at 1-2 blocks/CU.
// ---------------------------------------------------------------------------
template <int ACT, bool ACC, bool EMBED, bool OBF>
__global__ __launch_bounds__(256) void gemm_mfma64(
    const unsigned short* __restrict__ A, int lda,
    const unsigned short* __restrict__ W, int ldw,
    void* __restrict__ Cv, int ldc, int N, int K, int gx,
    const float* __restrict__ bias, const float* __restrict__ embed)
{
    __shared__ unsigned short Asm[2][64 * 64];
    __shared__ unsigned short Wsm[2][64 * 64];
    const int tid = (int)threadIdx.x;
    const int lane = tid & 63;
    const int wv = tid >> 6;
    const int wm = wv >> 1, wn = wv & 1;   // 2x2 wave grid, 32x32 per wave

    const int nwg = (int)gridDim.x;
    const int lin = (int)blockIdx.x;
    const int logical = (lin & 7) * (nwg >> 3) + (lin >> 3);
    const int by = logical / gx;
    const int bx = logical - by * gx;
    const int bm = by * 64, bn = bx * 64;

    f32x4 acc[2][2] = {};

    const int l8 = lane >> 3;
    const int wc = lane & 7;
    const int wcg = wc ^ l8;

    const int NT = K >> 6;

    {
        char* aB = (char*)Asm[0];
        char* bB = (char*)Wsm[0];
#pragma unroll
        for (int i = 0; i < 2; ++i) {
            int rb = (i * 4 + wv) * 8;
            gload16(W + (size_t)(bn + rb + l8) * ldw + wcg * 8, bB + rb * 128);
            gload16(A + (size_t)(bm + rb + l8) * lda + wcg * 8, aB + rb * 128);
        }
    }
    __syncthreads();

    for (int t = 0; t < NT; ++t) {
        const int cur = t & 1;
        if (t + 1 < NT) {
            const int k1 = (t + 1) << 6;
            char* aB = (char*)Asm[cur ^ 1];
            char* bB = (char*)Wsm[cur ^ 1];
#pragma unroll
            for (int i = 0; i < 2; ++i) {
                int rb = (i * 4 + wv) * 8;
                gload16(W + (size_t)(bn + rb + l8) * ldw + k1 + wcg * 8, bB + rb * 128);
                gload16(A + (size_t)(bm + rb + l8) * lda + k1 + wcg * 8, aB + rb * 128);
            }
        }
        const char* aB = (const char*)Asm[cur];
        const char* bB = (const char*)Wsm[cur];
        const int rA = wm * 32 + (lane & 15);
        const int rB = wn * 32 + (lane & 15);
        const int q = lane >> 4;
#pragma unroll
        for (int kk = 0; kk < 2; ++kk) {
            bf16x8 af[2], bfr[2];
#pragma unroll
            for (int mi = 0; mi < 2; ++mi) {
                int row = rA + mi * 16;
                int ch = (kk * 4 + q) ^ (row & 7);
                af[mi] = *(const bf16x8*)(aB + row * 128 + ch * 16);
            }
#pragma unroll
            for (int ni = 0; ni < 2; ++ni) {
                int row = rB + ni * 16;
                int ch = (kk * 4 + q) ^ (row & 7);
                bfr[ni] = *(const bf16x8*)(bB + row * 128 + ch * 16);
            }
#pragma unroll
            for (int mi = 0; mi < 2; ++mi)
#pragma unroll
                for (int ni = 0; ni < 2; ++ni)
                    acc[mi][ni] = __builtin_amdgcn_mfma_f32_16x16x32_bf16(
                        af[mi], bfr[ni], acc[mi][ni], 0, 0, 0);
        }
        __syncthreads();
    }

    const int cn = lane & 15;
    const int r0 = (lane >> 4) * 4;
    const int eb = EMBED ? (bm >> 10) * N : 0;
#pragma unroll
    for (int ni = 0; ni < 2; ++ni) {
        int col = bn + wn * 32 + ni * 16 + cn;
        float add = bias ? bias[col] : 0.0f;
        if (EMBED) add += embed[eb + col];
#pragma unroll
        for (int mi = 0; mi < 2; ++mi) {
#pragma unroll
            for (int r = 0; r < 4; ++r) {
                int row = bm + wm * 32 + mi * 16 + r0 + r;
                float v = acc[mi][ni][r] + add;
                if (ACT == 1) v = softplus_fast(v);
                if (OBF) {
                    ((unsigned short*)Cv)[(size_t)row * ldc + col] = f2bf(v);
                } else {
                    float* p = (float*)Cv + (size_t)row * ldc + col;
                    if (ACC) *p += v; else *p = v;
                }
            }
        }
    }
}

// ---------------------------------------------------------------------------
// dt GEMM: dt[8192,1024] = softplus(dtp[8192,32] @ dtw[1024,32]^T + bias)
// K=32 -> one MFMA per frag pair. Fragments loaded DIRECTLY from global
// (frag layout row=lane&15, k=(lane>>4)*8 is naturally coalesced).
// Output restaged through LDS for coalesced dwordx4 stores. Grid 512.
// ---------------------------------------------------------------------------
__global__ __launch_bounds__(256) void gemm_dt(
    const unsigned short* __restrict__ xdbc,  // (8192,64), dtp = cols [0,32)
    const unsigned short* __restrict__ wdt,   // (1024,32) bf16
    const float* __restrict__ bias,           // (1024)
    unsigned short* __restrict__ out)         // (8192,1024) bf16
{
    __shared__ unsigned short S[128 * 136];   // 34 KB out-stage, 136 = 17x8
    const int tid = (int)threadIdx.x;
    const int lane = tid & 63;
    const int wv = tid >> 6;
    const int wm = wv >> 1, wn = wv & 1;

    const int lin = (int)blockIdx.x;          // nwg = 512
    const int logical = (lin & 7) * 64 + (lin >> 3);
    const int bm = (logical >> 3) * 128;
    const int bn = (logical & 7) * 128;

    const int fr = lane & 15;
    const int q = lane >> 4;

    bf16x8 af[4], wf[4];
#pragma unroll
    for (int mi = 0; mi < 4; ++mi)
        af[mi] = *(const bf16x8*)(xdbc + (size_t)(bm + wm * 64 + mi * 16 + fr) * 64 + q * 8);
#pragma unroll
    for (int ni = 0; ni < 4; ++ni)
        wf[ni] = *(const bf16x8*)(wdt + (size_t)(bn + wn * 64 + ni * 16 + fr) * 32 + q * 8);

    f32x4 acc[4][4] = {};
#pragma unroll
    for (int mi = 0; mi < 4; ++mi)
#pragma unroll
        for (int ni = 0; ni < 4; ++ni)
            acc[mi][ni] = __builtin_amdgcn_mfma_f32_16x16x32_bf16(
                af[mi], wf[ni], acc[mi][ni], 0, 0, 0);

    const int cn = lane & 15;
    const int r0 = (lane >> 4) * 4;
#pragma unroll
    for (int ni = 0; ni < 4; ++ni) {
        int lcol = wn * 64 + ni * 16 + cn;
        float add = bias[bn + lcol];
#pragma unroll
        for (int mi = 0; mi < 4; ++mi) {
#pragma unroll
            for (int r = 0; r < 4; ++r) {
                int lrow = wm * 64 + mi * 16 + r0 + r;
                S[lrow * 136 + lcol] = f2bf(softplus_fast(acc[mi][ni][r] + add));
            }
        }
    }
    __syncthreads();

    // coalesced write-out: thread -> (row = tid>>1, half = tid&1), 128 B each
    const int row = tid >> 1;
    const int half = tid & 1;
    const unsigned short* src = S + row * 136 + half * 64;
    unsigned short* dst = out + (size_t)(bm + row) * 1024 + bn + half * 64;
#pragma unroll
    for (int k = 0; k < 8; ++k) {
        uint4 v = *(const uint4*)(src + k * 8);
        *(uint4*)(dst + k * 8) = v;
    }
}

// ---------------------------------------------------------------------------
// Skinny MFMA GEMM: xdbc[M,64] = u_bf16[M,1024] * xpw_bf16[64,1024]^T (bf16 out)
// ---------------------------------------------------------------------------
__global__ __launch_bounds__(128) void gemm_xdbc(
    const unsigned short* __restrict__ A,
    const unsigned short* __restrict__ W,
    unsigned short* __restrict__ C)
{
    __shared__ unsigned short Asm[64 * 64];
    __shared__ unsigned short Wsm[64 * 64];
    const int tid = (int)threadIdx.x;
    const int lane = tid & 63;
    const int w = tid >> 6;
    const int bm = blockIdx.x * 64;
    const int l8 = lane >> 3, wc = lane & 7, wcg = wc ^ l8;
    char* aB = (char*)Asm;
    char* bB = (char*)Wsm;

    f32x4 acc[2][4] = {};

    for (int k0 = 0; k0 < 1024; k0 += 64) {
#pragma unroll
        for (int i = 0; i < 4; ++i) {
            int rb = (i * 2 + w) * 8;
            gload16(A + (size_t)(bm + rb + l8) * 1024 + k0 + wcg * 8, aB + rb * 128);
            gload16(W + (size_t)(rb + l8) * 1024 + k0 + wcg * 8, bB + rb * 128);
        }
        __syncthreads();
        const int rA = w * 32 + (lane & 15);
        const int rB = (lane & 15);
        const int q = lane >> 4;
#pragma unroll
        for (int kk = 0; kk < 2; ++kk) {
            bf16x8 af[2], bfr[4];
#pragma unroll
            for (int mi = 0; mi < 2; ++mi) {
                int row = rA + mi * 16;
                int ch = (kk * 4 + q) ^ (row & 7);
                af[mi] = *(const bf16x8*)(aB + row * 128 + ch * 16);
            }
#pragma unroll
            for (int ni = 0; ni < 4; ++ni) {
                int row = rB + ni * 16;
                int ch = (kk * 4 + q) ^ (row & 7);
                bfr[ni] = *(const bf16x8*)(bB + row * 128 + ch * 16);
            }
#pragma unroll
            for (int mi = 0; mi < 2; ++mi)
#pragma unroll
                for (int ni = 0; ni < 4; ++ni)
                    acc[mi][ni] = __builtin_amdgcn_mfma_f32_16x16x32_bf16(
                        af[mi], bfr[ni], acc[mi][ni], 0, 0, 0);
        }
        __syncthreads();
    }
    const int cn = lane & 15;
    const int r0 = (lane >> 4) * 4;
#pragma unroll
    for (int mi = 0; mi < 2; ++mi)
#pragma unroll
        for (int ni = 0; ni < 4; ++ni)
#pragma unroll
            for (int r = 0; r < 4; ++r) {
                int row = bm + w * 32 + mi * 16 + r0 + r;
                C[(size_t)row * 64 + ni * 16 + cn] = f2bf(acc[mi][ni][r]);
            }
}

// ---------------------------------------------------------------------------
__global__ __launch_bounds__(256) void concat_skip(
    const float* __restrict__ skip, unsigned short* __restrict__ x0)
{
    int t = blockIdx.x * 256 + (int)threadIdx.x;
    int row = t >> 6;
    int c8 = (t & 63) << 3;
    const float* s = skip + (size_t)row * 512 + c8;
    float4 f0 = *(const float4*)s;
    float4 f1 = *(const float4*)(s + 4);
    union { unsigned short u[8]; uint4 v; } pk;
    pk.u[0] = f2bf(f0.x); pk.u[1] = f2bf(f0.y); pk.u[2] = f2bf(f0.z); pk.u[3] = f2bf(f0.w);
    pk.u[4] = f2bf(f1.x); pk.u[5] = f2bf(f1.y); pk.u[6] = f2bf(f1.z); pk.u[7] = f2bf(f1.w);
    *(uint4*)(x0 + (size_t)row * 1024 + 512 + c8) = pk.v;
}

// ---------------------------------------------------------------------------
template <bool BFOUT>
__global__ __launch_bounds__(256) void layernorm_k(
    const float* __restrict__ x, void* __restrict__ outp,
    const float* __restrict__ w, const float* __restrict__ b)
{
    const int row = blockIdx.x * 4 + ((int)threadIdx.x >> 6);
    const int lane = (int)threadIdx.x & 63;
    const float* xr = x + (size_t)row * 512;
    float4 v0 = *(const float4*)(xr + lane * 4);
    float4 v1 = *(const float4*)(xr + 256 + lane * 4);
    float s = v0.x + v0.y + v0.z + v0.w + v1.x + v1.y + v1.z + v1.w;
    float q = v0.x*v0.x + v0.y*v0.y + v0.z*v0.z + v0.w*v0.w
            + v1.x*v1.x + v1.y*v1.y + v1.z*v1.z + v1.w*v1.w;
#pragma unroll
    for (int o = 32; o; o >>= 1) {
        s += __shfl_xor(s, o, 64);
        q += __shfl_xor(q, o, 64);
    }
    const float mean = s * (1.0f / 512.0f);
    const float var = q * (1.0f / 512.0f) - mean * mean;
    const float rstd = rsqrtf(var + EPS);
    float4 w0 = *(const float4*)(w + lane * 4);
    float4 w1 = *(const float4*)(w + 256 + lane * 4);
    float4 b0 = *(const float4*)(b + lane * 4);
    float4 b1 = *(const float4*)(b + 256 + lane * 4);
    float4 o0, o1;
    o0.x = (v0.x - mean) * rstd * w0.x + b0.x;
    o0.y = (v0.y - mean) * rstd * w0.y + b0.y;
    o0.z = (v0.z - mean) * rstd * w0.z + b0.z;
    o0.w = (v0.w - mean) * rstd * w0.w + b0.w;
    o1.x = (v1.x - mean) * rstd * w1.x + b1.x;
    o1.y = (v1.y - mean) * rstd * w1.y + b1.y;
    o1.z = (v1.z - mean) * rstd * w1.z + b1.z;
    o1.w = (v1.w - mean) * rstd * w1.w + b1.w;
    if (BFOUT) {
        unsigned short* ob = (unsigned short*)outp + (size_t)row * 512;
        union { unsigned short u[4]; uint2 v; } p0, p1;
        p0.u[0] = f2bf(o0.x); p0.u[1] = f2bf(o0.y); p0.u[2] = f2bf(o0.z); p0.u[3] = f2bf(o0.w);
        p1.u[0] = f2bf(o1.x); p1.u[1] = f2bf(o1.y); p1.u[2] = f2bf(o1.z); p1.u[3] = f2bf(o1.w);
        *(uint2*)(ob + lane * 4) = p0.v;
        *(uint2*)(ob + 256 + lane * 4) = p1.v;
    } else {
        float* orow = (float*)outp + (size_t)row * 512;
        *(float4*)(orow + lane * 4) = o0;
        *(float4*)(orow + 256 + lane * 4) = o1;
    }
}

__global__ __launch_bounds__(256) void rms_silu_k(
    const float* __restrict__ x, unsigned short* __restrict__ o,
    const float* __restrict__ w)
{
    const int row = blockIdx.x * 4 + ((int)threadIdx.x >> 6);
    const int lane = (int)threadIdx.x & 63;
    const float* xr = x + (size_t)row * 512;
    float4 v0 = *(const float4*)(xr + lane * 4);
    float4 v1 = *(const float4*)(xr + 256 + lane * 4);
    float q = v0.x*v0.x + v0.y*v0.y + v0.z*v0.z + v0.w*v0.w
            + v1.x*v1.x + v1.y*v1.y + v1.z*v1.z + v1.w*v1.w;
#pragma unroll
    for (int of = 32; of; of >>= 1) q += __shfl_xor(q, of, 64);
    const float scale = rsqrtf(q * (1.0f / 512.0f) + EPS);
    float4 w0 = *(const float4*)(w + lane * 4);
    float4 w1 = *(const float4*)(w + 256 + lane * 4);
    union { unsigned short u[4]; uint2 v; } p0, p1;
    p0.u[0] = f2bf(siluf_(v0.x * scale * w0.x));
    p0.u[1] = f2bf(siluf_(v0.y * scale * w0.y));
    p0.u[2] = f2bf(siluf_(v0.z * scale * w0.z));
    p0.u[3] = f2bf(siluf_(v0.w * scale * w0.w));
    p1.u[0] = f2bf(siluf_(v1.x * scale * w1.x));
    p1.u[1] = f2bf(siluf_(v1.y * scale * w1.y));
    p1.u[2] = f2bf(siluf_(v1.z * scale * w1.z));
    p1.u[3] = f2bf(siluf_(v1.w * scale * w1.w));
    unsigned short* ob = o + (size_t)row * 512;
    *(uint2*)(ob + lane * 4) = p0.v;
    *(uint2*)(ob + 256 + lane * 4) = p1.v;
}

// ---------------------------------------------------------------------------
// Causal depthwise conv(k=4)+bias+silu: xz bf16 cols[0,1024) -> u bf16.
// ---------------------------------------------------------------------------
__global__ __launch_bounds__(256) void conv_silu_k2(
    const unsigned short* __restrict__ xz, unsigned short* __restrict__ ub,
    const float* __restrict__ cw, const float* __restrict__ cb)
{
    int t = blockIdx.x * 256 + (int)threadIdx.x;
    int d = t & 1023;
    int bc = t >> 10;
    int b = bc >> 4, ch = bc & 15;
    int l0 = ch * 64;
    float4 w4 = *(const float4*)(cw + (size_t)d * 4);
    float bias = cb[d];
    const unsigned short* src = xz + ((size_t)(b * 1024 + l0)) * 2048 + d;
    unsigned short* dst = ub + ((size_t)(b * 1024 + l0)) * 1024 + d;
    float x0 = 0.f, x1 = 0.f, x2 = 0.f;
    if (l0 > 0) {
        x0 = bf2f(src[-(size_t)3 * 2048]);
        x1 = bf2f(src[-(size_t)2 * 2048]);
        x2 = bf2f(src[-(size_t)1 * 2048]);
    }
    for (int l = 0; l < 64; ++l) {
        float x3 = bf2f(src[(size_t)l * 2048]);
        float v = fmaf(x0, w4.x, fmaf(x1, w4.y, fmaf(x2, w4.z, fmaf(x3, w4.w, bias))));
        dst[(size_t)l * 1024] = f2bf(siluf_(v));
        x0 = x1; x1 = x2; x2 = x3;
    }
}

// ---------------------------------------------------------------------------
// Split-L selective scan v4: 4 states per lane, 64 d's per block.
// ---------------------------------------------------------------------------
template <int CTRL>
DEV_INLINE float dpp_f(float x) {
    int yi = __builtin_amdgcn_update_dpp(
        0, __builtin_bit_cast(int, x), CTRL, 0xF, 0xF, true);
    return __builtin_bit_cast(float, yi);
}

template <int PHASE>
__global__ __launch_bounds__(256) void scan4(
    const unsigned short* __restrict__ dtp,  // (8192,1024) bf16 dt
    const unsigned short* ubf,               // (8192,1024) bf16 u (aliases ybf)
    unsigned short* ybf,                     // phase2 out (gated y)
    const unsigned short* __restrict__ xdbc, // (8192,64) bf16: dtp|B|C
    const unsigned short* __restrict__ zbf,  // z = xz bf16 cols [1024,2048)
    float* __restrict__ hp,                  // per (b,d,c,n): {h,prod}
    const float* __restrict__ A_log,
    const float* __restrict__ Dp)
{
    __shared__ float SDT[32][132];           // {dt, dt*u} pairs per d
    __shared__ float SB[32][20];
    __shared__ float SC[PHASE == 2 ? 32 : 1][20];
    __shared__ float YS[PHASE == 2 ? 32 : 1][68];

    const int lin = (int)blockIdx.x;
    const int logical = (lin & 7) * 128 + (lin >> 3);
    const int gg = logical & 15;             // d-group (64 d's)
    const int rr0 = logical >> 4;            // b*8 + c
    const int c = rr0 & 7, b = rr0 >> 3;
    if (PHASE == 1 && c == 7) return;
    const int tid = (int)threadIdx.x;
    const int dl = tid >> 2, q = tid & 3;
    const int dblk = gg << 6;
    const int d = dblk + dl;
    const int m0 = b * 1024 + c * 128;

    float An[4];
#pragma unroll
    for (int j = 0; j < 4; ++j)
        An[j] = -__expf(A_log[(size_t)d * 16 + q * 4 + j]);

    float h[4] = {};
    float prod[4] = {1.f, 1.f, 1.f, 1.f};
    if (PHASE == 2) {
        const float* hpb = hp + ((size_t)(b * 1024 + d)) * 256 + q * 8;
        for (int cc = 0; cc < c; ++cc) {
            float4 v0 = *(const float4*)(hpb + cc * 32);
            float4 v1 = *(const float4*)(hpb + cc * 32 + 4);
            h[0] = fmaf(v0.y, h[0], v0.x);
            h[1] = fmaf(v0.w, h[1], v0.z);
            h[2] = fmaf(v1.y, h[2], v1.x);
            h[3] = fmaf(v1.w, h[3], v1.z);
        }
    }

    const int sr = tid >> 3;                 // staging row 0..31
    const int c8 = tid & 7;                  // 8-wide column group
    const int bcr = (tid & 127) >> 2;        // B/C row
    const int bne = (tid & 3) << 2;          // B/C n-offset

    for (int s = 0; s < 4; ++s) {
        const int lbase = s * 32;
        {
            size_t gr = (size_t)(m0 + lbase + sr);
            uint4 d8 = *(const uint4*)(dtp + gr * 1024 + dblk + c8 * 8);
            uint4 u8 = *(const uint4*)(ubf + gr * 1024 + dblk + c8 * 8);
            const unsigned* dw = (const unsigned*)&d8;
            const unsigned* uw = (const unsigned*)&u8;
#pragma unroll
            for (int k = 0; k < 4; ++k) {
                float dt0 = bf2f((unsigned short)(dw[k] & 0xffff));
                float dt1 = bf2f((unsigned short)(dw[k] >> 16));
                float uu0 = bf2f((unsigned short)(uw[k] & 0xffff));
                float uu1 = bf2f((unsigned short)(uw[k] >> 16));
                float4 wv = {dt0, dt0 * uu0, dt1, dt1 * uu1};
                *(float4*)&SDT[sr][c8 * 16 + k * 4] = wv;
            }
        }
        {
            size_t gr = (size_t)(m0 + lbase + bcr);
            if (tid < 128) {
                uint2 Bu = *(const uint2*)(xdbc + gr * 64 + 32 + bne);
                SB[bcr][bne + 0] = bf2f((unsigned short)(Bu.x & 0xffff));
                SB[bcr][bne + 1] = bf2f((unsigned short)(Bu.x >> 16));
                SB[bcr][bne + 2] = bf2f((unsigned short)(Bu.y & 0xffff));
                SB[bcr][bne + 3] = bf2f((unsigned short)(Bu.y >> 16));
            } else if (PHASE == 2) {
                uint2 Cu = *(const uint2*)(xdbc + gr * 64 + 48 + bne);
                SC[bcr][bne + 0] = bf2f((unsigned short)(Cu.x & 0xffff));
                SC[bcr][bne + 1] = bf2f((unsigned short)(Cu.x >> 16));
                SC[bcr][bne + 2] = bf2f((unsigned short)(Cu.y & 0xffff));
                SC[bcr][bne + 3] = bf2f((unsigned short)(Cu.y >> 16));
            }
        }
        __syncthreads();

        for (int l = 0; l < 32; ++l) {
            float2 dd = *(const float2*)&SDT[l][2 * dl];
            float4 Bv = *(const float4*)&SB[l][q * 4];
            float p = 0.0f;
            float4 Cv;
            if (PHASE == 2) Cv = *(const float4*)&SC[l][q * 4];
            const float* Bp = (const float*)&Bv;
            const float* Cp = (const float*)&Cv;
#pragma unroll
            for (int j = 0; j < 4; ++j) {
                float e = __expf(dd.x * An[j]);
                if (PHASE == 1) prod[j] *= e;
                h[j] = fmaf(e, h[j], dd.y * Bp[j]);
                if (PHASE == 2) p = fmaf(h[j], Cp[j], p);
            }
            if (PHASE == 2) {
                p += dpp_f<0xB1>(p);
                p += dpp_f<0x4E>(p);
                if (q == 0) YS[l][dl] = p;
            }
        }
        __syncthreads();

        if (PHASE == 2) {
#pragma unroll
            for (int j2 = 0; j2 < 2; ++j2) {
                int task = tid + j2 * 256;
                int rw = task >> 4;
                int e4 = (task & 15) << 2;
                size_t gr = (size_t)(m0 + lbase + rw);
                float4 p4 = *(const float4*)&YS[rw][e4];
                uint2 uu = *(const uint2*)(ubf + gr * 1024 + dblk + e4);
                uint2 zz = *(const uint2*)(zbf + gr * 2048 + 1024 + dblk + e4);
                float4 Dv = *(const float4*)(Dp + dblk + e4);
                float y0 = fmaf(bf2f((unsigned short)(uu.x & 0xffff)), Dv.x, p4.x)
                         * siluf_(bf2f((unsigned short)(zz.x & 0xffff)));
                float y1 = fmaf(bf2f((unsigned short)(uu.x >> 16)), Dv.y, p4.y)
                         * siluf_(bf2f((unsigned short)(zz.x >> 16)));
                float y2 = fmaf(bf2f((unsigned short)(uu.y & 0xffff)), Dv.z, p4.z)
                         * siluf_(bf2f((unsigned short)(zz.y & 0xffff)));
                float y3 = fmaf(bf2f((unsigned short)(uu.y >> 16)), Dv.w, p4.w)
                         * siluf_(bf2f((unsigned short)(zz.y >> 16)));
                union { unsigned short u[4]; uint2 v; } pk;
                pk.u[0] = f2bf(y0); pk.u[1] = f2bf(y1);
                pk.u[2] = f2bf(y2); pk.u[3] = f2bf(y3);
                *(uint2*)(ybf + gr * 1024 + dblk + e4) = pk.v;
            }
        }
    }

    if (PHASE == 1) {
        float* hpo = hp + ((size_t)(b * 1024 + d)) * 256 + c * 32 + q * 8;
        float4 o0 = {h[0], prod[0], h[1], prod[1]};
        float4 o1 = {h[2], prod[2], h[3], prod[3]};
        *(float4*)hpo = o0;
        *(float4*)(hpo + 4) = o1;
    }
}

// ---------------------------------------------------------------------------
extern "C" void kernel_launch(void* const* d_in, const int* in_sizes, int n_in,
                              void* d_out, int out_size, void* d_ws, size_t ws_size,
                              hipStream_t stream)
{
    const float* motion     = (const float*)d_in[0];
    const float* skip       = (const float*)d_in[1];
    const float* embed      = (const float*)d_in[2];
    const float* w_up       = (const float*)d_in[3];
    const float* b_up       = (const float*)d_in[4];
    const float* w1         = (const float*)d_in[5];
    const float* b1         = (const float*)d_in[6];
    const float* rms_w      = (const float*)d_in[7];
    const float* w2         = (const float*)d_in[8];
    const float* b2         = (const float*)d_in[9];
    const float* ln_w       = (const float*)d_in[10];
    const float* ln_b       = (const float*)d_in[11];
    const float* in_proj_w  = (const float*)d_in[12];
    const float* conv_w     = (const float*)d_in[13];
    const float* conv_b     = (const float*)d_in[14];
    const float* x_proj_w   = (const float*)d_in[15];
    const float* dt_proj_w  = (const float*)d_in[16];
    const float* dt_proj_b  = (const float*)d_in[17];
    const float* A_log      = (const float*)d_in[18];
    const float* D_param    = (const float*)d_in[19];
    const float* out_proj_w = (const float*)d_in[20];
    const float* out_proj_b = (const float*)d_in[21];
    const float* norm_f_w   = (const float*)d_in[22];
    const float* norm_f_b   = (const float*)d_in[23];
    float* out = (float*)d_out;
    float* ws = (float*)d_ws;

    // Workspace (float offsets):
    float* xbuf = ws;                                        // (8192x512) f32
    float* xlnf = ws + 4194304;                              // (8192x512) f32 temp
    unsigned short* xzbf  = (unsigned short*)(ws + 8388608); // (8192x2048) bf16
    unsigned short* ubf   = (unsigned short*)(ws + 16777216);// (8192x1024) bf16, u -> y
    unsigned short* dtybf = (unsigned short*)(ws + 20971520);// (8192x1024) bf16 dt
    unsigned short* xdbc  = (unsigned short*)(ws + 25165824);// (8192x64) bf16
    float* hp  = ws + 25427968;                              // 2M f {h,prod}
    unsigned short* xsbf = (unsigned short*)(ws + 27525120); // (8192x512) bf16
    unsigned short* mbf  = (unsigned short*)(ws + 29622272); // motion bf16
    unsigned short* ipw  = (unsigned short*)(ws + 30670848); // 1M elems bf16
    unsigned short* wdt32= (unsigned short*)(ws + 31195136); // 32K elems bf16
    unsigned short* opw  = (unsigned short*)(ws + 31227904); // 512K elems bf16
    unsigned short* xpw  = (unsigned short*)(ws + 31490048); // 64K elems bf16

    unsigned short* x0bf = xzbf;   // (8192x1024) bf16, dead after stage 2

    dim3 blk(256);

    // --- Stage 1: upsample (MFMA, bf16) + concat ---
    cvt_bf16<<<dim3(1024), blk, 0, stream>>>(motion, mbf, 262144);
    transpose_wup_bf<<<dim3(1024), blk, 0, stream>>>(w_up, ipw);
    for (int k = 0; k < 2; ++k) {
        gemm_mfma64<0, false, false, true><<<dim3(1024), blk, 0, stream>>>(
            mbf, 512, ipw + (size_t)k * 262144, 512,
            x0bf + (size_t)k * 1024, 2048, 512, 512, 8, b_up, nullptr);
    }
    concat_skip<<<dim3(2048), blk, 0, stream>>>(skip, x0bf);

    // --- Stage 2: xlnf = x0 @ w1^T + b1 ; rmsnorm+silu -> xsbf ---
    cvt_bf16<<<dim3(256), blk, 0, stream>>>(w1, ipw, 65536);
    gemm_mfma64<0, false, false, false><<<dim3(1024), blk, 0, stream>>>(
        x0bf, 1024, ipw, 1024, xlnf, 512, 512, 1024, 8, b1, nullptr);
    rms_silu_k<<<dim3(2048), blk, 0, stream>>>(xlnf, xsbf, rms_w);

    // --- Stage 3: xbuf = xs @ w2^T + b2 + embed ---
    cvt_bf16<<<dim3(128), blk, 0, stream>>>(w2, ipw, 32768);
    gemm_mfma64<0, false, true, false><<<dim3(1024), blk, 0, stream>>>(
        xsbf, 512, ipw, 512, xbuf, 512, 512, 512, 8, b2, embed);

    // --- Mamba blocks ---
    for (int i = 0; i < 4; ++i) {
        layernorm_k<true><<<dim3(2048), blk, 0, stream>>>(
            xbuf, xsbf, ln_w + (size_t)i * 512, ln_b + (size_t)i * 512);
        prep_w<<<dim3(816), blk, 0, stream>>>(
            in_proj_w + (size_t)i * 1048576, out_proj_w + (size_t)i * 524288,
            x_proj_w + (size_t)i * 65536, dt_proj_w + (size_t)i * 32768,
            ipw, opw, xpw, wdt32);
        // xz = xln @ in_proj^T  (bf16 out)  [128-tile, 4 blocks/CU]
        gemm_mfma<0, false, false, true><<<dim3(1024), blk, 0, stream>>>(
            xsbf, 512, ipw, 512, xzbf, 2048, 2048, 512, 16, nullptr, nullptr);
        // conv + silu -> u (bf16)
        conv_silu_k2<<<dim3(512), blk, 0, stream>>>(
            xzbf, ubf, conv_w + (size_t)i * 4096, conv_b + (size_t)i * 1024);
        // xdbc = u @ x_proj^T  (8192x64, bf16)
        gemm_xdbc<<<dim3(128), dim3(128), 0, stream>>>(ubf, xpw, xdbc);
        // dt = softplus(dtp @ dtw^T + dtb)  (dedicated K=32 kernel)
        gemm_dt<<<dim3(512), blk, 0, stream>>>(
            xdbc, wdt32, dt_proj_b + (size_t)i * 1024, dtybf);
        // selective scan: phase1 (chunk summaries), phase2 (y + gate, bf16)
        scan4<1><<<dim3(1024), blk, 0, stream>>>(
            dtybf, ubf, nullptr, xdbc, xzbf, hp,
            A_log + (size_t)i * 16384, D_param + (size_t)i * 1024);
        scan4<2><<<dim3(1024), blk, 0, stream>>>(
            dtybf, ubf, ubf, xdbc, xzbf, hp,
            A_log + (size_t)i * 16384, D_param + (size_t)i * 1024);
        // xbuf += y @ out_proj^T + ob  [64-tile, high occupancy]
        gemm_mfma64<0, true, false, false><<<dim3(1024), blk, 0, stream>>>(
            ubf, 1024, opw, 1024, xbuf, 512, 512, 1024, 8,
            out_proj_b + (size_t)i * 512, nullptr);
    }

    // --- Final layernorm -> out ---
    layernorm_k<false><<<dim3(2048), blk, 0, stream>>>(xbuf, out, norm_f_w, norm_f_b);
}

// Round 8
// 692.348 us; speedup vs baseline: 6.8269x; 1.0662x over previous
//
#include <hip/hip_runtime.h>
#include <cstdint>
#include <cstddef>

#define DEV_INLINE __device__ __forceinline__

static constexpr float EPS = 1e-5f;

DEV_INLINE float sigmoidf_(float x) { return 1.0f / (1.0f + __expf(-x)); }
DEV_INLINE float siluf_(float x) { return x * sigmoidf_(x); }
DEV_INLINE float softplus_fast(float x) {
    return fmaxf(x, 0.0f) + __logf(1.0f + __expf(-fabsf(x)));
}
DEV_INLINE unsigned short f2bf(float x) {   // RNE f32 -> bf16
    unsigned u = __builtin_bit_cast(unsigned, x);
    u += 0x7FFFu + ((u >> 16) & 1u);
    return (unsigned short)(u >> 16);
}
DEV_INLINE float bf2f(unsigned short s) {
    unsigned u = ((unsigned)s) << 16;
    return __builtin_bit_cast(float, u);
}

typedef __attribute__((ext_vector_type(8))) short bf16x8;
typedef __attribute__((ext_vector_type(4))) float f32x4;

DEV_INLINE void gload16(const unsigned short* src, char* ldsdst) {
    __builtin_amdgcn_global_load_lds(
        (const __attribute__((address_space(1))) unsigned int*)src,
        (__attribute__((address_space(3))) unsigned int*)ldsdst, 16, 0, 0);
}

DEV_INLINE void cvt8(const float* __restrict__ s, unsigned short* __restrict__ d, int t) {
    float4 f0 = *(const float4*)(s + (size_t)t * 8);
    float4 f1 = *(const float4*)(s + (size_t)t * 8 + 4);
    union { unsigned short u[8]; uint4 v; } pk;
    pk.u[0] = f2bf(f0.x); pk.u[1] = f2bf(f0.y); pk.u[2] = f2bf(f0.z); pk.u[3] = f2bf(f0.w);
    pk.u[4] = f2bf(f1.x); pk.u[5] = f2bf(f1.y); pk.u[6] = f2bf(f1.z); pk.u[7] = f2bf(f1.w);
    *(uint4*)(d + (size_t)t * 8) = pk.v;
}

// ---------------------------------------------------------------------------
// One-shot prep: motion cvt | w_up transpose | w1 | w2 | 4x layer weights.
// grid = 1024 + 1024 + 256 + 128 + 4*816 = 5696
// ---------------------------------------------------------------------------
__global__ __launch_bounds__(256) void prep_all(
    const float* __restrict__ motion, const float* __restrict__ wup,
    const float* __restrict__ w1, const float* __restrict__ w2,
    const float* __restrict__ in_proj_w, const float* __restrict__ out_proj_w,
    const float* __restrict__ x_proj_w, const float* __restrict__ dt_proj_w,
    unsigned short* __restrict__ mbf, unsigned short* __restrict__ wupT,
    unsigned short* __restrict__ w1b, unsigned short* __restrict__ w2b,
    unsigned short* __restrict__ lw)   // per layer: ipw|opw|xpw|wdt32
{
    int bid = (int)blockIdx.x, tid = (int)threadIdx.x;
    if (bid < 1024) {
        cvt8(motion, mbf, bid * 256 + tid);
    } else if (bid < 2048) {
        int t = (bid - 1024) * 256 + tid;        // t = c*512 + o
        int c = t >> 9, o = t & 511;
        float2 v = *(const float2*)(wup + (size_t)t * 2);
        wupT[(size_t)o * 512 + c] = f2bf(v.x);
        wupT[262144 + (size_t)o * 512 + c] = f2bf(v.y);
    } else if (bid < 2304) {
        cvt8(w1, w1b, (bid - 2048) * 256 + tid);
    } else if (bid < 2432) {
        cvt8(w2, w2b, (bid - 2304) * 256 + tid);
    } else {
        int r = bid - 2432;
        int layer = r / 816;
        int lb = r - layer * 816;
        unsigned short* base = lw + (size_t)layer * 1671168;
        if (lb < 512) {
            cvt8(in_proj_w + (size_t)layer * 1048576, base, lb * 256 + tid);
        } else if (lb < 768) {
            cvt8(out_proj_w + (size_t)layer * 524288, base + 1048576,
                 (lb - 512) * 256 + tid);
        } else if (lb < 800) {
            cvt8(x_proj_w + (size_t)layer * 65536, base + 1572864,
                 (lb - 768) * 256 + tid);
        } else {
            cvt8(dt_proj_w + (size_t)layer * 32768, base + 1638400,
                 (lb - 800) * 256 + tid);
        }
    }
}

// ---------------------------------------------------------------------------
// MFMA GEMM 128x128: C[M,N] (+)= A_bf16[M,K] * W_bf16[N,K]^T
// ---------------------------------------------------------------------------
template <int ACT, bool ACC, bool EMBED, bool OBF>
__global__ __launch_bounds__(256) void gemm_mfma(
    const unsigned short* __restrict__ A, int lda,
    const unsigned short* __restrict__ W, int ldw,
    void* __restrict__ Cv, int ldc, int N, int K, int gx,
    const float* __restrict__ bias, const float* __restrict__ embed)
{
    __shared__ unsigned short Asm[2][128 * 64];
    __shared__ unsigned short Wsm[2][128 * 64];
    const int tid = (int)threadIdx.x;
    const int lane = tid & 63;
    const int wv = tid >> 6;
    const int wm = wv >> 1, wn = wv & 1;

    const int nwg = (int)gridDim.x;
    const int lin = (int)blockIdx.x;
    const int logical = (lin & 7) * (nwg >> 3) + (lin >> 3);
    const int by = logical / gx;
    const int bx = logical - by * gx;
    const int bm = by * 128, bn = bx * 128;

    f32x4 acc[4][4] = {};
    const int l8 = lane >> 3;
    const int wc = lane & 7;
    const int wcg = wc ^ l8;
    const int NT = K >> 6;

    {
        char* aB = (char*)Asm[0];
        char* bB = (char*)Wsm[0];
#pragma unroll
        for (int i = 0; i < 4; ++i) {
            int rb = (i * 4 + wv) * 8;
            gload16(W + (size_t)(bn + rb + l8) * ldw + wcg * 8, bB + rb * 128);
            gload16(A + (size_t)(bm + rb + l8) * lda + wcg * 8, aB + rb * 128);
        }
    }
    __syncthreads();

    for (int t = 0; t < NT; ++t) {
        const int cur = t & 1;
        if (t + 1 < NT) {
            const int k1 = (t + 1) << 6;
            char* aB = (char*)Asm[cur ^ 1];
            char* bB = (char*)Wsm[cur ^ 1];
#pragma unroll
            for (int i = 0; i < 4; ++i) {
                int rb = (i * 4 + wv) * 8;
                gload16(W + (size_t)(bn + rb + l8) * ldw + k1 + wcg * 8, bB + rb * 128);
                gload16(A + (size_t)(bm + rb + l8) * lda + k1 + wcg * 8, aB + rb * 128);
            }
        }
        const char* aB = (const char*)Asm[cur];
        const char* bB = (const char*)Wsm[cur];
        const int rA = wm * 64 + (lane & 15);
        const int rB = wn * 64 + (lane & 15);
        const int q = lane >> 4;
#pragma unroll
        for (int kk = 0; kk < 2; ++kk) {
            bf16x8 af[4], bfr[4];
#pragma unroll
            for (int mi = 0; mi < 4; ++mi) {
                int row = rA + mi * 16;
                int ch = (kk * 4 + q) ^ (row & 7);
                af[mi] = *(const bf16x8*)(aB + row * 128 + ch * 16);
            }
#pragma unroll
            for (int ni = 0; ni < 4; ++ni) {
                int row = rB + ni * 16;
                int ch = (kk * 4 + q) ^ (row & 7);
                bfr[ni] = *(const bf16x8*)(bB + row * 128 + ch * 16);
            }
#pragma unroll
            for (int mi = 0; mi < 4; ++mi)
#pragma unroll
                for (int ni = 0; ni < 4; ++ni)
                    acc[mi][ni] = __builtin_amdgcn_mfma_f32_16x16x32_bf16(
                        af[mi], bfr[ni], acc[mi][ni], 0, 0, 0);
        }
        __syncthreads();
    }

    const int cn = lane & 15;
    const int r0 = (lane >> 4) * 4;
    const int eb = EMBED ? (bm >> 10) * N : 0;
#pragma unroll
    for (int ni = 0; ni < 4; ++ni) {
        int col = bn + wn * 64 + ni * 16 + cn;
        float add = bias ? bias[col] : 0.0f;
        if (EMBED) add += embed[eb + col];
#pragma unroll
        for (int mi = 0; mi < 4; ++mi) {
#pragma unroll
            for (int r = 0; r < 4; ++r) {
                int row = bm + wm * 64 + mi * 16 + r0 + r;
                float v = acc[mi][ni][r] + add;
                if (ACT == 1) v = softplus_fast(v);
                if (OBF) {
                    ((unsigned short*)Cv)[(size_t)row * ldc + col] = f2bf(v);
                } else {
                    float* p = (float*)Cv + (size_t)row * ldc + col;
                    if (ACC) *p += v; else *p = v;
                }
            }
        }
    }
}

// ---------------------------------------------------------------------------
// MFMA GEMM 64x64 (high occupancy). UPS: upsample epilogue — output col j
// maps to addr row*2048 + (j>>9)*1024 + (j&511), bias indexed by (j&511).
// ---------------------------------------------------------------------------
template <int ACT, bool ACC, bool EMBED, bool OBF, bool UPS>
__global__ __launch_bounds__(256) void gemm_mfma64(
    const unsigned short* __restrict__ A, int lda,
    const unsigned short* __restrict__ W, int ldw,
    void* __restrict__ Cv, int ldc, int N, int K, int gx,
    const float* __restrict__ bias, const float* __restrict__ embed)
{
    __shared__ unsigned short Asm[2][64 * 64];
    __shared__ unsigned short Wsm[2][64 * 64];
    const int tid = (int)threadIdx.x;
    const int lane = tid & 63;
    const int wv = tid >> 6;
    const int wm = wv >> 1, wn = wv & 1;

    const int nwg = (int)gridDim.x;
    const int lin = (int)blockIdx.x;
    const int logical = (lin & 7) * (nwg >> 3) + (lin >> 3);
    const int by = logical / gx;
    const int bx = logical - by * gx;
    const int bm = by * 64, bn = bx * 64;

    f32x4 acc[2][2] = {};
    const int l8 = lane >> 3;
    const int wc = lane & 7;
    const int wcg = wc ^ l8;
    const int NT = K >> 6;

    {
        char* aB = (char*)Asm[0];
        char* bB = (char*)Wsm[0];
#pragma unroll
        for (int i = 0; i < 2; ++i) {
            int rb = (i * 4 + wv) * 8;
            gload16(W + (size_t)(bn + rb + l8) * ldw + wcg * 8, bB + rb * 128);
            gload16(A + (size_t)(bm + rb + l8) * lda + wcg * 8, aB + rb * 128);
        }
    }
    __syncthreads();

    for (int t = 0; t < NT; ++t) {
        const int cur = t & 1;
        if (t + 1 < NT) {
            const int k1 = (t + 1) << 6;
            char* aB = (char*)Asm[cur ^ 1];
            char* bB = (char*)Wsm[cur ^ 1];
#pragma unroll
            for (int i = 0; i < 2; ++i) {
                int rb = (i * 4 + wv) * 8;
                gload16(W + (size_t)(bn + rb + l8) * ldw + k1 + wcg * 8, bB + rb * 128);
                gload16(A + (size_t)(bm + rb + l8) * lda + k1 + wcg * 8, aB + rb * 128);
            }
        }
        const char* aB = (const char*)Asm[cur];
        const char* bB = (const char*)Wsm[cur];
        const int rA = wm * 32 + (lane & 15);
        const int rB = wn * 32 + (lane & 15);
        const int q = lane >> 4;
#pragma unroll
        for (int kk = 0; kk < 2; ++kk) {
            bf16x8 af[2], bfr[2];
#pragma unroll
            for (int mi = 0; mi < 2; ++mi) {
                int row = rA + mi * 16;
                int ch = (kk * 4 + q) ^ (row & 7);
                af[mi] = *(const bf16x8*)(aB + row * 128 + ch * 16);
            }
#pragma unroll
            for (int ni = 0; ni < 2; ++ni) {
                int row = rB + ni * 16;
                int ch = (kk * 4 + q) ^ (row & 7);
                bfr[ni] = *(const bf16x8*)(bB + row * 128 + ch * 16);
            }
#pragma unroll
            for (int mi = 0; mi < 2; ++mi)
#pragma unroll
                for (int ni = 0; ni < 2; ++ni)
                    acc[mi][ni] = __builtin_amdgcn_mfma_f32_16x16x32_bf16(
                        af[mi], bfr[ni], acc[mi][ni], 0, 0, 0);
        }
        __syncthreads();
    }

    const int cn = lane & 15;
    const int r0 = (lane >> 4) * 4;
    const int eb = EMBED ? (bm >> 10) * N : 0;
#pragma unroll
    for (int ni = 0; ni < 2; ++ni) {
        int col = bn + wn * 32 + ni * 16 + cn;
        float add = bias ? bias[UPS ? (col & 511) : col] : 0.0f;
        if (EMBED) add += embed[eb + col];
#pragma unroll
        for (int mi = 0; mi < 2; ++mi) {
#pragma unroll
            for (int r = 0; r < 4; ++r) {
                int row = bm + wm * 32 + mi * 16 + r0 + r;
                float v = acc[mi][ni][r] + add;
                if (ACT == 1) v = softplus_fast(v);
                if (UPS) {
                    size_t ad = (size_t)row * 2048 + ((col >> 9) << 10) + (col & 511);
                    ((unsigned short*)Cv)[ad] = f2bf(v);
                } else if (OBF) {
                    ((unsigned short*)Cv)[(size_t)row * ldc + col] = f2bf(v);
                } else {
                    float* p = (float*)Cv + (size_t)row * ldc + col;
                    if (ACC) *p += v; else *p = v;
                }
            }
        }
    }
}

// ---------------------------------------------------------------------------
// dt GEMM: dt[8192,1024] = softplus(dtp[8192,32] @ dtw[1024,32]^T + bias)
// ---------------------------------------------------------------------------
__global__ __launch_bounds__(256) void gemm_dt(
    const unsigned short* __restrict__ xdbc,
    const unsigned short* __restrict__ wdt,
    const float* __restrict__ bias,
    unsigned short* __restrict__ out)
{
    __shared__ unsigned short S[128 * 136];
    const int tid = (int)threadIdx.x;
    const int lane = tid & 63;
    const int wv = tid >> 6;
    const int wm = wv >> 1, wn = wv & 1;

    const int lin = (int)blockIdx.x;
    const int logical = (lin & 7) * 64 + (lin >> 3);
    const int bm = (logical >> 3) * 128;
    const int bn = (logical & 7) * 128;

    const int fr = lane & 15;
    const int q = lane >> 4;

    bf16x8 af[4], wf[4];
#pragma unroll
    for (int mi = 0; mi < 4; ++mi)
        af[mi] = *(const bf16x8*)(xdbc + (size_t)(bm + wm * 64 + mi * 16 + fr) * 64 + q * 8);
#pragma unroll
    for (int ni = 0; ni < 4; ++ni)
        wf[ni] = *(const bf16x8*)(wdt + (size_t)(bn + wn * 64 + ni * 16 + fr) * 32 + q * 8);

    f32x4 acc[4][4] = {};
#pragma unroll
    for (int mi = 0; mi < 4; ++mi)
#pragma unroll
        for (int ni = 0; ni < 4; ++ni)
            acc[mi][ni] = __builtin_amdgcn_mfma_f32_16x16x32_bf16(
                af[mi], wf[ni], acc[mi][ni], 0, 0, 0);

    const int cn = lane & 15;
    const int r0 = (lane >> 4) * 4;
#pragma unroll
    for (int ni = 0; ni < 4; ++ni) {
        int lcol = wn * 64 + ni * 16 + cn;
        float add = bias[bn + lcol];
#pragma unroll
        for (int mi = 0; mi < 4; ++mi) {
#pragma unroll
            for (int r = 0; r < 4; ++r) {
                int lrow = wm * 64 + mi * 16 + r0 + r;
                S[lrow * 136 + lcol] = f2bf(softplus_fast(acc[mi][ni][r] + add));
            }
        }
    }
    __syncthreads();

    const int row = tid >> 1;
    const int half = tid & 1;
    const unsigned short* src = S + row * 136 + half * 64;
    unsigned short* dst = out + (size_t)(bm + row) * 1024 + bn + half * 64;
#pragma unroll
    for (int k = 0; k < 8; ++k) {
        uint4 v = *(const uint4*)(src + k * 8);
        *(uint4*)(dst + k * 8) = v;
    }
}

// ---------------------------------------------------------------------------
// Skinny MFMA GEMM: xdbc[M,64] = u[M,1024] * xpw[64,1024]^T (bf16 out)
// ---------------------------------------------------------------------------
__global__ __launch_bounds__(128) void gemm_xdbc(
    const unsigned short* __restrict__ A,
    const unsigned short* __restrict__ W,
    unsigned short* __restrict__ C)
{
    __shared__ unsigned short Asm[64 * 64];
    __shared__ unsigned short Wsm[64 * 64];
    const int tid = (int)threadIdx.x;
    const int lane = tid & 63;
    const int w = tid >> 6;
    const int bm = blockIdx.x * 64;
    const int l8 = lane >> 3, wc = lane & 7, wcg = wc ^ l8;
    char* aB = (char*)Asm;
    char* bB = (char*)Wsm;

    f32x4 acc[2][4] = {};

    for (int k0 = 0; k0 < 1024; k0 += 64) {
#pragma unroll
        for (int i = 0; i < 4; ++i) {
            int rb = (i * 2 + w) * 8;
            gload16(A + (size_t)(bm + rb + l8) * 1024 + k0 + wcg * 8, aB + rb * 128);
            gload16(W + (size_t)(rb + l8) * 1024 + k0 + wcg * 8, bB + rb * 128);
        }
        __syncthreads();
        const int rA = w * 32 + (lane & 15);
        const int rB = (lane & 15);
        const int q = lane >> 4;
#pragma unroll
        for (int kk = 0; kk < 2; ++kk) {
            bf16x8 af[2], bfr[4];
#pragma unroll
            for (int mi = 0; mi < 2; ++mi) {
                int row = rA + mi * 16;
                int ch = (kk * 4 + q) ^ (row & 7);
                af[mi] = *(const bf16x8*)(aB + row * 128 + ch * 16);
            }
#pragma unroll
            for (int ni = 0; ni < 4; ++ni) {
                int row = rB + ni * 16;
                int ch = (kk * 4 + q) ^ (row & 7);
                bfr[ni] = *(const bf16x8*)(bB + row * 128 + ch * 16);
            }
#pragma unroll
            for (int mi = 0; mi < 2; ++mi)
#pragma unroll
                for (int ni = 0; ni < 4; ++ni)
                    acc[mi][ni] = __builtin_amdgcn_mfma_f32_16x16x32_bf16(
                        af[mi], bfr[ni], acc[mi][ni], 0, 0, 0);
        }
        __syncthreads();
    }
    const int cn = lane & 15;
    const int r0 = (lane >> 4) * 4;
#pragma unroll
    for (int mi = 0; mi < 2; ++mi)
#pragma unroll
        for (int ni = 0; ni < 4; ++ni)
#pragma unroll
            for (int r = 0; r < 4; ++r) {
                int row = bm + w * 32 + mi * 16 + r0 + r;
                C[(size_t)row * 64 + ni * 16 + cn] = f2bf(acc[mi][ni][r]);
            }
}

// ---------------------------------------------------------------------------
__global__ __launch_bounds__(256) void concat_skip(
    const float* __restrict__ skip, unsigned short* __restrict__ x0)
{
    int t = blockIdx.x * 256 + (int)threadIdx.x;
    int row = t >> 6;
    int c8 = (t & 63) << 3;
    const float* s = skip + (size_t)row * 512 + c8;
    float4 f0 = *(const float4*)s;
    float4 f1 = *(const float4*)(s + 4);
    union { unsigned short u[8]; uint4 v; } pk;
    pk.u[0] = f2bf(f0.x); pk.u[1] = f2bf(f0.y); pk.u[2] = f2bf(f0.z); pk.u[3] = f2bf(f0.w);
    pk.u[4] = f2bf(f1.x); pk.u[5] = f2bf(f1.y); pk.u[6] = f2bf(f1.z); pk.u[7] = f2bf(f1.w);
    *(uint4*)(x0 + (size_t)row * 1024 + 512 + c8) = pk.v;
}

// ---------------------------------------------------------------------------
template <bool BFOUT>
__global__ __launch_bounds__(256) void layernorm_k(
    const float* __restrict__ x, void* __restrict__ outp,
    const float* __restrict__ w, const float* __restrict__ b)
{
    const int row = blockIdx.x * 4 + ((int)threadIdx.x >> 6);
    const int lane = (int)threadIdx.x & 63;
    const float* xr = x + (size_t)row * 512;
    float4 v0 = *(const float4*)(xr + lane * 4);
    float4 v1 = *(const float4*)(xr + 256 + lane * 4);
    float s = v0.x + v0.y + v0.z + v0.w + v1.x + v1.y + v1.z + v1.w;
    float q = v0.x*v0.x + v0.y*v0.y + v0.z*v0.z + v0.w*v0.w
            + v1.x*v1.x + v1.y*v1.y + v1.z*v1.z + v1.w*v1.w;
#pragma unroll
    for (int o = 32; o; o >>= 1) {
        s += __shfl_xor(s, o, 64);
        q += __shfl_xor(q, o, 64);
    }
    const float mean = s * (1.0f / 512.0f);
    const float var = q * (1.0f / 512.0f) - mean * mean;
    const float rstd = rsqrtf(var + EPS);
    float4 w0 = *(const float4*)(w + lane * 4);
    float4 w1 = *(const float4*)(w + 256 + lane * 4);
    float4 b0 = *(const float4*)(b + lane * 4);
    float4 b1 = *(const float4*)(b + 256 + lane * 4);
    float4 o0, o1;
    o0.x = (v0.x - mean) * rstd * w0.x + b0.x;
    o0.y = (v0.y - mean) * rstd * w0.y + b0.y;
    o0.z = (v0.z - mean) * rstd * w0.z + b0.z;
    o0.w = (v0.w - mean) * rstd * w0.w + b0.w;
    o1.x = (v1.x - mean) * rstd * w1.x + b1.x;
    o1.y = (v1.y - mean) * rstd * w1.y + b1.y;
    o1.z = (v1.z - mean) * rstd * w1.z + b1.z;
    o1.w = (v1.w - mean) * rstd * w1.w + b1.w;
    if (BFOUT) {
        unsigned short* ob = (unsigned short*)outp + (size_t)row * 512;
        union { unsigned short u[4]; uint2 v; } p0, p1;
        p0.u[0] = f2bf(o0.x); p0.u[1] = f2bf(o0.y); p0.u[2] = f2bf(o0.z); p0.u[3] = f2bf(o0.w);
        p1.u[0] = f2bf(o1.x); p1.u[1] = f2bf(o1.y); p1.u[2] = f2bf(o1.z); p1.u[3] = f2bf(o1.w);
        *(uint2*)(ob + lane * 4) = p0.v;
        *(uint2*)(ob + 256 + lane * 4) = p1.v;
    } else {
        float* orow = (float*)outp + (size_t)row * 512;
        *(float4*)(orow + lane * 4) = o0;
        *(float4*)(orow + 256 + lane * 4) = o1;
    }
}

__global__ __launch_bounds__(256) void rms_silu_k(
    const float* __restrict__ x, unsigned short* __restrict__ o,
    const float* __restrict__ w)
{
    const int row = blockIdx.x * 4 + ((int)threadIdx.x >> 6);
    const int lane = (int)threadIdx.x & 63;
    const float* xr = x + (size_t)row * 512;
    float4 v0 = *(const float4*)(xr + lane * 4);
    float4 v1 = *(const float4*)(xr + 256 + lane * 4);
    float q = v0.x*v0.x + v0.y*v0.y + v0.z*v0.z + v0.w*v0.w
            + v1.x*v1.x + v1.y*v1.y + v1.z*v1.z + v1.w*v1.w;
#pragma unroll
    for (int of = 32; of; of >>= 1) q += __shfl_xor(q, of, 64);
    const float scale = rsqrtf(q * (1.0f / 512.0f) + EPS);
    float4 w0 = *(const float4*)(w + lane * 4);
    float4 w1 = *(const float4*)(w + 256 + lane * 4);
    union { unsigned short u[4]; uint2 v; } p0, p1;
    p0.u[0] = f2bf(siluf_(v0.x * scale * w0.x));
    p0.u[1] = f2bf(siluf_(v0.y * scale * w0.y));
    p0.u[2] = f2bf(siluf_(v0.z * scale * w0.z));
    p0.u[3] = f2bf(siluf_(v0.w * scale * w0.w));
    p1.u[0] = f2bf(siluf_(v1.x * scale * w1.x));
    p1.u[1] = f2bf(siluf_(v1.y * scale * w1.y));
    p1.u[2] = f2bf(siluf_(v1.z * scale * w1.z));
    p1.u[3] = f2bf(siluf_(v1.w * scale * w1.w));
    unsigned short* ob = o + (size_t)row * 512;
    *(uint2*)(ob + lane * 4) = p0.v;
    *(uint2*)(ob + 256 + lane * 4) = p1.v;
}

// ---------------------------------------------------------------------------
__global__ __launch_bounds__(256) void conv_silu_k2(
    const unsigned short* __restrict__ xz, unsigned short* __restrict__ ub,
    const float* __restrict__ cw, const float* __restrict__ cb)
{
    int t = blockIdx.x * 256 + (int)threadIdx.x;
    int d = t & 1023;
    int bc = t >> 10;
    int b = bc >> 4, ch = bc & 15;
    int l0 = ch * 64;
    float4 w4 = *(const float4*)(cw + (size_t)d * 4);
    float bias = cb[d];
    const unsigned short* src = xz + ((size_t)(b * 1024 + l0)) * 2048 + d;
    unsigned short* dst = ub + ((size_t)(b * 1024 + l0)) * 1024 + d;
    float x0 = 0.f, x1 = 0.f, x2 = 0.f;
    if (l0 > 0) {
        x0 = bf2f(src[-(size_t)3 * 2048]);
        x1 = bf2f(src[-(size_t)2 * 2048]);
        x2 = bf2f(src[-(size_t)1 * 2048]);
    }
    for (int l = 0; l < 64; ++l) {
        float x3 = bf2f(src[(size_t)l * 2048]);
        float v = fmaf(x0, w4.x, fmaf(x1, w4.y, fmaf(x2, w4.z, fmaf(x3, w4.w, bias))));
        dst[(size_t)l * 1024] = f2bf(siluf_(v));
        x0 = x1; x1 = x2; x2 = x3;
    }
}

// ---------------------------------------------------------------------------
// Split-L scan v5: 16 chunks x 64 l, grid 2048 (8 b x 16 ch x 16 dgroups).
// Thread = (dl 0..63, q 0..3); q owns n = 4q..4q+3. Sub-chunks of 32 l.
// SDT2 packs {dt,dtu} for 2 timesteps per float4 (1 b128 read per 2 l).
// ---------------------------------------------------------------------------
template <int CTRL>
DEV_INLINE float dpp_f(float x) {
    int yi = __builtin_amdgcn_update_dpp(
        0, __builtin_bit_cast(int, x), CTRL, 0xF, 0xF, true);
    return __builtin_bit_cast(float, yi);
}

template <int PHASE>
__global__ __launch_bounds__(256) void scan5(
    const unsigned short* __restrict__ dtp,
    const unsigned short* ubf,
    unsigned short* ybf,
    const unsigned short* __restrict__ xdbc,
    const unsigned short* __restrict__ zbf,
    float* __restrict__ hp,                  // (8,1024,16ch,16n) x {h,prod}
    const float* __restrict__ A_log,
    const float* __restrict__ Dp)
{
    __shared__ float SDT2[16][260];          // [l2][d*4]: {dt0,dtu0,dt1,dtu1}
    __shared__ float SB[32][20];
    __shared__ float SC[PHASE == 2 ? 32 : 1][20];
    __shared__ float YS[PHASE == 2 ? 32 : 1][68];

    const int lin = (int)blockIdx.x;
    const int logical = (lin & 7) * 256 + (lin >> 3);
    const int gg = logical & 15;
    const int t2 = logical >> 4;
    const int ch = t2 & 15, b = t2 >> 4;
    if (PHASE == 1 && ch == 15) return;
    const int tid = (int)threadIdx.x;
    const int dl = tid >> 2, q = tid & 2 ? (tid & 3) : (tid & 3);
    const int qq = tid & 3;
    const int dblk = gg << 6;
    const int d = dblk + dl;
    const int m0 = b * 1024 + ch * 64;

    float An[4];
#pragma unroll
    for (int j = 0; j < 4; ++j)
        An[j] = -__expf(A_log[(size_t)d * 16 + qq * 4 + j]);

    float h[4] = {};
    float prod[4] = {1.f, 1.f, 1.f, 1.f};
    if (PHASE == 2) {
        const float* hpb = hp + (((size_t)(b * 1024 + d)) * 16) * 32 + qq * 8;
        for (int cc = 0; cc < ch; ++cc) {
            float4 v0 = *(const float4*)(hpb + cc * 32);
            float4 v1 = *(const float4*)(hpb + cc * 32 + 4);
            h[0] = fmaf(v0.y, h[0], v0.x);
            h[1] = fmaf(v0.w, h[1], v0.z);
            h[2] = fmaf(v1.y, h[2], v1.x);
            h[3] = fmaf(v1.w, h[3], v1.z);
        }
    }

    // staging roles
    const int sl2 = tid >> 4;            // 0..15 (l-pair)
    const int sdg = (tid & 15) * 4;      // 4 d's
    const int bcr = (tid & 127) >> 2;    // B/C row 0..31
    const int bne = (tid & 3) << 2;      // n offset

    for (int s = 0; s < 2; ++s) {
        const int lbase = s * 32;
        {   // ---- stage SDT2 ----
            size_t r0 = (size_t)(m0 + lbase + 2 * sl2);
            uint2 dA = *(const uint2*)(dtp + r0 * 1024 + dblk + sdg);
            uint2 dB = *(const uint2*)(dtp + (r0 + 1) * 1024 + dblk + sdg);
            uint2 uA = *(const uint2*)(ubf + r0 * 1024 + dblk + sdg);
            uint2 uB = *(const uint2*)(ubf + (r0 + 1) * 1024 + dblk + sdg);
            const unsigned short* da = (const unsigned short*)&dA;
            const unsigned short* db = (const unsigned short*)&dB;
            const unsigned short* ua = (const unsigned short*)&uA;
            const unsigned short* ub2 = (const unsigned short*)&uB;
#pragma unroll
            for (int j = 0; j < 4; ++j) {
                float d0 = bf2f(da[j]), d1 = bf2f(db[j]);
                float4 wv = {d0, d0 * bf2f(ua[j]), d1, d1 * bf2f(ub2[j])};
                *(float4*)&SDT2[sl2][(sdg + j) * 4] = wv;
            }
        }
        {   // ---- stage B / C ----
            size_t gr = (size_t)(m0 + lbase + bcr);
            if (tid < 128) {
                uint2 Bu = *(const uint2*)(xdbc + gr * 64 + 32 + bne);
                const unsigned short* bb = (const unsigned short*)&Bu;
                float4 bv = {bf2f(bb[0]), bf2f(bb[1]), bf2f(bb[2]), bf2f(bb[3])};
                *(float4*)&SB[bcr][bne] = bv;
            } else if (PHASE == 2) {
                uint2 Cu = *(const uint2*)(xdbc + gr * 64 + 48 + bne);
                const unsigned short* cc2 = (const unsigned short*)&Cu;
                float4 cv = {bf2f(cc2[0]), bf2f(cc2[1]), bf2f(cc2[2]), bf2f(cc2[3])};
                *(float4*)&SC[bcr][bne] = cv;
            }
        }
        __syncthreads();

        // ---- scan 32 steps (16 l-pairs) ----
        for (int l2 = 0; l2 < 16; ++l2) {
            float4 sd = *(const float4*)&SDT2[l2][dl * 4];
            float4 B0 = *(const float4*)&SB[2 * l2][qq * 4];
            float4 B1 = *(const float4*)&SB[2 * l2 + 1][qq * 4];
            float p0 = 0.0f, p1 = 0.0f;
            float4 C0, C1;
            if (PHASE == 2) {
                C0 = *(const float4*)&SC[2 * l2][qq * 4];
                C1 = *(const float4*)&SC[2 * l2 + 1][qq * 4];
            }
            const float* B0p = (const float*)&B0;
            const float* B1p = (const float*)&B1;
            const float* C0p = (const float*)&C0;
            const float* C1p = (const float*)&C1;
#pragma unroll
            for (int j = 0; j < 4; ++j) {
                float e0 = __expf(sd.x * An[j]);
                if (PHASE == 1) prod[j] *= e0;
                h[j] = fmaf(e0, h[j], sd.y * B0p[j]);
                if (PHASE == 2) p0 = fmaf(h[j], C0p[j], p0);
                float e1 = __expf(sd.z * An[j]);
                if (PHASE == 1) prod[j] *= e1;
                h[j] = fmaf(e1, h[j], sd.w * B1p[j]);
                if (PHASE == 2) p1 = fmaf(h[j], C1p[j], p1);
            }
            if (PHASE == 2) {
                p0 += dpp_f<0xB1>(p0);
                p0 += dpp_f<0x4E>(p0);
                p1 += dpp_f<0xB1>(p1);
                p1 += dpp_f<0x4E>(p1);
                if (qq == 0) {
                    YS[2 * l2][dl] = p0;
                    YS[2 * l2 + 1][dl] = p1;
                }
            }
        }
        __syncthreads();

        // ---- store y = (p + u*D) * silu(z), bf16 ----
        if (PHASE == 2) {
            const int row = tid >> 3;
            const int e8 = (tid & 7) * 8;
            size_t gr = (size_t)(m0 + lbase + row);
            float4 p40 = *(const float4*)&YS[row][e8];
            float4 p41 = *(const float4*)&YS[row][e8 + 4];
            uint4 uu = *(const uint4*)(ubf + gr * 1024 + dblk + e8);
            uint4 zz = *(const uint4*)(zbf + gr * 2048 + 1024 + dblk + e8);
            float4 D0 = *(const float4*)(Dp + dblk + e8);
            float4 D1 = *(const float4*)(Dp + dblk + e8 + 4);
            const unsigned short* up = (const unsigned short*)&uu;
            const unsigned short* zp = (const unsigned short*)&zz;
            const float* pp0 = (const float*)&p40;
            const float* pp1 = (const float*)&p41;
            const float* dd0 = (const float*)&D0;
            const float* dd1 = (const float*)&D1;
            union { unsigned short u[8]; uint4 v; } pk;
#pragma unroll
            for (int j = 0; j < 4; ++j) {
                float y = fmaf(bf2f(up[j]), dd0[j], pp0[j]) * siluf_(bf2f(zp[j]));
                pk.u[j] = f2bf(y);
            }
#pragma unroll
            for (int j = 0; j < 4; ++j) {
                float y = fmaf(bf2f(up[4 + j]), dd1[j], pp1[j]) * siluf_(bf2f(zp[4 + j]));
                pk.u[4 + j] = f2bf(y);
            }
            *(uint4*)(ybf + gr * 1024 + dblk + e8) = pk.v;
        }
        __syncthreads();
    }

    if (PHASE == 1) {
        float* hpo = hp + (((size_t)(b * 1024 + d) * 16 + ch)) * 32 + qq * 8;
        float4 o0 = {h[0], prod[0], h[1], prod[1]};
        float4 o1 = {h[2], prod[2], h[3], prod[3]};
        *(float4*)hpo = o0;
        *(float4*)(hpo + 4) = o1;
    }
}

// ---------------------------------------------------------------------------
extern "C" void kernel_launch(void* const* d_in, const int* in_sizes, int n_in,
                              void* d_out, int out_size, void* d_ws, size_t ws_size,
                              hipStream_t stream)
{
    const float* motion     = (const float*)d_in[0];
    const float* skip       = (const float*)d_in[1];
    const float* embed      = (const float*)d_in[2];
    const float* w_up       = (const float*)d_in[3];
    const float* b_up       = (const float*)d_in[4];
    const float* w1         = (const float*)d_in[5];
    const float* b1         = (const float*)d_in[6];
    const float* rms_w      = (const float*)d_in[7];
    const float* w2         = (const float*)d_in[8];
    const float* b2         = (const float*)d_in[9];
    const float* ln_w       = (const float*)d_in[10];
    const float* ln_b       = (const float*)d_in[11];
    const float* in_proj_w  = (const float*)d_in[12];
    const float* conv_w     = (const float*)d_in[13];
    const float* conv_b     = (const float*)d_in[14];
    const float* x_proj_w   = (const float*)d_in[15];
    const float* dt_proj_w  = (const float*)d_in[16];
    const float* dt_proj_b  = (const float*)d_in[17];
    const float* A_log      = (const float*)d_in[18];
    const float* D_param    = (const float*)d_in[19];
    const float* out_proj_w = (const float*)d_in[20];
    const float* out_proj_b = (const float*)d_in[21];
    const float* norm_f_w   = (const float*)d_in[22];
    const float* norm_f_b   = (const float*)d_in[23];
    float* out = (float*)d_out;
    float* ws = (float*)d_ws;

    // Workspace (float offsets):
    float* xbuf = ws;                                        // (8192x512) f32
    float* xlnf = ws + 4194304;                              // (8192x512) f32
    unsigned short* xzbf  = (unsigned short*)(ws + 8388608); // (8192x2048) bf16
    unsigned short* ubf   = (unsigned short*)(ws + 16777216);// (8192x1024) bf16
    unsigned short* dtybf = (unsigned short*)(ws + 20971520);// (8192x1024) bf16
    unsigned short* xdbc  = (unsigned short*)(ws + 25165824);// (8192x64) bf16
    float* hp  = ws + 25427968;                              // 4M f (16 chunks)
    unsigned short* xsbf = (unsigned short*)(ws + 29622272); // (8192x512) bf16
    unsigned short* mbf  = (unsigned short*)(ws + 31719424); // 2M bf16
    unsigned short* wupT = (unsigned short*)(ws + 32768000); // 512K bf16
    unsigned short* w1b  = (unsigned short*)(ws + 33030144); // 512K bf16
    unsigned short* w2b  = (unsigned short*)(ws + 33292288); // 256K bf16
    unsigned short* lw   = (unsigned short*)(ws + 33423360); // 4 x 1671168 bf16

    unsigned short* x0bf = xzbf;

    dim3 blk(256);

    // --- All weight/input prep in one launch ---
    prep_all<<<dim3(5696), blk, 0, stream>>>(
        motion, w_up, w1, w2, in_proj_w, out_proj_w, x_proj_w, dt_proj_w,
        mbf, wupT, w1b, w2b, lw);

    // --- Stage 1: upsample (single merged GEMM) + concat ---
    gemm_mfma64<0, false, false, true, true><<<dim3(1024), blk, 0, stream>>>(
        mbf, 512, wupT, 512, x0bf, 0, 1024, 512, 16, b_up, nullptr);
    concat_skip<<<dim3(2048), blk, 0, stream>>>(skip, x0bf);

    // --- Stage 2 ---
    gemm_mfma64<0, false, false, false, false><<<dim3(1024), blk, 0, stream>>>(
        x0bf, 1024, w1b, 1024, xlnf, 512, 512, 1024, 8, b1, nullptr);
    rms_silu_k<<<dim3(2048), blk, 0, stream>>>(xlnf, xsbf, rms_w);

    // --- Stage 3 ---
    gemm_mfma64<0, false, true, false, false><<<dim3(1024), blk, 0, stream>>>(
        xsbf, 512, w2b, 512, xbuf, 512, 512, 512, 8, b2, embed);

    // --- Mamba blocks ---
    for (int i = 0; i < 4; ++i) {
        unsigned short* ipw = lw + (size_t)i * 1671168;
        unsigned short* opw = ipw + 1048576;
        unsigned short* xpw = ipw + 1572864;
        unsigned short* wdt = ipw + 1638400;
        layernorm_k<true><<<dim3(2048), blk, 0, stream>>>(
            xbuf, xsbf, ln_w + (size_t)i * 512, ln_b + (size_t)i * 512);
        gemm_mfma<0, false, false, true><<<dim3(1024), blk, 0, stream>>>(
            xsbf, 512, ipw, 512, xzbf, 2048, 2048, 512, 16, nullptr, nullptr);
        conv_silu_k2<<<dim3(512), blk, 0, stream>>>(
            xzbf, ubf, conv_w + (size_t)i * 4096, conv_b + (size_t)i * 1024);
        gemm_xdbc<<<dim3(128), dim3(128), 0, stream>>>(ubf, xpw, xdbc);
        gemm_dt<<<dim3(512), blk, 0, stream>>>(
            xdbc, wdt, dt_proj_b + (size_t)i * 1024, dtybf);
        scan5<1><<<dim3(2048), blk, 0, stream>>>(
            dtybf, ubf, nullptr, xdbc, xzbf, hp,
            A_log + (size_t)i * 16384, D_param + (size_t)i * 1024);
        scan5<2><<<dim3(2048), blk, 0, stream>>>(
            dtybf, ubf, ubf, xdbc, xzbf, hp,
            A_log + (size_t)i * 16384, D_param + (size_t)i * 1024);
        gemm_mfma64<0, true, false, false, false><<<dim3(1024), blk, 0, stream>>>(
            ubf, 1024, opw, 1024, xbuf, 512, 512, 1024, 8,
            out_proj_b + (size_t)i * 512, nullptr);
    }

    // --- Final layernorm -> out ---
    layernorm_k<false><<<dim3(2048), blk, 0, stream>>>(xbuf, out, norm_f_w, norm_f_b);
}